// Round 4
// baseline (373.384 us; speedup 1.0000x reference)
//
#include <hip/hip_runtime.h>
#include <stdint.h>

typedef unsigned short ushort_t;
typedef __attribute__((ext_vector_type(8))) short bf16x8;   // 8 bf16 in 4 VGPRs
typedef __attribute__((ext_vector_type(4))) float f32x4;

// ---------- helpers ----------
__device__ __forceinline__ unsigned short f2b(float f) {
  unsigned u = __float_as_uint(f);
  u += 0x7fffu + ((u >> 16) & 1u);   // round-to-nearest-even
  return (unsigned short)(u >> 16);
}

__device__ __forceinline__ void async16(const void* g, void* l) {
  __builtin_amdgcn_global_load_lds(
      (const __attribute__((address_space(1))) void*)g,
      (__attribute__((address_space(3))) void*)l, 16, 0, 0);
}

// ---------- LayerNorm (fp32 in -> bf16 out), one block per row, C=1024 ----------
__global__ __launch_bounds__(256) void ln_kernel(
    const float* __restrict__ x, const float* __restrict__ g,
    const float* __restrict__ be, ushort_t* __restrict__ out) {
  const int C = 1024;
  int row = blockIdx.x;
  const float4* xr = (const float4*)(x + (size_t)row * C);
  int tid = threadIdx.x;
  float4 v = xr[tid];
  float s = v.x + v.y + v.z + v.w;
  float sq = v.x * v.x + v.y * v.y + v.z * v.z + v.w * v.w;
  #pragma unroll
  for (int off = 32; off > 0; off >>= 1) {
    s += __shfl_xor(s, off);
    sq += __shfl_xor(sq, off);
  }
  __shared__ float ss[4], ssq[4];
  int wv = tid >> 6;
  if ((tid & 63) == 0) { ss[wv] = s; ssq[wv] = sq; }
  __syncthreads();
  s = ss[0] + ss[1] + ss[2] + ss[3];
  sq = ssq[0] + ssq[1] + ssq[2] + ssq[3];
  float mu = s * (1.f / C);
  float var = sq * (1.f / C) - mu * mu;
  float rs = rsqrtf(var + 1e-5f);
  float4 gv = ((const float4*)g)[tid];
  float4 bv = ((const float4*)be)[tid];
  ushort4 o;
  o.x = f2b((v.x - mu) * rs * gv.x + bv.x);
  o.y = f2b((v.y - mu) * rs * gv.y + bv.y);
  o.z = f2b((v.z - mu) * rs * gv.z + bv.z);
  o.w = f2b((v.w - mu) * rs * gv.w + bv.w);
  ((ushort4*)(out + (size_t)row * C))[tid] = o;
}

// ---------- batched transpose + fp32->bf16 cast: in (bz,R,Cin) -> out (bz,Cin,R) ----------
__global__ __launch_bounds__(256) void transpose_cast_kernel(
    const float* __restrict__ in, ushort_t* __restrict__ out, int R, int Cin) {
  __shared__ float tile[32][33];
  int bz = blockIdx.z;
  in += (size_t)bz * R * Cin;
  out += (size_t)bz * R * Cin;
  int c0 = blockIdx.x * 32, r0 = blockIdx.y * 32;
  int tx = threadIdx.x, ty = threadIdx.y;
  #pragma unroll
  for (int i = 0; i < 4; i++)
    tile[ty + 8 * i][tx] = in[(size_t)(r0 + ty + 8 * i) * Cin + c0 + tx];
  __syncthreads();
  #pragma unroll
  for (int i = 0; i < 4; i++)
    out[(size_t)(c0 + ty + 8 * i) * R + r0 + tx] = f2b(tile[tx][ty + 8 * i]);
}

// ---------- V transpose: QKV (4096,3072) bf16 -> Vt (B*H, 64, 2048) bf16 ----------
__global__ __launch_bounds__(256) void transpose_v_kernel(
    const ushort_t* __restrict__ qkv, ushort_t* __restrict__ vt) {
  __shared__ ushort_t tile[32][33];
  int bh = blockIdx.z;
  int b = bh >> 4, h = bh & 15;
  int d0 = blockIdx.x * 32, t0 = blockIdx.y * 32;
  int tx = threadIdx.x, ty = threadIdx.y;
  #pragma unroll
  for (int i = 0; i < 4; i++)
    tile[ty + 8 * i][tx] =
        qkv[(size_t)(b * 2048 + t0 + ty + 8 * i) * 3072 + 2048 + h * 64 + d0 + tx];
  __syncthreads();
  #pragma unroll
  for (int i = 0; i < 4; i++)
    vt[(size_t)(bh * 64 + d0 + ty + 8 * i) * 2048 + t0 + tx] = tile[tx][ty + 8 * i];
}

// ---------- GEMM: out(M,N) = A(M,K) @ Bt(N,K)^T, bf16 in, 128x128 tile ----------
// T4 pipeline (counted vmcnt, loads in flight ACROSS barriers):
//   3 LDS buffers (48 KB), prefetch depth 2 tiles, ONE raw s_barrier per K-tile
//   preceded by s_waitcnt vmcnt(4) (retires only the 2-iteration-old loads,
//   which are long complete -> near-zero stall; the 1-iter-old prefetch stays
//   in flight). Race ledger: iter t reads buf t%3 (DMA retired by the counted
//   wait, FIFO); stage(t+2) writes buf (t-1)%3 whose last reads completed
//   before this iter's barrier. FLAGS: 1=relu, 2=bf16 out, 4=+bias, 8=+resid.
template <int BN, int N, int K, int FLAGS, int SK>
__global__ __launch_bounds__(256, 3) void gemm_bt_kernel(
    const ushort_t* __restrict__ A, const ushort_t* __restrict__ Bt,
    const float* __restrict__ bias, const float* __restrict__ resid,
    void* __restrict__ outv, float* __restrict__ pp0, float* __restrict__ pp1) {
  constexpr int KS = K / SK;             // K-span per block
  constexpr int NT = KS / 32;            // K-tiles (>= 3)
  __shared__ ushort_t Als[3][128 * 32];
  __shared__ ushort_t Bls[3][128 * 32];
  int tid = threadIdx.x, w = tid >> 6, lane = tid & 63, quad = lane >> 4, l16 = lane & 15;
  // ---- XCD-group swizzle (fid mod 8 = XCD under round-robin dispatch) ----
  int fid = blockIdx.x;
  int bn_low = (fid >> 3) & 7;
  int meta = (fid & 7) | ((fid >> 6) << 3);
  int bm = meta & 31;                    // BM = 32 always (M = 4096)
  int high = meta >> 5;
  int bn, zz;
  if constexpr (SK > 1) { zz = high; bn = bn_low; }
  else { zz = 0; bn = bn_low + 8 * high; }
  int bn0 = bn * 128, bm0 = bm * 128;
  int koff = (SK > 1) ? zz * KS : 0;
  int wm = (w >> 1) * 64, wn = (w & 1) * 64;
  f32x4 acc[4][4];
  #pragma unroll
  for (int i = 0; i < 4; i++)
    #pragma unroll
    for (int j = 0; j < 4; j++) acc[i][j] = f32x4{0.f, 0.f, 0.f, 0.f};
  const ushort_t* Ag = A + (size_t)bm0 * K + koff;
  const ushort_t* Bg = Bt + (size_t)bn0 * K + koff;
  int lr = lane >> 2, lco = (lane & 3) * 8;
  auto stage = [&](int k0, int bi) {
    async16(Ag + (size_t)(w * 32 + lr) * K + k0 + lco, &Als[bi][w * 1024]);
    async16(Ag + (size_t)(w * 32 + 16 + lr) * K + k0 + lco, &Als[bi][w * 1024 + 512]);
    async16(Bg + (size_t)(w * 32 + lr) * K + k0 + lco, &Bls[bi][w * 1024]);
    async16(Bg + (size_t)(w * 32 + 16 + lr) * K + k0 + lco, &Bls[bi][w * 1024 + 512]);
  };
  stage(0, 0);
  stage(32, 1);
  int rb = 0, sb = 2;
  for (int t = 0; t < NT; ++t) {
    if (t < NT - 1) asm volatile("s_waitcnt vmcnt(4)" ::: "memory");
    else            asm volatile("s_waitcnt vmcnt(0)" ::: "memory");
    __builtin_amdgcn_s_barrier();
    if (t + 2 < NT) stage((t + 2) * 32, sb);
    bf16x8 af[4], bf[4];
    #pragma unroll
    for (int i = 0; i < 4; i++)
      af[i] = *(const bf16x8*)&Als[rb][(wm + i * 16 + l16) * 32 + quad * 8];
    #pragma unroll
    for (int j = 0; j < 4; j++)
      bf[j] = *(const bf16x8*)&Bls[rb][(wn + j * 16 + l16) * 32 + quad * 8];
    asm volatile("s_waitcnt lgkmcnt(0)" ::: "memory");
    __builtin_amdgcn_sched_barrier(0);
    __builtin_amdgcn_s_setprio(1);
    #pragma unroll
    for (int i = 0; i < 4; i++)
      #pragma unroll
      for (int j = 0; j < 4; j++)
        acc[i][j] = __builtin_amdgcn_mfma_f32_16x16x32_bf16(af[i], bf[j], acc[i][j], 0, 0, 0);
    __builtin_amdgcn_s_setprio(0);
    rb = rb == 2 ? 0 : rb + 1;
    sb = sb == 2 ? 0 : sb + 1;
  }
  float* pdst = nullptr;
  if constexpr (SK > 1) pdst = zz ? pp1 : pp0;
  #pragma unroll
  for (int i = 0; i < 4; i++)
    #pragma unroll
    for (int j = 0; j < 4; j++)
      #pragma unroll
      for (int r = 0; r < 4; r++) {
        int row = bm0 + wm + i * 16 + quad * 4 + r;
        int col = bn0 + wn + j * 16 + l16;
        float v = acc[i][j][r];
        if constexpr (SK > 1) {
          pdst[(size_t)row * N + col] = v;   // raw partial
        } else {
          if constexpr (FLAGS & 4) v += bias[col];
          if constexpr (FLAGS & 8) v += resid[(size_t)row * N + col];
          if constexpr (FLAGS & 1) v = fmaxf(v, 0.f);
          if constexpr ((FLAGS & 2) != 0)
            ((ushort_t*)outv)[(size_t)row * N + col] = f2b(v);
          else
            ((float*)outv)[(size_t)row * N + col] = v;
        }
      }
}

// ---------- GEMM 128x64 tile, same T4 pipeline (36 KB LDS, vmcnt(3)) ----------
// Used for narrow-N shapes: Wo (N=1024, 512 blocks) and FF2 (N=1024, K=4096,
// 512 blocks, fused bias+resid epilogue -> no split-K, no reduce pass).
template <int N, int K, int FLAGS, int SK>
__global__ __launch_bounds__(256, 3) void gemm_bt64_kernel(
    const ushort_t* __restrict__ A, const ushort_t* __restrict__ Bt,
    const float* __restrict__ bias, const float* __restrict__ resid,
    void* __restrict__ outv, float* __restrict__ pp0, float* __restrict__ pp1) {
  constexpr int KS = K / SK;
  constexpr int NT = KS / 32;            // >= 3
  constexpr int NBM = 32;                // M = 4096 / 128
  constexpr int NBN = N / 64;
  constexpr int NWG = NBM * NBN * SK;    // must == gridDim.x, % 8 == 0
  __shared__ ushort_t Als[3][128 * 32];  // 24 KB
  __shared__ ushort_t Bls[3][64 * 32];   // 12 KB
  int tid = threadIdx.x, w = tid >> 6, lane = tid & 63, quad = lane >> 4, l16 = lane & 15;
  // XCD-chunked bijective swizzle: consecutive swz share bm -> A-panel stays
  // hot in the XCD's L2 while bn sweeps.
  int bid = blockIdx.x;
  int swz = (bid & 7) * (NWG / 8) + (bid >> 3);
  int z = 0;
  if constexpr (SK > 1) { z = swz / (NBM * NBN); swz -= z * (NBM * NBN); }
  int bm = swz / NBN, bn = swz - bm * NBN;
  int bm0 = bm * 128, bn0 = bn * 64;
  int koff = z * KS;
  int wm = (w >> 1) * 64, wn = (w & 1) * 32;
  f32x4 acc[4][2];
  #pragma unroll
  for (int i = 0; i < 4; i++)
    #pragma unroll
    for (int j = 0; j < 2; j++) acc[i][j] = f32x4{0.f, 0.f, 0.f, 0.f};
  const ushort_t* Ag = A + (size_t)bm0 * K + koff;
  const ushort_t* Bg = Bt + (size_t)bn0 * K + koff;
  int lr = lane >> 2, lco = (lane & 3) * 8;
  auto stage = [&](int k0, int bi) {
    async16(Ag + (size_t)(w * 32 + lr) * K + k0 + lco, &Als[bi][w * 1024]);
    async16(Ag + (size_t)(w * 32 + 16 + lr) * K + k0 + lco, &Als[bi][w * 1024 + 512]);
    async16(Bg + (size_t)(w * 16 + lr) * K + k0 + lco, &Bls[bi][w * 512]);
  };
  stage(0, 0);
  stage(32, 1);
  int rb = 0, sb = 2;
  for (int t = 0; t < NT; ++t) {
    if (t < NT - 1) asm volatile("s_waitcnt vmcnt(3)" ::: "memory");
    else            asm volatile("s_waitcnt vmcnt(0)" ::: "memory");
    __builtin_amdgcn_s_barrier();
    if (t + 2 < NT) stage((t + 2) * 32, sb);
    bf16x8 af[4], bf[2];
    #pragma unroll
    for (int i = 0; i < 4; i++)
      af[i] = *(const bf16x8*)&Als[rb][(wm + i * 16 + l16) * 32 + quad * 8];
    #pragma unroll
    for (int j = 0; j < 2; j++)
      bf[j] = *(const bf16x8*)&Bls[rb][(wn + j * 16 + l16) * 32 + quad * 8];
    asm volatile("s_waitcnt lgkmcnt(0)" ::: "memory");
    __builtin_amdgcn_sched_barrier(0);
    __builtin_amdgcn_s_setprio(1);
    #pragma unroll
    for (int i = 0; i < 4; i++)
      #pragma unroll
      for (int j = 0; j < 2; j++)
        acc[i][j] = __builtin_amdgcn_mfma_f32_16x16x32_bf16(af[i], bf[j], acc[i][j], 0, 0, 0);
    __builtin_amdgcn_s_setprio(0);
    rb = rb == 2 ? 0 : rb + 1;
    sb = sb == 2 ? 0 : sb + 1;
  }
  float* pdst = nullptr;
  if constexpr (SK > 1) pdst = z ? pp1 : pp0;
  #pragma unroll
  for (int i = 0; i < 4; i++)
    #pragma unroll
    for (int j = 0; j < 2; j++)
      #pragma unroll
      for (int r = 0; r < 4; r++) {
        int row = bm0 + wm + i * 16 + quad * 4 + r;
        int col = bn0 + wn + j * 16 + l16;
        float v = acc[i][j][r];
        if constexpr (SK > 1) {
          pdst[(size_t)row * N + col] = v;   // raw partial
        } else {
          if constexpr (FLAGS & 4) v += bias[col];
          if constexpr (FLAGS & 8) v += resid[(size_t)row * N + col];
          if constexpr (FLAGS & 1) v = fmaxf(v, 0.f);
          if constexpr ((FLAGS & 2) != 0)
            ((ushort_t*)outv)[(size_t)row * N + col] = f2b(v);
          else
            ((float*)outv)[(size_t)row * N + col] = v;
        }
      }
}

// ---------- causal flash attention: dbuf LDS staging + S^T softmax ----------
// 1024 blocks = 32 (b,h) x 32 q-blocks of 64 rows -> 4 blocks/CU.
__global__ __launch_bounds__(256, 4) void attn_kernel(
    const ushort_t* __restrict__ qkv, const ushort_t* __restrict__ vt,
    ushort_t* __restrict__ out) {
  const int T = 2048, CC = 3072;
  __shared__ ushort_t Kls[2][2 * 64 * 32];
  __shared__ ushort_t Vls[2][2 * 64 * 32];
  int fid = blockIdx.x;                       // 1024
  int bh = (fid & 7) * 4 + ((fid >> 3) & 3);  // XCD swizzle: 4 heads per XCD
  int qb = 31 - (fid >> 5);                   // longest q-blocks first
  int b = bh >> 4, h = bh & 15;
  int q0 = qb * 64;
  int tid = threadIdx.x, w = tid >> 6, lane = tid & 63, quad = lane >> 4, l16 = lane & 15;
  int srow = w * 16 + (lane >> 2);
  int sco = (lane & 3) * 8;
  const ushort_t* kg = qkv + (size_t)(b * T + srow) * CC + 1024 + h * 64 + sco;
  const ushort_t* vg = vt + (size_t)(bh * 64 + srow) * T + sco;
  int q0s = q0 + w * 16;
  int trow = q0s + l16;
  const ushort_t* qp = qkv + (size_t)(b * T + trow) * CC + h * 64 + quad * 8;
  bf16x8 aq[2] = { *(const bf16x8*)qp, *(const bf16x8*)(qp + 32) };
  f32x4 O[4];
  #pragma unroll
  for (int i = 0; i < 4; i++) O[i] = f32x4{0.f, 0.f, 0.f, 0.f};
  float mrun = -1e30f, lrun = 0.f;
  const float ksc = 0.03125f * 1.44269504f;  // C^-0.5 * log2(e)
  int src0 = (quad & 1) * 32 + l16;
  int src1 = src0 + 16;
  bool hiq = quad >= 2;
  auto stage = [&](int kb, int bi) {
    int s0 = kb * 64;
    async16(kg + (size_t)s0 * CC, &Kls[bi][w * 512]);
    async16(kg + (size_t)s0 * CC + 32, &Kls[bi][2048 + w * 512]);
    async16(vg + s0, &Vls[bi][w * 512]);
    async16(vg + s0 + 32, &Vls[bi][2048 + w * 512]);
  };
  stage(0, 0);
  for (int kb = 0; kb <= qb; kb++) {
    __syncthreads();
    if (kb < qb) stage(kb + 1, (kb + 1) & 1);
    int bi = kb & 1;
    int s0 = kb * 64;
    bf16x8 kfr[4][2], vfr[4][2];
    #pragma unroll
    for (int t = 0; t < 4; t++)
      #pragma unroll
      for (int ks = 0; ks < 2; ks++) {
        kfr[t][ks] = *(const bf16x8*)&Kls[bi][(ks * 64 + t * 16 + l16) * 32 + quad * 8];
        vfr[t][ks] = *(const bf16x8*)&Vls[bi][(ks * 64 + t * 16 + l16) * 32 + quad * 8];
      }
    f32x4 st[4];
    #pragma unroll
    for (int t = 0; t < 4; t++) {
      st[t] = f32x4{0.f, 0.f, 0.f, 0.f};
      #pragma unroll
      for (int ks = 0; ks < 2; ks++)
        st[t] = __builtin_amdgcn_mfma_f32_16x16x32_bf16(kfr[t][ks], aq[ks], st[t], 0, 0, 0);
    }
    float sv[4][4];
    float vmax = -1e30f;
    if (kb == qb) {
      #pragma unroll
      for (int t = 0; t < 4; t++)
        #pragma unroll
        for (int r = 0; r < 4; r++) {
          float sc = st[t][r] * ksc;
          int scol = s0 + t * 16 + quad * 4 + r;
          if (scol > trow) sc = -1e30f;
          sv[t][r] = sc;
          vmax = fmaxf(vmax, sc);
        }
    } else {
      #pragma unroll
      for (int t = 0; t < 4; t++)
        #pragma unroll
        for (int r = 0; r < 4; r++) {
          float sc = st[t][r] * ksc;
          sv[t][r] = sc;
          vmax = fmaxf(vmax, sc);
        }
    }
    vmax = fmaxf(vmax, __shfl_xor(vmax, 16));
    vmax = fmaxf(vmax, __shfl_xor(vmax, 32));
    float mnew = fmaxf(mrun, vmax);
    float alpha = __builtin_amdgcn_exp2f(mrun - mnew);
    mrun = mnew;
    float psum = 0.f;
    int pk[4][2];
    #pragma unroll
    for (int t = 0; t < 4; t++) {
      float p0 = __builtin_amdgcn_exp2f(sv[t][0] - mnew);
      float p1 = __builtin_amdgcn_exp2f(sv[t][1] - mnew);
      float p2 = __builtin_amdgcn_exp2f(sv[t][2] - mnew);
      float p3 = __builtin_amdgcn_exp2f(sv[t][3] - mnew);
      psum += (p0 + p1) + (p2 + p3);
      pk[t][0] = (int)((unsigned)f2b(p0) | ((unsigned)f2b(p1) << 16));
      pk[t][1] = (int)((unsigned)f2b(p2) | ((unsigned)f2b(p3) << 16));
    }
    psum += __shfl_xor(psum, 16);
    psum += __shfl_xor(psum, 32);
    lrun = lrun * alpha + psum;
    #pragma unroll
    for (int dt = 0; dt < 4; dt++) O[dt] *= alpha;
    #pragma unroll
    for (int g32 = 0; g32 < 2; g32++) {
      int t0 = 2 * g32, t1 = t0 + 1;
      int a0 = __shfl(pk[t0][0], src0), b0 = __shfl(pk[t1][0], src0);
      int a1 = __shfl(pk[t0][1], src0), b1 = __shfl(pk[t1][1], src0);
      int a2 = __shfl(pk[t0][0], src1), b2 = __shfl(pk[t1][0], src1);
      int a3 = __shfl(pk[t0][1], src1), b3 = __shfl(pk[t1][1], src1);
      union { int4 i; bf16x8 h; } u;
      u.i.x = hiq ? b0 : a0;
      u.i.y = hiq ? b1 : a1;
      u.i.z = hiq ? b2 : a2;
      u.i.w = hiq ? b3 : a3;
      #pragma unroll
      for (int dt = 0; dt < 4; dt++)
        O[dt] = __builtin_amdgcn_mfma_f32_16x16x32_bf16(vfr[dt][g32], u.h, O[dt], 0, 0, 0);
    }
  }
  float inv = 1.f / lrun;
  #pragma unroll
  for (int dt = 0; dt < 4; dt++) {
    ushort4 o;
    unsigned short* op = (unsigned short*)&o;
    #pragma unroll
    for (int r = 0; r < 4; r++) op[r] = f2b(O[dt][r] * inv);
    *(ushort4*)&out[(size_t)(b * T + trow) * 1024 + h * 64 + dt * 16 + quad * 4] = o;
  }
}

// ---------- host ----------
extern "C" void kernel_launch(void* const* d_in, const int* in_sizes, int n_in,
                              void* d_out, int out_size, void* d_ws, size_t ws_size,
                              hipStream_t stream) {
  const int B = 2, T = 2048, C = 1024, H = 16, D = 64, FF = 4096;
  const int M = B * T;  // 4096
  const float* x   = (const float*)d_in[0];
  const float* Wq  = (const float*)d_in[1];
  const float* Wk  = (const float*)d_in[2];
  const float* Wv  = (const float*)d_in[3];
  const float* Wo  = (const float*)d_in[4];
  const float* bo  = (const float*)d_in[5];
  const float* W1  = (const float*)d_in[6];
  const float* b1  = (const float*)d_in[7];
  const float* W2  = (const float*)d_in[8];
  const float* b2  = (const float*)d_in[9];
  const float* g1  = (const float*)d_in[10];
  const float* be1 = (const float*)d_in[11];
  const float* g2  = (const float*)d_in[12];
  const float* be2 = (const float*)d_in[13];
  float* out = (float*)d_out;

  char* ws = (char*)d_ws;
  size_t off = 0;
  auto alloc = [&](size_t bytes) {
    void* p = ws + off;
    off += (bytes + 255) & ~(size_t)255;
    return p;
  };
  ushort_t* qkvt = (ushort_t*)alloc((size_t)3 * C * C * 2);  // 6.29 MB
  ushort_t* wot  = (ushort_t*)alloc((size_t)C * C * 2);      // 2.10 MB
  ushort_t* w1t  = (ushort_t*)alloc((size_t)FF * C * 2);     // 8.39 MB
  ushort_t* w2t  = (ushort_t*)alloc((size_t)C * FF * 2);     // 8.39 MB
  ushort_t* hbuf = (ushort_t*)alloc((size_t)M * C * 2);      // 8.39 MB
  ushort_t* big  = (ushort_t*)alloc((size_t)M * FF * 2);     // 33.55 MB
  ushort_t* vtb  = (ushort_t*)alloc((size_t)M * C * 2);      // 8.39 MB
  ushort_t* aout = (ushort_t*)alloc((size_t)M * C * 2);      // 8.39 MB
  float*    x2   = (float*)alloc((size_t)M * C * 4);         // 16.78 MB

  dim3 tb(32, 8);
  transpose_cast_kernel<<<dim3(D / 32, C / 32, H), tb, 0, stream>>>(Wq, qkvt, C, D);
  transpose_cast_kernel<<<dim3(D / 32, C / 32, H), tb, 0, stream>>>(Wk, qkvt + (size_t)C * C, C, D);
  transpose_cast_kernel<<<dim3(D / 32, C / 32, H), tb, 0, stream>>>(Wv, qkvt + (size_t)2 * C * C, C, D);
  transpose_cast_kernel<<<dim3(C / 32, C / 32, 1), tb, 0, stream>>>(Wo, wot, C, C);
  transpose_cast_kernel<<<dim3(FF / 32, C / 32, 1), tb, 0, stream>>>(W1, w1t, C, FF);
  transpose_cast_kernel<<<dim3(C / 32, FF / 32, 1), tb, 0, stream>>>(W2, w2t, FF, C);
  ln_kernel<<<M, 256, 0, stream>>>(x, g1, be1, hbuf);
  // QKV = h @ Wqkv^T -> bf16  (768 blocks of 128^2 = 3/CU, XCD-grouped)
  gemm_bt_kernel<24, 3072, 1024, 2, 1><<<768, 256, 0, stream>>>(
      hbuf, qkvt, nullptr, nullptr, big, nullptr, nullptr);
  transpose_v_kernel<<<dim3(2, T / 32, B * H), tb, 0, stream>>>(big, vtb);
  attn_kernel<<<1024, 256, 0, stream>>>(big, vtb, aout);
  // x2 = attn @ Wo^T + bo + x (fp32)  (128x64 tiles: 512 blocks = 2/CU)
  gemm_bt64_kernel<1024, 1024, 4 | 8, 1><<<512, 256, 0, stream>>>(
      aout, wot, bo, x, x2, nullptr, nullptr);
  ln_kernel<<<M, 256, 0, stream>>>(x2, g2, be2, hbuf);
  // ff1 = relu(h2 @ W1^T + b1) -> bf16  (1024 blocks of 128^2 = 4/CU)
  gemm_bt_kernel<32, 4096, 1024, 1 | 2 | 4, 1><<<1024, 256, 0, stream>>>(
      hbuf, w1t, b1, nullptr, big, nullptr, nullptr);
  // out = ff1 @ W2^T + b2 + x2 (fp32, single-K: no partials, no reduce pass)
  gemm_bt64_kernel<1024, 4096, 4 | 8, 1><<<512, 256, 0, stream>>>(
      big, w2t, b2, x2, out, nullptr, nullptr);
}

// Round 5
// 366.577 us; speedup vs baseline: 1.0186x; 1.0186x over previous
//
#include <hip/hip_runtime.h>
#include <stdint.h>

typedef unsigned short ushort_t;
typedef __attribute__((ext_vector_type(8))) short bf16x8;   // 8 bf16 in 4 VGPRs
typedef __attribute__((ext_vector_type(4))) float f32x4;

// ---------- helpers ----------
__device__ __forceinline__ unsigned short f2b(float f) {
  unsigned u = __float_as_uint(f);
  u += 0x7fffu + ((u >> 16) & 1u);   // round-to-nearest-even
  return (unsigned short)(u >> 16);
}

__device__ __forceinline__ void async16(const void* g, void* l) {
  __builtin_amdgcn_global_load_lds(
      (const __attribute__((address_space(1))) void*)g,
      (__attribute__((address_space(3))) void*)l, 16, 0, 0);
}

// ---------- LayerNorm (fp32 in -> bf16 out), one block per row, C=1024 ----------
// Optional prefill: pout[row] = x[row] + pbias (used to seed out = x2 + b2
// before FF2's atomic accumulation; rides the pass that already loads x2).
__global__ __launch_bounds__(256) void ln_kernel(
    const float* __restrict__ x, const float* __restrict__ g,
    const float* __restrict__ be, ushort_t* __restrict__ out,
    const float* __restrict__ pbias, float* __restrict__ pout) {
  const int C = 1024;
  int row = blockIdx.x;
  const float4* xr = (const float4*)(x + (size_t)row * C);
  int tid = threadIdx.x;
  float4 v = xr[tid];
  float s = v.x + v.y + v.z + v.w;
  float sq = v.x * v.x + v.y * v.y + v.z * v.z + v.w * v.w;
  #pragma unroll
  for (int off = 32; off > 0; off >>= 1) {
    s += __shfl_xor(s, off);
    sq += __shfl_xor(sq, off);
  }
  __shared__ float ss[4], ssq[4];
  int wv = tid >> 6;
  if ((tid & 63) == 0) { ss[wv] = s; ssq[wv] = sq; }
  __syncthreads();
  s = ss[0] + ss[1] + ss[2] + ss[3];
  sq = ssq[0] + ssq[1] + ssq[2] + ssq[3];
  float mu = s * (1.f / C);
  float var = sq * (1.f / C) - mu * mu;
  float rs = rsqrtf(var + 1e-5f);
  float4 gv = ((const float4*)g)[tid];
  float4 bv = ((const float4*)be)[tid];
  ushort4 o;
  o.x = f2b((v.x - mu) * rs * gv.x + bv.x);
  o.y = f2b((v.y - mu) * rs * gv.y + bv.y);
  o.z = f2b((v.z - mu) * rs * gv.z + bv.z);
  o.w = f2b((v.w - mu) * rs * gv.w + bv.w);
  ((ushort4*)(out + (size_t)row * C))[tid] = o;
  if (pout) {
    float4 pb = ((const float4*)pbias)[tid];
    float4 po;
    po.x = v.x + pb.x;
    po.y = v.y + pb.y;
    po.z = v.z + pb.z;
    po.w = v.w + pb.w;
    ((float4*)(pout + (size_t)row * C))[tid] = po;
  }
}

// ---------- batched transpose + fp32->bf16 cast: in (bz,R,Cin) -> out (bz,Cin,R) ----------
__global__ __launch_bounds__(256) void transpose_cast_kernel(
    const float* __restrict__ in, ushort_t* __restrict__ out, int R, int Cin) {
  __shared__ float tile[32][33];
  int bz = blockIdx.z;
  in += (size_t)bz * R * Cin;
  out += (size_t)bz * R * Cin;
  int c0 = blockIdx.x * 32, r0 = blockIdx.y * 32;
  int tx = threadIdx.x, ty = threadIdx.y;
  #pragma unroll
  for (int i = 0; i < 4; i++)
    tile[ty + 8 * i][tx] = in[(size_t)(r0 + ty + 8 * i) * Cin + c0 + tx];
  __syncthreads();
  #pragma unroll
  for (int i = 0; i < 4; i++)
    out[(size_t)(c0 + ty + 8 * i) * R + r0 + tx] = f2b(tile[tx][ty + 8 * i]);
}

// ---------- V transpose: QKV (4096,3072) bf16 -> Vt (B*H, 64, 2048) bf16 ----------
__global__ __launch_bounds__(256) void transpose_v_kernel(
    const ushort_t* __restrict__ qkv, ushort_t* __restrict__ vt) {
  __shared__ ushort_t tile[32][33];
  int bh = blockIdx.z;
  int b = bh >> 4, h = bh & 15;
  int d0 = blockIdx.x * 32, t0 = blockIdx.y * 32;
  int tx = threadIdx.x, ty = threadIdx.y;
  #pragma unroll
  for (int i = 0; i < 4; i++)
    tile[ty + 8 * i][tx] =
        qkv[(size_t)(b * 2048 + t0 + ty + 8 * i) * 3072 + 2048 + h * 64 + d0 + tx];
  __syncthreads();
  #pragma unroll
  for (int i = 0; i < 4; i++)
    vt[(size_t)(bh * 64 + d0 + ty + 8 * i) * 2048 + t0 + tx] = tile[tx][ty + 8 * i];
}

// ---------- GEMM: out(M,N) = A(M,K) @ Bt(N,K)^T, bf16 in, 128x128 tile, dbuf ----------
// 1D grid of BN*32*SK blocks with XCD-group swizzle: the 8 bn-tiles sharing an
// A-row-block get block ids congruent mod 8 -> same XCD -> A fetched once per
// XCD L2 instead of 8x from HBM. FLAGS: 1=relu, 2=bf16 out, 4=+bias, 8=+resid.
template <int BN, int N, int K, int FLAGS, int SK>
__global__ __launch_bounds__(256, 3) void gemm_bt_kernel(
    const ushort_t* __restrict__ A, const ushort_t* __restrict__ Bt,
    const float* __restrict__ bias, const float* __restrict__ resid,
    void* __restrict__ outv, float* __restrict__ pp0, float* __restrict__ pp1) {
  constexpr int KS = K / SK;             // K-span per block
  __shared__ ushort_t Als[2][128 * 32];
  __shared__ ushort_t Bls[2][128 * 32];
  int tid = threadIdx.x, w = tid >> 6, lane = tid & 63, quad = lane >> 4, l16 = lane & 15;
  // ---- XCD-group swizzle (fid mod 8 = XCD under round-robin dispatch) ----
  int fid = blockIdx.x;
  int bn_low = (fid >> 3) & 7;
  int meta = (fid & 7) | ((fid >> 6) << 3);
  int bm = meta & 31;                    // BM = 32 always (M = 4096)
  int high = meta >> 5;
  int bn, zz;
  if constexpr (SK > 1) { zz = high; bn = bn_low; }
  else { zz = 0; bn = bn_low + 8 * high; }
  int bn0 = bn * 128, bm0 = bm * 128;
  int koff = (SK > 1) ? zz * KS : 0;
  int wm = (w >> 1) * 64, wn = (w & 1) * 64;
  f32x4 acc[4][4];
  #pragma unroll
  for (int i = 0; i < 4; i++)
    #pragma unroll
    for (int j = 0; j < 4; j++) acc[i][j] = f32x4{0.f, 0.f, 0.f, 0.f};
  const ushort_t* Ag = A + (size_t)bm0 * K + koff;
  const ushort_t* Bg = Bt + (size_t)bn0 * K + koff;
  int lr = lane >> 2, lco = (lane & 3) * 8;
  auto stage = [&](int k0, int bi) {
    async16(Ag + (size_t)(w * 32 + lr) * K + k0 + lco, &Als[bi][w * 1024]);
    async16(Ag + (size_t)(w * 32 + 16 + lr) * K + k0 + lco, &Als[bi][w * 1024 + 512]);
    async16(Bg + (size_t)(w * 32 + lr) * K + k0 + lco, &Bls[bi][w * 1024]);
    async16(Bg + (size_t)(w * 32 + 16 + lr) * K + k0 + lco, &Bls[bi][w * 1024 + 512]);
  };
  stage(0, 0);
  int s = 0;
  for (int k0 = 0; k0 < KS; k0 += 32, s ^= 1) {
    __syncthreads();
    if (k0 + 32 < KS) stage(k0 + 32, s ^ 1);
    bf16x8 af[4], bf[4];
    #pragma unroll
    for (int i = 0; i < 4; i++)
      af[i] = *(const bf16x8*)&Als[s][(wm + i * 16 + l16) * 32 + quad * 8];
    #pragma unroll
    for (int j = 0; j < 4; j++)
      bf[j] = *(const bf16x8*)&Bls[s][(wn + j * 16 + l16) * 32 + quad * 8];
    #pragma unroll
    for (int i = 0; i < 4; i++)
      #pragma unroll
      for (int j = 0; j < 4; j++)
        acc[i][j] = __builtin_amdgcn_mfma_f32_16x16x32_bf16(af[i], bf[j], acc[i][j], 0, 0, 0);
  }
  float* pdst = nullptr;
  if constexpr (SK > 1) pdst = zz ? pp1 : pp0;
  #pragma unroll
  for (int i = 0; i < 4; i++)
    #pragma unroll
    for (int j = 0; j < 4; j++)
      #pragma unroll
      for (int r = 0; r < 4; r++) {
        int row = bm0 + wm + i * 16 + quad * 4 + r;
        int col = bn0 + wn + j * 16 + l16;
        float v = acc[i][j][r];
        if constexpr (SK > 1) {
          pdst[(size_t)row * N + col] = v;   // raw partial
        } else {
          if constexpr (FLAGS & 4) v += bias[col];
          if constexpr (FLAGS & 8) v += resid[(size_t)row * N + col];
          if constexpr (FLAGS & 1) v = fmaxf(v, 0.f);
          if constexpr ((FLAGS & 2) != 0)
            ((ushort_t*)outv)[(size_t)row * N + col] = f2b(v);
          else
            ((float*)outv)[(size_t)row * N + col] = v;
        }
      }
}

// ---------- GEMM 128x64 tile: occupancy variant for narrow-N / deep-K shapes ----
// Same m97 structure as gemm_bt_kernel but half the N-tile: 24 KB LDS, grid =
// 32 * (N/64) * SK blocks. Used where 128x128 leaves CUs idle:
//   Wo  (N=1024, SK=1):  512 blocks = 2/CU
//   FF2 (N=1024, SK=2): 1024 blocks = 4/CU, FLAGS|16 -> atomic accumulate
// Per wave: 64x32 output (acc[4][2]), 3 async16/iter.
// FLAGS: 1=relu, 2=bf16 out, 4=+bias, 8=+resid, 16=fp32 atomicAdd into outv
// (outv must be pre-seeded with bias+resid; both SK halves commute).
template <int N, int K, int FLAGS, int SK>
__global__ __launch_bounds__(256, 3) void gemm_bt64_kernel(
    const ushort_t* __restrict__ A, const ushort_t* __restrict__ Bt,
    const float* __restrict__ bias, const float* __restrict__ resid,
    void* __restrict__ outv, float* __restrict__ pp0, float* __restrict__ pp1) {
  constexpr int KS = K / SK;
  constexpr int NBM = 32;                // M = 4096 / 128
  constexpr int NBN = N / 64;
  constexpr int NWG = NBM * NBN * SK;    // must == gridDim.x, % 8 == 0
  __shared__ ushort_t Als[2][128 * 32];  // 16 KB
  __shared__ ushort_t Bls[2][64 * 32];   //  8 KB
  int tid = threadIdx.x, w = tid >> 6, lane = tid & 63, quad = lane >> 4, l16 = lane & 15;
  // XCD-chunked bijective swizzle: consecutive swz share bm -> A-panel stays
  // hot in the XCD's L2 while bn sweeps.
  int bid = blockIdx.x;
  int swz = (bid & 7) * (NWG / 8) + (bid >> 3);
  int z = 0;
  if constexpr (SK > 1) { z = swz / (NBM * NBN); swz -= z * (NBM * NBN); }
  int bm = swz / NBN, bn = swz - bm * NBN;
  int bm0 = bm * 128, bn0 = bn * 64;
  int koff = z * KS;
  int wm = (w >> 1) * 64, wn = (w & 1) * 32;
  f32x4 acc[4][2];
  #pragma unroll
  for (int i = 0; i < 4; i++)
    #pragma unroll
    for (int j = 0; j < 2; j++) acc[i][j] = f32x4{0.f, 0.f, 0.f, 0.f};
  const ushort_t* Ag = A + (size_t)bm0 * K + koff;
  const ushort_t* Bg = Bt + (size_t)bn0 * K + koff;
  int lr = lane >> 2, lco = (lane & 3) * 8;
  auto stage = [&](int k0, int bi) {
    async16(Ag + (size_t)(w * 32 + lr) * K + k0 + lco, &Als[bi][w * 1024]);
    async16(Ag + (size_t)(w * 32 + 16 + lr) * K + k0 + lco, &Als[bi][w * 1024 + 512]);
    async16(Bg + (size_t)(w * 16 + lr) * K + k0 + lco, &Bls[bi][w * 512]);
  };
  stage(0, 0);
  int s = 0;
  for (int k0 = 0; k0 < KS; k0 += 32, s ^= 1) {
    __syncthreads();
    if (k0 + 32 < KS) stage(k0 + 32, s ^ 1);
    bf16x8 af[4], bf[2];
    #pragma unroll
    for (int i = 0; i < 4; i++)
      af[i] = *(const bf16x8*)&Als[s][(wm + i * 16 + l16) * 32 + quad * 8];
    #pragma unroll
    for (int j = 0; j < 2; j++)
      bf[j] = *(const bf16x8*)&Bls[s][(wn + j * 16 + l16) * 32 + quad * 8];
    #pragma unroll
    for (int i = 0; i < 4; i++)
      #pragma unroll
      for (int j = 0; j < 2; j++)
        acc[i][j] = __builtin_amdgcn_mfma_f32_16x16x32_bf16(af[i], bf[j], acc[i][j], 0, 0, 0);
  }
  float* pdst = nullptr;
  if constexpr (SK > 1 && !(FLAGS & 16)) pdst = z ? pp1 : pp0;
  #pragma unroll
  for (int i = 0; i < 4; i++)
    #pragma unroll
    for (int j = 0; j < 2; j++)
      #pragma unroll
      for (int r = 0; r < 4; r++) {
        int row = bm0 + wm + i * 16 + quad * 4 + r;
        int col = bn0 + wn + j * 16 + l16;
        float v = acc[i][j][r];
        if constexpr ((FLAGS & 16) != 0) {
          __hip_atomic_fetch_add(&((float*)outv)[(size_t)row * N + col], v,
                                 __ATOMIC_RELAXED, __HIP_MEMORY_SCOPE_AGENT);
        } else if constexpr (SK > 1) {
          pdst[(size_t)row * N + col] = v;   // raw partial
        } else {
          if constexpr (FLAGS & 4) v += bias[col];
          if constexpr (FLAGS & 8) v += resid[(size_t)row * N + col];
          if constexpr (FLAGS & 1) v = fmaxf(v, 0.f);
          if constexpr ((FLAGS & 2) != 0)
            ((ushort_t*)outv)[(size_t)row * N + col] = f2b(v);
          else
            ((float*)outv)[(size_t)row * N + col] = v;
        }
      }
}

// ---------- causal flash attention: dbuf LDS staging + S^T softmax ----------
// 1024 blocks = 32 (b,h) x 32 q-blocks of 64 rows -> 4 blocks/CU.
__global__ __launch_bounds__(256, 4) void attn_kernel(
    const ushort_t* __restrict__ qkv, const ushort_t* __restrict__ vt,
    ushort_t* __restrict__ out) {
  const int T = 2048, CC = 3072;
  __shared__ ushort_t Kls[2][2 * 64 * 32];
  __shared__ ushort_t Vls[2][2 * 64 * 32];
  int fid = blockIdx.x;                       // 1024
  int bh = (fid & 7) * 4 + ((fid >> 3) & 3);  // XCD swizzle: 4 heads per XCD
  int qb = 31 - (fid >> 5);                   // longest q-blocks first
  int b = bh >> 4, h = bh & 15;
  int q0 = qb * 64;
  int tid = threadIdx.x, w = tid >> 6, lane = tid & 63, quad = lane >> 4, l16 = lane & 15;
  int srow = w * 16 + (lane >> 2);
  int sco = (lane & 3) * 8;
  const ushort_t* kg = qkv + (size_t)(b * T + srow) * CC + 1024 + h * 64 + sco;
  const ushort_t* vg = vt + (size_t)(bh * 64 + srow) * T + sco;
  int q0s = q0 + w * 16;
  int trow = q0s + l16;
  const ushort_t* qp = qkv + (size_t)(b * T + trow) * CC + h * 64 + quad * 8;
  bf16x8 aq[2] = { *(const bf16x8*)qp, *(const bf16x8*)(qp + 32) };
  f32x4 O[4];
  #pragma unroll
  for (int i = 0; i < 4; i++) O[i] = f32x4{0.f, 0.f, 0.f, 0.f};
  float mrun = -1e30f, lrun = 0.f;
  const float ksc = 0.03125f * 1.44269504f;  // C^-0.5 * log2(e)
  int src0 = (quad & 1) * 32 + l16;
  int src1 = src0 + 16;
  bool hiq = quad >= 2;
  auto stage = [&](int kb, int bi) {
    int s0 = kb * 64;
    async16(kg + (size_t)s0 * CC, &Kls[bi][w * 512]);
    async16(kg + (size_t)s0 * CC + 32, &Kls[bi][2048 + w * 512]);
    async16(vg + s0, &Vls[bi][w * 512]);
    async16(vg + s0 + 32, &Vls[bi][2048 + w * 512]);
  };
  stage(0, 0);
  for (int kb = 0; kb <= qb; kb++) {
    __syncthreads();
    if (kb < qb) stage(kb + 1, (kb + 1) & 1);
    int bi = kb & 1;
    int s0 = kb * 64;
    bf16x8 kfr[4][2], vfr[4][2];
    #pragma unroll
    for (int t = 0; t < 4; t++)
      #pragma unroll
      for (int ks = 0; ks < 2; ks++) {
        kfr[t][ks] = *(const bf16x8*)&Kls[bi][(ks * 64 + t * 16 + l16) * 32 + quad * 8];
        vfr[t][ks] = *(const bf16x8*)&Vls[bi][(ks * 64 + t * 16 + l16) * 32 + quad * 8];
      }
    f32x4 st[4];
    #pragma unroll
    for (int t = 0; t < 4; t++) {
      st[t] = f32x4{0.f, 0.f, 0.f, 0.f};
      #pragma unroll
      for (int ks = 0; ks < 2; ks++)
        st[t] = __builtin_amdgcn_mfma_f32_16x16x32_bf16(kfr[t][ks], aq[ks], st[t], 0, 0, 0);
    }
    float sv[4][4];
    float vmax = -1e30f;
    if (kb == qb) {
      #pragma unroll
      for (int t = 0; t < 4; t++)
        #pragma unroll
        for (int r = 0; r < 4; r++) {
          float sc = st[t][r] * ksc;
          int scol = s0 + t * 16 + quad * 4 + r;
          if (scol > trow) sc = -1e30f;
          sv[t][r] = sc;
          vmax = fmaxf(vmax, sc);
        }
    } else {
      #pragma unroll
      for (int t = 0; t < 4; t++)
        #pragma unroll
        for (int r = 0; r < 4; r++) {
          float sc = st[t][r] * ksc;
          sv[t][r] = sc;
          vmax = fmaxf(vmax, sc);
        }
    }
    vmax = fmaxf(vmax, __shfl_xor(vmax, 16));
    vmax = fmaxf(vmax, __shfl_xor(vmax, 32));
    float mnew = fmaxf(mrun, vmax);
    float alpha = __builtin_amdgcn_exp2f(mrun - mnew);
    mrun = mnew;
    float psum = 0.f;
    int pk[4][2];
    #pragma unroll
    for (int t = 0; t < 4; t++) {
      float p0 = __builtin_amdgcn_exp2f(sv[t][0] - mnew);
      float p1 = __builtin_amdgcn_exp2f(sv[t][1] - mnew);
      float p2 = __builtin_amdgcn_exp2f(sv[t][2] - mnew);
      float p3 = __builtin_amdgcn_exp2f(sv[t][3] - mnew);
      psum += (p0 + p1) + (p2 + p3);
      pk[t][0] = (int)((unsigned)f2b(p0) | ((unsigned)f2b(p1) << 16));
      pk[t][1] = (int)((unsigned)f2b(p2) | ((unsigned)f2b(p3) << 16));
    }
    psum += __shfl_xor(psum, 16);
    psum += __shfl_xor(psum, 32);
    lrun = lrun * alpha + psum;
    #pragma unroll
    for (int dt = 0; dt < 4; dt++) O[dt] *= alpha;
    #pragma unroll
    for (int g32 = 0; g32 < 2; g32++) {
      int t0 = 2 * g32, t1 = t0 + 1;
      int a0 = __shfl(pk[t0][0], src0), b0 = __shfl(pk[t1][0], src0);
      int a1 = __shfl(pk[t0][1], src0), b1 = __shfl(pk[t1][1], src0);
      int a2 = __shfl(pk[t0][0], src1), b2 = __shfl(pk[t1][0], src1);
      int a3 = __shfl(pk[t0][1], src1), b3 = __shfl(pk[t1][1], src1);
      union { int4 i; bf16x8 h; } u;
      u.i.x = hiq ? b0 : a0;
      u.i.y = hiq ? b1 : a1;
      u.i.z = hiq ? b2 : a2;
      u.i.w = hiq ? b3 : a3;
      #pragma unroll
      for (int dt = 0; dt < 4; dt++)
        O[dt] = __builtin_amdgcn_mfma_f32_16x16x32_bf16(vfr[dt][g32], u.h, O[dt], 0, 0, 0);
    }
  }
  float inv = 1.f / lrun;
  #pragma unroll
  for (int dt = 0; dt < 4; dt++) {
    ushort4 o;
    unsigned short* op = (unsigned short*)&o;
    #pragma unroll
    for (int r = 0; r < 4; r++) op[r] = f2b(O[dt][r] * inv);
    *(ushort4*)&out[(size_t)(b * T + trow) * 1024 + h * 64 + dt * 16 + quad * 4] = o;
  }
}

// ---------- host ----------
extern "C" void kernel_launch(void* const* d_in, const int* in_sizes, int n_in,
                              void* d_out, int out_size, void* d_ws, size_t ws_size,
                              hipStream_t stream) {
  const int B = 2, T = 2048, C = 1024, H = 16, D = 64, FF = 4096;
  const int M = B * T;  // 4096
  const float* x   = (const float*)d_in[0];
  const float* Wq  = (const float*)d_in[1];
  const float* Wk  = (const float*)d_in[2];
  const float* Wv  = (const float*)d_in[3];
  const float* Wo  = (const float*)d_in[4];
  const float* bo  = (const float*)d_in[5];
  const float* W1  = (const float*)d_in[6];
  const float* b1  = (const float*)d_in[7];
  const float* W2  = (const float*)d_in[8];
  const float* b2  = (const float*)d_in[9];
  const float* g1  = (const float*)d_in[10];
  const float* be1 = (const float*)d_in[11];
  const float* g2  = (const float*)d_in[12];
  const float* be2 = (const float*)d_in[13];
  float* out = (float*)d_out;

  char* ws = (char*)d_ws;
  size_t off = 0;
  auto alloc = [&](size_t bytes) {
    void* p = ws + off;
    off += (bytes + 255) & ~(size_t)255;
    return p;
  };
  ushort_t* qkvt = (ushort_t*)alloc((size_t)3 * C * C * 2);  // 6.29 MB
  ushort_t* wot  = (ushort_t*)alloc((size_t)C * C * 2);      // 2.10 MB
  ushort_t* w1t  = (ushort_t*)alloc((size_t)FF * C * 2);     // 8.39 MB
  ushort_t* w2t  = (ushort_t*)alloc((size_t)C * FF * 2);     // 8.39 MB
  ushort_t* hbuf = (ushort_t*)alloc((size_t)M * C * 2);      // 8.39 MB
  ushort_t* big  = (ushort_t*)alloc((size_t)M * FF * 2);     // 33.55 MB
  ushort_t* vtb  = (ushort_t*)alloc((size_t)M * C * 2);      // 8.39 MB
  ushort_t* aout = (ushort_t*)alloc((size_t)M * C * 2);      // 8.39 MB
  float*    x2   = (float*)alloc((size_t)M * C * 4);         // 16.78 MB

  dim3 tb(32, 8);
  transpose_cast_kernel<<<dim3(D / 32, C / 32, H), tb, 0, stream>>>(Wq, qkvt, C, D);
  transpose_cast_kernel<<<dim3(D / 32, C / 32, H), tb, 0, stream>>>(Wk, qkvt + (size_t)C * C, C, D);
  transpose_cast_kernel<<<dim3(D / 32, C / 32, H), tb, 0, stream>>>(Wv, qkvt + (size_t)2 * C * C, C, D);
  transpose_cast_kernel<<<dim3(C / 32, C / 32, 1), tb, 0, stream>>>(Wo, wot, C, C);
  transpose_cast_kernel<<<dim3(FF / 32, C / 32, 1), tb, 0, stream>>>(W1, w1t, C, FF);
  transpose_cast_kernel<<<dim3(C / 32, FF / 32, 1), tb, 0, stream>>>(W2, w2t, FF, C);
  ln_kernel<<<M, 256, 0, stream>>>(x, g1, be1, hbuf, nullptr, nullptr);
  // QKV = h @ Wqkv^T -> bf16  (768 blocks of 128^2 = 3/CU, XCD-grouped)
  gemm_bt_kernel<24, 3072, 1024, 2, 1><<<768, 256, 0, stream>>>(
      hbuf, qkvt, nullptr, nullptr, big, nullptr, nullptr);
  transpose_v_kernel<<<dim3(2, T / 32, B * H), tb, 0, stream>>>(big, vtb);
  attn_kernel<<<1024, 256, 0, stream>>>(big, vtb, aout);
  // x2 = attn @ Wo^T + bo + x (fp32)  (128x64 tiles: 512 blocks = 2/CU)
  gemm_bt64_kernel<1024, 1024, 4 | 8, 1><<<512, 256, 0, stream>>>(
      aout, wot, bo, x, x2, nullptr, nullptr);
  // ln2 + prefill out = x2 + b2 (seed for FF2's atomic accumulation)
  ln_kernel<<<M, 256, 0, stream>>>(x2, g2, be2, hbuf, b2, out);
  // ff1 = relu(h2 @ W1^T + b1) -> bf16  (1024 blocks of 128^2 = 4/CU)
  gemm_bt_kernel<32, 4096, 1024, 1 | 2 | 4, 1><<<1024, 256, 0, stream>>>(
      hbuf, w1t, b1, nullptr, big, nullptr, nullptr);
  // ff2 split-K=2 at 128x64 tiles (1024 blocks = 4/CU), atomic into out
  gemm_bt64_kernel<1024, 4096, 16, 2><<<1024, 256, 0, stream>>>(
      big, w2t, nullptr, nullptr, out, nullptr, nullptr);
}

// Round 6
// 364.237 us; speedup vs baseline: 1.0251x; 1.0064x over previous
//
#include <hip/hip_runtime.h>
#include <stdint.h>

typedef unsigned short ushort_t;
typedef __attribute__((ext_vector_type(8))) short bf16x8;   // 8 bf16 in 4 VGPRs
typedef __attribute__((ext_vector_type(4))) float f32x4;

// ---------- helpers ----------
__device__ __forceinline__ unsigned short f2b(float f) {
  unsigned u = __float_as_uint(f);
  u += 0x7fffu + ((u >> 16) & 1u);   // round-to-nearest-even
  return (unsigned short)(u >> 16);
}

__device__ __forceinline__ void async16(const void* g, void* l) {
  __builtin_amdgcn_global_load_lds(
      (const __attribute__((address_space(1))) void*)g,
      (__attribute__((address_space(3))) void*)l, 16, 0, 0);
}

// ---------- LayerNorm (fp32 in -> bf16 out), one block per row, C=1024 ----------
__global__ __launch_bounds__(256) void ln_kernel(
    const float* __restrict__ x, const float* __restrict__ g,
    const float* __restrict__ be, ushort_t* __restrict__ out) {
  const int C = 1024;
  int row = blockIdx.x;
  const float4* xr = (const float4*)(x + (size_t)row * C);
  int tid = threadIdx.x;
  float4 v = xr[tid];
  float s = v.x + v.y + v.z + v.w;
  float sq = v.x * v.x + v.y * v.y + v.z * v.z + v.w * v.w;
  #pragma unroll
  for (int off = 32; off > 0; off >>= 1) {
    s += __shfl_xor(s, off);
    sq += __shfl_xor(sq, off);
  }
  __shared__ float ss[4], ssq[4];
  int wv = tid >> 6;
  if ((tid & 63) == 0) { ss[wv] = s; ssq[wv] = sq; }
  __syncthreads();
  s = ss[0] + ss[1] + ss[2] + ss[3];
  sq = ssq[0] + ssq[1] + ssq[2] + ssq[3];
  float mu = s * (1.f / C);
  float var = sq * (1.f / C) - mu * mu;
  float rs = rsqrtf(var + 1e-5f);
  float4 gv = ((const float4*)g)[tid];
  float4 bv = ((const float4*)be)[tid];
  ushort4 o;
  o.x = f2b((v.x - mu) * rs * gv.x + bv.x);
  o.y = f2b((v.y - mu) * rs * gv.y + bv.y);
  o.z = f2b((v.z - mu) * rs * gv.z + bv.z);
  o.w = f2b((v.w - mu) * rs * gv.w + bv.w);
  ((ushort4*)(out + (size_t)row * C))[tid] = o;
}

// ---------- split-K final reduce: out = p0 + p1 + bias + resid (fp32), N=1024 ----------
__global__ __launch_bounds__(256) void reduce2_kernel(
    const float* __restrict__ p0, const float* __restrict__ p1,
    const float* __restrict__ bias, const float* __restrict__ resid,
    float* __restrict__ out) {
  int idx = blockIdx.x * 256 + threadIdx.x;      // float4 index
  float4 a = ((const float4*)p0)[idx];
  float4 b = ((const float4*)p1)[idx];
  float4 r = ((const float4*)resid)[idx];
  float4 bi = ((const float4*)bias)[idx & 255];  // 1024 floats = 256 float4 per row
  float4 o;
  o.x = a.x + b.x + r.x + bi.x;
  o.y = a.y + b.y + r.y + bi.y;
  o.z = a.z + b.z + r.z + bi.z;
  o.w = a.w + b.w + r.w + bi.w;
  ((float4*)out)[idx] = o;
}

// ---------- batched transpose + fp32->bf16 cast: in (bz,R,Cin) -> out (bz,Cin,R) ----------
__global__ __launch_bounds__(256) void transpose_cast_kernel(
    const float* __restrict__ in, ushort_t* __restrict__ out, int R, int Cin) {
  __shared__ float tile[32][33];
  int bz = blockIdx.z;
  in += (size_t)bz * R * Cin;
  out += (size_t)bz * R * Cin;
  int c0 = blockIdx.x * 32, r0 = blockIdx.y * 32;
  int tx = threadIdx.x, ty = threadIdx.y;
  #pragma unroll
  for (int i = 0; i < 4; i++)
    tile[ty + 8 * i][tx] = in[(size_t)(r0 + ty + 8 * i) * Cin + c0 + tx];
  __syncthreads();
  #pragma unroll
  for (int i = 0; i < 4; i++)
    out[(size_t)(c0 + ty + 8 * i) * R + r0 + tx] = f2b(tile[tx][ty + 8 * i]);
}

// ---------- fused Wq/Wk/Wv transpose+cast: one launch for all 3 (z = 48) ----------
__global__ __launch_bounds__(256) void transpose_cast_qkv_kernel(
    const float* __restrict__ wq, const float* __restrict__ wk,
    const float* __restrict__ wv, ushort_t* __restrict__ out) {
  __shared__ float tile[32][33];
  int bz = blockIdx.z;                 // 0..47: wsel*16 + head
  int wsel = bz >> 4, h = bz & 15;
  const float* in = (wsel == 0 ? wq : wsel == 1 ? wk : wv) + (size_t)h * 1024 * 64;
  ushort_t* o = out + (size_t)wsel * 1024 * 1024 + (size_t)h * 1024 * 64;
  int c0 = blockIdx.x * 32, r0 = blockIdx.y * 32;   // x: 64/32, y: 1024/32
  int tx = threadIdx.x, ty = threadIdx.y;
  #pragma unroll
  for (int i = 0; i < 4; i++)
    tile[ty + 8 * i][tx] = in[(size_t)(r0 + ty + 8 * i) * 64 + c0 + tx];
  __syncthreads();
  #pragma unroll
  for (int i = 0; i < 4; i++)
    o[(size_t)(c0 + ty + 8 * i) * 1024 + r0 + tx] = f2b(tile[tx][ty + 8 * i]);
}

// ---------- V transpose: QKV (4096,3072) bf16 -> Vt (B*H, 64, 2048) bf16 ----------
__global__ __launch_bounds__(256) void transpose_v_kernel(
    const ushort_t* __restrict__ qkv, ushort_t* __restrict__ vt) {
  __shared__ ushort_t tile[32][33];
  int bh = blockIdx.z;
  int b = bh >> 4, h = bh & 15;
  int d0 = blockIdx.x * 32, t0 = blockIdx.y * 32;
  int tx = threadIdx.x, ty = threadIdx.y;
  #pragma unroll
  for (int i = 0; i < 4; i++)
    tile[ty + 8 * i][tx] =
        qkv[(size_t)(b * 2048 + t0 + ty + 8 * i) * 3072 + 2048 + h * 64 + d0 + tx];
  __syncthreads();
  #pragma unroll
  for (int i = 0; i < 4; i++)
    vt[(size_t)(bh * 64 + d0 + ty + 8 * i) * 2048 + t0 + tx] = tile[tx][ty + 8 * i];
}

// ---------- GEMM: out(M,N) = A(M,K) @ Bt(N,K)^T, bf16 in, 128x128 tile, dbuf ----------
// 1D grid of BN*32*SK blocks with XCD-group swizzle. launch_bounds min-waves=4:
// 4 resident blocks/CU (vs 3) -> more inter-wave overlap to absorb the barrier
// drain (m114 mechanism). FLAGS: 1=relu, 2=bf16 out, 4=+bias, 8=+resid.
template <int BN, int N, int K, int FLAGS, int SK>
__global__ __launch_bounds__(256, 4) void gemm_bt_kernel(
    const ushort_t* __restrict__ A, const ushort_t* __restrict__ Bt,
    const float* __restrict__ bias, const float* __restrict__ resid,
    void* __restrict__ outv, float* __restrict__ pp0, float* __restrict__ pp1) {
  constexpr int KS = K / SK;             // K-span per block
  __shared__ ushort_t Als[2][128 * 32];
  __shared__ ushort_t Bls[2][128 * 32];
  int tid = threadIdx.x, w = tid >> 6, lane = tid & 63, quad = lane >> 4, l16 = lane & 15;
  // ---- XCD-group swizzle (fid mod 8 = XCD under round-robin dispatch) ----
  int fid = blockIdx.x;
  int bn_low = (fid >> 3) & 7;
  int meta = (fid & 7) | ((fid >> 6) << 3);
  int bm = meta & 31;                    // BM = 32 always (M = 4096)
  int high = meta >> 5;
  int bn, zz;
  if constexpr (SK > 1) { zz = high; bn = bn_low; }
  else { zz = 0; bn = bn_low + 8 * high; }
  int bn0 = bn * 128, bm0 = bm * 128;
  int koff = (SK > 1) ? zz * KS : 0;
  int wm = (w >> 1) * 64, wn = (w & 1) * 64;
  f32x4 acc[4][4];
  #pragma unroll
  for (int i = 0; i < 4; i++)
    #pragma unroll
    for (int j = 0; j < 4; j++) acc[i][j] = f32x4{0.f, 0.f, 0.f, 0.f};
  const ushort_t* Ag = A + (size_t)bm0 * K + koff;
  const ushort_t* Bg = Bt + (size_t)bn0 * K + koff;
  int lr = lane >> 2, lco = (lane & 3) * 8;
  auto stage = [&](int k0, int bi) {
    async16(Ag + (size_t)(w * 32 + lr) * K + k0 + lco, &Als[bi][w * 1024]);
    async16(Ag + (size_t)(w * 32 + 16 + lr) * K + k0 + lco, &Als[bi][w * 1024 + 512]);
    async16(Bg + (size_t)(w * 32 + lr) * K + k0 + lco, &Bls[bi][w * 1024]);
    async16(Bg + (size_t)(w * 32 + 16 + lr) * K + k0 + lco, &Bls[bi][w * 1024 + 512]);
  };
  stage(0, 0);
  int s = 0;
  for (int k0 = 0; k0 < KS; k0 += 32, s ^= 1) {
    __syncthreads();
    if (k0 + 32 < KS) stage(k0 + 32, s ^ 1);
    bf16x8 af[4], bf[4];
    #pragma unroll
    for (int i = 0; i < 4; i++)
      af[i] = *(const bf16x8*)&Als[s][(wm + i * 16 + l16) * 32 + quad * 8];
    #pragma unroll
    for (int j = 0; j < 4; j++)
      bf[j] = *(const bf16x8*)&Bls[s][(wn + j * 16 + l16) * 32 + quad * 8];
    #pragma unroll
    for (int i = 0; i < 4; i++)
      #pragma unroll
      for (int j = 0; j < 4; j++)
        acc[i][j] = __builtin_amdgcn_mfma_f32_16x16x32_bf16(af[i], bf[j], acc[i][j], 0, 0, 0);
  }
  float* pdst = nullptr;
  if constexpr (SK > 1) pdst = zz ? pp1 : pp0;
  #pragma unroll
  for (int i = 0; i < 4; i++)
    #pragma unroll
    for (int j = 0; j < 4; j++)
      #pragma unroll
      for (int r = 0; r < 4; r++) {
        int row = bm0 + wm + i * 16 + quad * 4 + r;
        int col = bn0 + wn + j * 16 + l16;
        float v = acc[i][j][r];
        if constexpr (SK > 1) {
          pdst[(size_t)row * N + col] = v;   // raw partial
        } else {
          if constexpr (FLAGS & 4) v += bias[col];
          if constexpr (FLAGS & 8) v += resid[(size_t)row * N + col];
          if constexpr (FLAGS & 1) v = fmaxf(v, 0.f);
          if constexpr ((FLAGS & 2) != 0)
            ((ushort_t*)outv)[(size_t)row * N + col] = f2b(v);
          else
            ((float*)outv)[(size_t)row * N + col] = v;
        }
      }
}

// ---------- GEMM 128x64 tile: occupancy variant for narrow-N / deep-K shapes ----
// Same m97 structure, half N-tile: 24 KB LDS. launch_bounds min-waves=4.
//   Wo  (N=1024, SK=1):  512 blocks
//   FF2 (N=1024, SK=2): 1024 blocks
// Per wave: 64x32 output (acc[4][2]), 3 async16/iter. FLAGS as above.
template <int N, int K, int FLAGS, int SK>
__global__ __launch_bounds__(256, 4) void gemm_bt64_kernel(
    const ushort_t* __restrict__ A, const ushort_t* __restrict__ Bt,
    const float* __restrict__ bias, const float* __restrict__ resid,
    void* __restrict__ outv, float* __restrict__ pp0, float* __restrict__ pp1) {
  constexpr int KS = K / SK;
  constexpr int NBM = 32;                // M = 4096 / 128
  constexpr int NBN = N / 64;
  constexpr int NWG = NBM * NBN * SK;    // must == gridDim.x, % 8 == 0
  __shared__ ushort_t Als[2][128 * 32];  // 16 KB
  __shared__ ushort_t Bls[2][64 * 32];   //  8 KB
  int tid = threadIdx.x, w = tid >> 6, lane = tid & 63, quad = lane >> 4, l16 = lane & 15;
  // XCD-chunked bijective swizzle: consecutive swz share bm -> A-panel stays
  // hot in the XCD's L2 while bn sweeps.
  int bid = blockIdx.x;
  int swz = (bid & 7) * (NWG / 8) + (bid >> 3);
  int z = 0;
  if constexpr (SK > 1) { z = swz / (NBM * NBN); swz -= z * (NBM * NBN); }
  int bm = swz / NBN, bn = swz - bm * NBN;
  int bm0 = bm * 128, bn0 = bn * 64;
  int koff = z * KS;
  int wm = (w >> 1) * 64, wn = (w & 1) * 32;
  f32x4 acc[4][2];
  #pragma unroll
  for (int i = 0; i < 4; i++)
    #pragma unroll
    for (int j = 0; j < 2; j++) acc[i][j] = f32x4{0.f, 0.f, 0.f, 0.f};
  const ushort_t* Ag = A + (size_t)bm0 * K + koff;
  const ushort_t* Bg = Bt + (size_t)bn0 * K + koff;
  int lr = lane >> 2, lco = (lane & 3) * 8;
  auto stage = [&](int k0, int bi) {
    async16(Ag + (size_t)(w * 32 + lr) * K + k0 + lco, &Als[bi][w * 1024]);
    async16(Ag + (size_t)(w * 32 + 16 + lr) * K + k0 + lco, &Als[bi][w * 1024 + 512]);
    async16(Bg + (size_t)(w * 16 + lr) * K + k0 + lco, &Bls[bi][w * 512]);
  };
  stage(0, 0);
  int s = 0;
  for (int k0 = 0; k0 < KS; k0 += 32, s ^= 1) {
    __syncthreads();
    if (k0 + 32 < KS) stage(k0 + 32, s ^ 1);
    bf16x8 af[4], bf[2];
    #pragma unroll
    for (int i = 0; i < 4; i++)
      af[i] = *(const bf16x8*)&Als[s][(wm + i * 16 + l16) * 32 + quad * 8];
    #pragma unroll
    for (int j = 0; j < 2; j++)
      bf[j] = *(const bf16x8*)&Bls[s][(wn + j * 16 + l16) * 32 + quad * 8];
    #pragma unroll
    for (int i = 0; i < 4; i++)
      #pragma unroll
      for (int j = 0; j < 2; j++)
        acc[i][j] = __builtin_amdgcn_mfma_f32_16x16x32_bf16(af[i], bf[j], acc[i][j], 0, 0, 0);
  }
  float* pdst = nullptr;
  if constexpr (SK > 1) pdst = z ? pp1 : pp0;
  #pragma unroll
  for (int i = 0; i < 4; i++)
    #pragma unroll
    for (int j = 0; j < 2; j++)
      #pragma unroll
      for (int r = 0; r < 4; r++) {
        int row = bm0 + wm + i * 16 + quad * 4 + r;
        int col = bn0 + wn + j * 16 + l16;
        float v = acc[i][j][r];
        if constexpr (SK > 1) {
          pdst[(size_t)row * N + col] = v;   // raw partial
        } else {
          if constexpr (FLAGS & 4) v += bias[col];
          if constexpr (FLAGS & 8) v += resid[(size_t)row * N + col];
          if constexpr (FLAGS & 1) v = fmaxf(v, 0.f);
          if constexpr ((FLAGS & 2) != 0)
            ((ushort_t*)outv)[(size_t)row * N + col] = f2b(v);
          else
            ((float*)outv)[(size_t)row * N + col] = v;
        }
      }
}

// ---------- causal flash attention: dbuf LDS staging + S^T softmax ----------
// 1024 blocks = 32 (b,h) x 32 q-blocks of 64 rows -> 4 blocks/CU.
// T5: setprio(1) around MFMA clusters (blocks sit at different phases -> the
// CU scheduler can prefer the MFMA-issuing wave; m191 mechanism).
__global__ __launch_bounds__(256, 4) void attn_kernel(
    const ushort_t* __restrict__ qkv, const ushort_t* __restrict__ vt,
    ushort_t* __restrict__ out) {
  const int T = 2048, CC = 3072;
  __shared__ ushort_t Kls[2][2 * 64 * 32];
  __shared__ ushort_t Vls[2][2 * 64 * 32];
  int fid = blockIdx.x;                       // 1024
  int bh = (fid & 7) * 4 + ((fid >> 3) & 3);  // XCD swizzle: 4 heads per XCD
  int qb = 31 - (fid >> 5);                   // longest q-blocks first
  int b = bh >> 4, h = bh & 15;
  int q0 = qb * 64;
  int tid = threadIdx.x, w = tid >> 6, lane = tid & 63, quad = lane >> 4, l16 = lane & 15;
  int srow = w * 16 + (lane >> 2);
  int sco = (lane & 3) * 8;
  const ushort_t* kg = qkv + (size_t)(b * T + srow) * CC + 1024 + h * 64 + sco;
  const ushort_t* vg = vt + (size_t)(bh * 64 + srow) * T + sco;
  int q0s = q0 + w * 16;
  int trow = q0s + l16;
  const ushort_t* qp = qkv + (size_t)(b * T + trow) * CC + h * 64 + quad * 8;
  bf16x8 aq[2] = { *(const bf16x8*)qp, *(const bf16x8*)(qp + 32) };
  f32x4 O[4];
  #pragma unroll
  for (int i = 0; i < 4; i++) O[i] = f32x4{0.f, 0.f, 0.f, 0.f};
  float mrun = -1e30f, lrun = 0.f;
  const float ksc = 0.03125f * 1.44269504f;  // C^-0.5 * log2(e)
  int src0 = (quad & 1) * 32 + l16;
  int src1 = src0 + 16;
  bool hiq = quad >= 2;
  auto stage = [&](int kb, int bi) {
    int s0 = kb * 64;
    async16(kg + (size_t)s0 * CC, &Kls[bi][w * 512]);
    async16(kg + (size_t)s0 * CC + 32, &Kls[bi][2048 + w * 512]);
    async16(vg + s0, &Vls[bi][w * 512]);
    async16(vg + s0 + 32, &Vls[bi][2048 + w * 512]);
  };
  stage(0, 0);
  for (int kb = 0; kb <= qb; kb++) {
    __syncthreads();
    if (kb < qb) stage(kb + 1, (kb + 1) & 1);
    int bi = kb & 1;
    int s0 = kb * 64;
    bf16x8 kfr[4][2], vfr[4][2];
    #pragma unroll
    for (int t = 0; t < 4; t++)
      #pragma unroll
      for (int ks = 0; ks < 2; ks++) {
        kfr[t][ks] = *(const bf16x8*)&Kls[bi][(ks * 64 + t * 16 + l16) * 32 + quad * 8];
        vfr[t][ks] = *(const bf16x8*)&Vls[bi][(ks * 64 + t * 16 + l16) * 32 + quad * 8];
      }
    f32x4 st[4];
    __builtin_amdgcn_s_setprio(1);
    #pragma unroll
    for (int t = 0; t < 4; t++) {
      st[t] = f32x4{0.f, 0.f, 0.f, 0.f};
      #pragma unroll
      for (int ks = 0; ks < 2; ks++)
        st[t] = __builtin_amdgcn_mfma_f32_16x16x32_bf16(kfr[t][ks], aq[ks], st[t], 0, 0, 0);
    }
    __builtin_amdgcn_s_setprio(0);
    float sv[4][4];
    float vmax = -1e30f;
    if (kb == qb) {
      #pragma unroll
      for (int t = 0; t < 4; t++)
        #pragma unroll
        for (int r = 0; r < 4; r++) {
          float sc = st[t][r] * ksc;
          int scol = s0 + t * 16 + quad * 4 + r;
          if (scol > trow) sc = -1e30f;
          sv[t][r] = sc;
          vmax = fmaxf(vmax, sc);
        }
    } else {
      #pragma unroll
      for (int t = 0; t < 4; t++)
        #pragma unroll
        for (int r = 0; r < 4; r++) {
          float sc = st[t][r] * ksc;
          sv[t][r] = sc;
          vmax = fmaxf(vmax, sc);
        }
    }
    vmax = fmaxf(vmax, __shfl_xor(vmax, 16));
    vmax = fmaxf(vmax, __shfl_xor(vmax, 32));
    float mnew = fmaxf(mrun, vmax);
    float alpha = __builtin_amdgcn_exp2f(mrun - mnew);
    mrun = mnew;
    float psum = 0.f;
    int pk[4][2];
    #pragma unroll
    for (int t = 0; t < 4; t++) {
      float p0 = __builtin_amdgcn_exp2f(sv[t][0] - mnew);
      float p1 = __builtin_amdgcn_exp2f(sv[t][1] - mnew);
      float p2 = __builtin_amdgcn_exp2f(sv[t][2] - mnew);
      float p3 = __builtin_amdgcn_exp2f(sv[t][3] - mnew);
      psum += (p0 + p1) + (p2 + p3);
      pk[t][0] = (int)((unsigned)f2b(p0) | ((unsigned)f2b(p1) << 16));
      pk[t][1] = (int)((unsigned)f2b(p2) | ((unsigned)f2b(p3) << 16));
    }
    psum += __shfl_xor(psum, 16);
    psum += __shfl_xor(psum, 32);
    lrun = lrun * alpha + psum;
    #pragma unroll
    for (int dt = 0; dt < 4; dt++) O[dt] *= alpha;
    #pragma unroll
    for (int g32 = 0; g32 < 2; g32++) {
      int t0 = 2 * g32, t1 = t0 + 1;
      int a0 = __shfl(pk[t0][0], src0), b0 = __shfl(pk[t1][0], src0);
      int a1 = __shfl(pk[t0][1], src0), b1 = __shfl(pk[t1][1], src0);
      int a2 = __shfl(pk[t0][0], src1), b2 = __shfl(pk[t1][0], src1);
      int a3 = __shfl(pk[t0][1], src1), b3 = __shfl(pk[t1][1], src1);
      union { int4 i; bf16x8 h; } u;
      u.i.x = hiq ? b0 : a0;
      u.i.y = hiq ? b1 : a1;
      u.i.z = hiq ? b2 : a2;
      u.i.w = hiq ? b3 : a3;
      __builtin_amdgcn_s_setprio(1);
      #pragma unroll
      for (int dt = 0; dt < 4; dt++)
        O[dt] = __builtin_amdgcn_mfma_f32_16x16x32_bf16(vfr[dt][g32], u.h, O[dt], 0, 0, 0);
      __builtin_amdgcn_s_setprio(0);
    }
  }
  float inv = 1.f / lrun;
  #pragma unroll
  for (int dt = 0; dt < 4; dt++) {
    ushort4 o;
    unsigned short* op = (unsigned short*)&o;
    #pragma unroll
    for (int r = 0; r < 4; r++) op[r] = f2b(O[dt][r] * inv);
    *(ushort4*)&out[(size_t)(b * T + trow) * 1024 + h * 64 + dt * 16 + quad * 4] = o;
  }
}

// ---------- host ----------
extern "C" void kernel_launch(void* const* d_in, const int* in_sizes, int n_in,
                              void* d_out, int out_size, void* d_ws, size_t ws_size,
                              hipStream_t stream) {
  const int B = 2, T = 2048, C = 1024, H = 16, D = 64, FF = 4096;
  const int M = B * T;  // 4096
  const float* x   = (const float*)d_in[0];
  const float* Wq  = (const float*)d_in[1];
  const float* Wk  = (const float*)d_in[2];
  const float* Wv  = (const float*)d_in[3];
  const float* Wo  = (const float*)d_in[4];
  const float* bo  = (const float*)d_in[5];
  const float* W1  = (const float*)d_in[6];
  const float* b1  = (const float*)d_in[7];
  const float* W2  = (const float*)d_in[8];
  const float* b2  = (const float*)d_in[9];
  const float* g1  = (const float*)d_in[10];
  const float* be1 = (const float*)d_in[11];
  const float* g2  = (const float*)d_in[12];
  const float* be2 = (const float*)d_in[13];
  float* out = (float*)d_out;

  char* ws = (char*)d_ws;
  size_t off = 0;
  auto alloc = [&](size_t bytes) {
    void* p = ws + off;
    off += (bytes + 255) & ~(size_t)255;
    return p;
  };
  // NOTE: split-K partial buffers alias dead regions (layout-dependent!):
  //   pf0 = vtb (spans vtb+aout, dead after Wo gemm)  = M*C floats
  //   pf1 = qkvt (spans qkvt+wot+w1t, dead after ff1) = M*C floats
  ushort_t* qkvt = (ushort_t*)alloc((size_t)3 * C * C * 2);  // 6.29 MB
  ushort_t* wot  = (ushort_t*)alloc((size_t)C * C * 2);      // 2.10 MB
  ushort_t* w1t  = (ushort_t*)alloc((size_t)FF * C * 2);     // 8.39 MB
  ushort_t* w2t  = (ushort_t*)alloc((size_t)C * FF * 2);     // 8.39 MB
  ushort_t* hbuf = (ushort_t*)alloc((size_t)M * C * 2);      // 8.39 MB
  ushort_t* big  = (ushort_t*)alloc((size_t)M * FF * 2);     // 33.55 MB
  ushort_t* vtb  = (ushort_t*)alloc((size_t)M * C * 2);      // 8.39 MB
  ushort_t* aout = (ushort_t*)alloc((size_t)M * C * 2);      // 8.39 MB
  float*    x2   = (float*)alloc((size_t)M * C * 4);         // 16.78 MB
  float* pf0 = (float*)vtb;    // 16.78 MB span (vtb+aout)
  float* pf1 = (float*)qkvt;   // 16.78 MB span (qkvt+wot+w1t)

  dim3 tb(32, 8);
  transpose_cast_qkv_kernel<<<dim3(D / 32, C / 32, 3 * H), tb, 0, stream>>>(
      Wq, Wk, Wv, qkvt);
  transpose_cast_kernel<<<dim3(C / 32, C / 32, 1), tb, 0, stream>>>(Wo, wot, C, C);
  transpose_cast_kernel<<<dim3(FF / 32, C / 32, 1), tb, 0, stream>>>(W1, w1t, C, FF);
  transpose_cast_kernel<<<dim3(C / 32, FF / 32, 1), tb, 0, stream>>>(W2, w2t, FF, C);
  ln_kernel<<<M, 256, 0, stream>>>(x, g1, be1, hbuf);
  // QKV = h @ Wqkv^T -> bf16  (768 blocks of 128^2 = 3/CU, XCD-grouped)
  gemm_bt_kernel<24, 3072, 1024, 2, 1><<<768, 256, 0, stream>>>(
      hbuf, qkvt, nullptr, nullptr, big, nullptr, nullptr);
  transpose_v_kernel<<<dim3(2, T / 32, B * H), tb, 0, stream>>>(big, vtb);
  attn_kernel<<<1024, 256, 0, stream>>>(big, vtb, aout);
  // x2 = attn @ Wo^T + bo + x (fp32)  (128x64 tiles: 512 blocks = 2/CU)
  gemm_bt64_kernel<1024, 1024, 4 | 8, 1><<<512, 256, 0, stream>>>(
      aout, wot, bo, x, x2, nullptr, nullptr);
  ln_kernel<<<M, 256, 0, stream>>>(x2, g2, be2, hbuf);
  // ff1 = relu(h2 @ W1^T + b1) -> bf16  (1024 blocks of 128^2 = 4/CU)
  gemm_bt_kernel<32, 4096, 1024, 1 | 2 | 4, 1><<<1024, 256, 0, stream>>>(
      hbuf, w1t, b1, nullptr, big, nullptr, nullptr);
  // ff2 split-K=2 at 128x64 tiles (1024 blocks = 4/CU), then reduce
  gemm_bt64_kernel<1024, 4096, 0, 2><<<1024, 256, 0, stream>>>(
      big, w2t, nullptr, nullptr, nullptr, pf0, pf1);
  reduce2_kernel<<<M * C / 1024, 256, 0, stream>>>(pf0, pf1, b2, x2, out);
}

// Round 8
// 360.449 us; speedup vs baseline: 1.0359x; 1.0105x over previous
//
#include <hip/hip_runtime.h>
#include <stdint.h>

typedef unsigned short ushort_t;
typedef __attribute__((ext_vector_type(8))) short bf16x8;   // 8 bf16 in 4 VGPRs
typedef __attribute__((ext_vector_type(4))) float f32x4;

// ---------- helpers ----------
__device__ __forceinline__ unsigned short f2b(float f) {
  unsigned u = __float_as_uint(f);
  u += 0x7fffu + ((u >> 16) & 1u);   // round-to-nearest-even
  return (unsigned short)(u >> 16);
}

__device__ __forceinline__ void async16(const void* g, void* l) {
  __builtin_amdgcn_global_load_lds(
      (const __attribute__((address_space(1))) void*)g,
      (__attribute__((address_space(3))) void*)l, 16, 0, 0);
}

// ---------- LayerNorm (fp32 in -> bf16 out), one block per row, C=1024 ----------
__global__ __launch_bounds__(256) void ln_kernel(
    const float* __restrict__ x, const float* __restrict__ g,
    const float* __restrict__ be, ushort_t* __restrict__ out) {
  const int C = 1024;
  int row = blockIdx.x;
  const float4* xr = (const float4*)(x + (size_t)row * C);
  int tid = threadIdx.x;
  float4 v = xr[tid];
  float s = v.x + v.y + v.z + v.w;
  float sq = v.x * v.x + v.y * v.y + v.z * v.z + v.w * v.w;
  #pragma unroll
  for (int off = 32; off > 0; off >>= 1) {
    s += __shfl_xor(s, off);
    sq += __shfl_xor(sq, off);
  }
  __shared__ float ss[4], ssq[4];
  int wv = tid >> 6;
  if ((tid & 63) == 0) { ss[wv] = s; ssq[wv] = sq; }
  __syncthreads();
  s = ss[0] + ss[1] + ss[2] + ss[3];
  sq = ssq[0] + ssq[1] + ssq[2] + ssq[3];
  float mu = s * (1.f / C);
  float var = sq * (1.f / C) - mu * mu;
  float rs = rsqrtf(var + 1e-5f);
  float4 gv = ((const float4*)g)[tid];
  float4 bv = ((const float4*)be)[tid];
  ushort4 o;
  o.x = f2b((v.x - mu) * rs * gv.x + bv.x);
  o.y = f2b((v.y - mu) * rs * gv.y + bv.y);
  o.z = f2b((v.z - mu) * rs * gv.z + bv.z);
  o.w = f2b((v.w - mu) * rs * gv.w + bv.w);
  ((ushort4*)(out + (size_t)row * C))[tid] = o;
}

// ---------- split-K final reduce: out = p0 + p1 + bias + resid (fp32), N=1024 ----------
__global__ __launch_bounds__(256) void reduce2_kernel(
    const float* __restrict__ p0, const float* __restrict__ p1,
    const float* __restrict__ bias, const float* __restrict__ resid,
    float* __restrict__ out) {
  int idx = blockIdx.x * 256 + threadIdx.x;      // float4 index
  float4 a = ((const float4*)p0)[idx];
  float4 b = ((const float4*)p1)[idx];
  float4 r = ((const float4*)resid)[idx];
  float4 bi = ((const float4*)bias)[idx & 255];  // 1024 floats = 256 float4 per row
  float4 o;
  o.x = a.x + b.x + r.x + bi.x;
  o.y = a.y + b.y + r.y + bi.y;
  o.z = a.z + b.z + r.z + bi.z;
  o.w = a.w + b.w + r.w + bi.w;
  ((float4*)out)[idx] = o;
}

// ---------- fused weight transpose+cast: ALL weights in one launch ----------
// Flat 12288-block grid, segment-decoded:
//   [0,3072):   Wq/Wk/Wv per-head (R=1024, Cin=64), 48 heads x 2 x-tiles x 32 y
//   [3072,4096): Wo  (R=1024, Cin=1024)
//   [4096,8192): W1  (R=1024, Cin=4096)
//   [8192,12288): W2 (R=4096, Cin=1024)
// Each block: standard 32x32 tile transpose, fp32 -> bf16.
__global__ __launch_bounds__(256) void transpose_all_kernel(
    const float* __restrict__ Wq, const float* __restrict__ Wk,
    const float* __restrict__ Wv, const float* __restrict__ Wo,
    const float* __restrict__ W1, const float* __restrict__ W2,
    ushort_t* __restrict__ qkvt, ushort_t* __restrict__ wot,
    ushort_t* __restrict__ w1t, ushort_t* __restrict__ w2t) {
  int bid = blockIdx.x;
  const float* in;
  ushort_t* out;
  int R, Cin, bx, by;
  if (bid < 3072) {
    int z = bid >> 6, rem = bid & 63;
    bx = rem & 1; by = rem >> 1;          // x: 64/32=2, y: 1024/32=32
    int wsel = z >> 4, h = z & 15;
    in = (wsel == 0 ? Wq : wsel == 1 ? Wk : Wv) + (size_t)h * 1024 * 64;
    out = qkvt + (size_t)wsel * 1024 * 1024 + (size_t)h * 1024 * 64;
    R = 1024; Cin = 64;
  } else if (bid < 4096) {
    int rem = bid - 3072;
    bx = rem & 31; by = rem >> 5;
    in = Wo; out = wot; R = 1024; Cin = 1024;
  } else if (bid < 8192) {
    int rem = bid - 4096;
    bx = rem & 127; by = rem >> 7;
    in = W1; out = w1t; R = 1024; Cin = 4096;
  } else {
    int rem = bid - 8192;
    bx = rem & 31; by = rem >> 5;
    in = W2; out = w2t; R = 4096; Cin = 1024;
  }
  __shared__ float tile[32][33];
  int c0 = bx * 32, r0 = by * 32;
  int tx = threadIdx.x, ty = threadIdx.y;
  #pragma unroll
  for (int i = 0; i < 4; i++)
    tile[ty + 8 * i][tx] = in[(size_t)(r0 + ty + 8 * i) * Cin + c0 + tx];
  __syncthreads();
  #pragma unroll
  for (int i = 0; i < 4; i++)
    out[(size_t)(c0 + ty + 8 * i) * R + r0 + tx] = f2b(tile[tx][ty + 8 * i]);
}

// ---------- V transpose: QKV (4096,3072) bf16 -> Vt (B*H, 64, 2048) bf16 ----------
__global__ __launch_bounds__(256) void transpose_v_kernel(
    const ushort_t* __restrict__ qkv, ushort_t* __restrict__ vt) {
  __shared__ ushort_t tile[32][33];
  int bh = blockIdx.z;
  int b = bh >> 4, h = bh & 15;
  int d0 = blockIdx.x * 32, t0 = blockIdx.y * 32;
  int tx = threadIdx.x, ty = threadIdx.y;
  #pragma unroll
  for (int i = 0; i < 4; i++)
    tile[ty + 8 * i][tx] =
        qkv[(size_t)(b * 2048 + t0 + ty + 8 * i) * 3072 + 2048 + h * 64 + d0 + tx];
  __syncthreads();
  #pragma unroll
  for (int i = 0; i < 4; i++)
    vt[(size_t)(bh * 64 + d0 + ty + 8 * i) * 2048 + t0 + tx] = tile[tx][ty + 8 * i];
}

// ---------- GEMM: out(M,N) = A(M,K) @ Bt(N,K)^T, bf16 in, 128x128 tile, dbuf ----------
// 1D grid of BN*32*SK blocks with XCD-group swizzle: the 8 bn-tiles sharing an
// A-row-block get block ids congruent mod 8 -> same XCD -> A fetched once per
// XCD L2 instead of 8x from HBM. FLAGS: 1=relu, 2=bf16 out, 4=+bias, 8=+resid.
template <int BN, int N, int K, int FLAGS, int SK>
__global__ __launch_bounds__(256, 3) void gemm_bt_kernel(
    const ushort_t* __restrict__ A, const ushort_t* __restrict__ Bt,
    const float* __restrict__ bias, const float* __restrict__ resid,
    void* __restrict__ outv, float* __restrict__ pp0, float* __restrict__ pp1) {
  constexpr int KS = K / SK;             // K-span per block
  __shared__ ushort_t Als[2][128 * 32];
  __shared__ ushort_t Bls[2][128 * 32];
  int tid = threadIdx.x, w = tid >> 6, lane = tid & 63, quad = lane >> 4, l16 = lane & 15;
  // ---- XCD-group swizzle (fid mod 8 = XCD under round-robin dispatch) ----
  int fid = blockIdx.x;
  int bn_low = (fid >> 3) & 7;
  int meta = (fid & 7) | ((fid >> 6) << 3);
  int bm = meta & 31;                    // BM = 32 always (M = 4096)
  int high = meta >> 5;
  int bn, zz;
  if constexpr (SK > 1) { zz = high; bn = bn_low; }
  else { zz = 0; bn = bn_low + 8 * high; }
  int bn0 = bn * 128, bm0 = bm * 128;
  int koff = (SK > 1) ? zz * KS : 0;
  int wm = (w >> 1) * 64, wn = (w & 1) * 64;
  f32x4 acc[4][4];
  #pragma unroll
  for (int i = 0; i < 4; i++)
    #pragma unroll
    for (int j = 0; j < 4; j++) acc[i][j] = f32x4{0.f, 0.f, 0.f, 0.f};
  const ushort_t* Ag = A + (size_t)bm0 * K + koff;
  const ushort_t* Bg = Bt + (size_t)bn0 * K + koff;
  int lr = lane >> 2, lco = (lane & 3) * 8;
  auto stage = [&](int k0, int bi) {
    async16(Ag + (size_t)(w * 32 + lr) * K + k0 + lco, &Als[bi][w * 1024]);
    async16(Ag + (size_t)(w * 32 + 16 + lr) * K + k0 + lco, &Als[bi][w * 1024 + 512]);
    async16(Bg + (size_t)(w * 32 + lr) * K + k0 + lco, &Bls[bi][w * 1024]);
    async16(Bg + (size_t)(w * 32 + 16 + lr) * K + k0 + lco, &Bls[bi][w * 1024 + 512]);
  };
  stage(0, 0);
  int s = 0;
  for (int k0 = 0; k0 < KS; k0 += 32, s ^= 1) {
    __syncthreads();
    if (k0 + 32 < KS) stage(k0 + 32, s ^ 1);
    bf16x8 af[4], bf[4];
    #pragma unroll
    for (int i = 0; i < 4; i++)
      af[i] = *(const bf16x8*)&Als[s][(wm + i * 16 + l16) * 32 + quad * 8];
    #pragma unroll
    for (int j = 0; j < 4; j++)
      bf[j] = *(const bf16x8*)&Bls[s][(wn + j * 16 + l16) * 32 + quad * 8];
    #pragma unroll
    for (int i = 0; i < 4; i++)
      #pragma unroll
      for (int j = 0; j < 4; j++)
        acc[i][j] = __builtin_amdgcn_mfma_f32_16x16x32_bf16(af[i], bf[j], acc[i][j], 0, 0, 0);
  }
  float* pdst = nullptr;
  if constexpr (SK > 1) pdst = zz ? pp1 : pp0;
  #pragma unroll
  for (int i = 0; i < 4; i++)
    #pragma unroll
    for (int j = 0; j < 4; j++)
      #pragma unroll
      for (int r = 0; r < 4; r++) {
        int row = bm0 + wm + i * 16 + quad * 4 + r;
        int col = bn0 + wn + j * 16 + l16;
        float v = acc[i][j][r];
        if constexpr (SK > 1) {
          pdst[(size_t)row * N + col] = v;   // raw partial
        } else {
          if constexpr (FLAGS & 4) v += bias[col];
          if constexpr (FLAGS & 8) v += resid[(size_t)row * N + col];
          if constexpr (FLAGS & 1) v = fmaxf(v, 0.f);
          if constexpr ((FLAGS & 2) != 0)
            ((ushort_t*)outv)[(size_t)row * N + col] = f2b(v);
          else
            ((float*)outv)[(size_t)row * N + col] = v;
        }
      }
}

// ---------- GEMM 128x64 tile: occupancy variant for narrow-N / deep-K shapes ----
// Same m97 structure as gemm_bt_kernel but half the N-tile: 24 KB LDS, grid =
// 32 * (N/64) * SK blocks. Used where 128x128 leaves CUs idle:
//   Wo  (N=1024, SK=1):  512 blocks = 2/CU
//   FF2 (N=1024, SK=2): 1024 blocks = 4/CU
// Per wave: 64x32 output (acc[4][2]), 3 async16/iter. FLAGS as above.
template <int N, int K, int FLAGS, int SK>
__global__ __launch_bounds__(256, 3) void gemm_bt64_kernel(
    const ushort_t* __restrict__ A, const ushort_t* __restrict__ Bt,
    const float* __restrict__ bias, const float* __restrict__ resid,
    void* __restrict__ outv, float* __restrict__ pp0, float* __restrict__ pp1) {
  constexpr int KS = K / SK;
  constexpr int NBM = 32;                // M = 4096 / 128
  constexpr int NBN = N / 64;
  constexpr int NWG = NBM * NBN * SK;    // must == gridDim.x, % 8 == 0
  __shared__ ushort_t Als[2][128 * 32];  // 16 KB
  __shared__ ushort_t Bls[2][64 * 32];   //  8 KB
  int tid = threadIdx.x, w = tid >> 6, lane = tid & 63, quad = lane >> 4, l16 = lane & 15;
  // XCD-chunked bijective swizzle: consecutive swz share bm -> A-panel stays
  // hot in the XCD's L2 while bn sweeps.
  int bid = blockIdx.x;
  int swz = (bid & 7) * (NWG / 8) + (bid >> 3);
  int z = 0;
  if constexpr (SK > 1) { z = swz / (NBM * NBN); swz -= z * (NBM * NBN); }
  int bm = swz / NBN, bn = swz - bm * NBN;
  int bm0 = bm * 128, bn0 = bn * 64;
  int koff = z * KS;
  int wm = (w >> 1) * 64, wn = (w & 1) * 32;
  f32x4 acc[4][2];
  #pragma unroll
  for (int i = 0; i < 4; i++)
    #pragma unroll
    for (int j = 0; j < 2; j++) acc[i][j] = f32x4{0.f, 0.f, 0.f, 0.f};
  const ushort_t* Ag = A + (size_t)bm0 * K + koff;
  const ushort_t* Bg = Bt + (size_t)bn0 * K + koff;
  int lr = lane >> 2, lco = (lane & 3) * 8;
  auto stage = [&](int k0, int bi) {
    async16(Ag + (size_t)(w * 32 + lr) * K + k0 + lco, &Als[bi][w * 1024]);
    async16(Ag + (size_t)(w * 32 + 16 + lr) * K + k0 + lco, &Als[bi][w * 1024 + 512]);
    async16(Bg + (size_t)(w * 16 + lr) * K + k0 + lco, &Bls[bi][w * 512]);
  };
  stage(0, 0);
  int s = 0;
  for (int k0 = 0; k0 < KS; k0 += 32, s ^= 1) {
    __syncthreads();
    if (k0 + 32 < KS) stage(k0 + 32, s ^ 1);
    bf16x8 af[4], bf[2];
    #pragma unroll
    for (int i = 0; i < 4; i++)
      af[i] = *(const bf16x8*)&Als[s][(wm + i * 16 + l16) * 32 + quad * 8];
    #pragma unroll
    for (int j = 0; j < 2; j++)
      bf[j] = *(const bf16x8*)&Bls[s][(wn + j * 16 + l16) * 32 + quad * 8];
    #pragma unroll
    for (int i = 0; i < 4; i++)
      #pragma unroll
      for (int j = 0; j < 2; j++)
        acc[i][j] = __builtin_amdgcn_mfma_f32_16x16x32_bf16(af[i], bf[j], acc[i][j], 0, 0, 0);
  }
  float* pdst = nullptr;
  if constexpr (SK > 1) pdst = z ? pp1 : pp0;
  #pragma unroll
  for (int i = 0; i < 4; i++)
    #pragma unroll
    for (int j = 0; j < 2; j++)
      #pragma unroll
      for (int r = 0; r < 4; r++) {
        int row = bm0 + wm + i * 16 + quad * 4 + r;
        int col = bn0 + wn + j * 16 + l16;
        float v = acc[i][j][r];
        if constexpr (SK > 1) {
          pdst[(size_t)row * N + col] = v;   // raw partial
        } else {
          if constexpr (FLAGS & 4) v += bias[col];
          if constexpr (FLAGS & 8) v += resid[(size_t)row * N + col];
          if constexpr (FLAGS & 1) v = fmaxf(v, 0.f);
          if constexpr ((FLAGS & 2) != 0)
            ((ushort_t*)outv)[(size_t)row * N + col] = f2b(v);
          else
            ((float*)outv)[(size_t)row * N + col] = v;
        }
      }
}

// ---------- causal flash attention: dbuf LDS staging + S^T softmax ----------
// 1024 blocks = 32 (b,h) x 32 q-blocks of 64 rows -> 4 blocks/CU.
__global__ __launch_bounds__(256, 4) void attn_kernel(
    const ushort_t* __restrict__ qkv, const ushort_t* __restrict__ vt,
    ushort_t* __restrict__ out) {
  const int T = 2048, CC = 3072;
  __shared__ ushort_t Kls[2][2 * 64 * 32];
  __shared__ ushort_t Vls[2][2 * 64 * 32];
  int fid = blockIdx.x;                       // 1024
  int bh = (fid & 7) * 4 + ((fid >> 3) & 3);  // XCD swizzle: 4 heads per XCD
  int qb = 31 - (fid >> 5);                   // longest q-blocks first
  int b = bh >> 4, h = bh & 15;
  int q0 = qb * 64;
  int tid = threadIdx.x, w = tid >> 6, lane = tid & 63, quad = lane >> 4, l16 = lane & 15;
  int srow = w * 16 + (lane >> 2);
  int sco = (lane & 3) * 8;
  const ushort_t* kg = qkv + (size_t)(b * T + srow) * CC + 1024 + h * 64 + sco;
  const ushort_t* vg = vt + (size_t)(bh * 64 + srow) * T + sco;
  int q0s = q0 + w * 16;
  int trow = q0s + l16;
  const ushort_t* qp = qkv + (size_t)(b * T + trow) * CC + h * 64 + quad * 8;
  bf16x8 aq[2] = { *(const bf16x8*)qp, *(const bf16x8*)(qp + 32) };
  f32x4 O[4];
  #pragma unroll
  for (int i = 0; i < 4; i++) O[i] = f32x4{0.f, 0.f, 0.f, 0.f};
  float mrun = -1e30f, lrun = 0.f;
  const float ksc = 0.03125f * 1.44269504f;  // C^-0.5 * log2(e)
  int src0 = (quad & 1) * 32 + l16;
  int src1 = src0 + 16;
  bool hiq = quad >= 2;
  auto stage = [&](int kb, int bi) {
    int s0 = kb * 64;
    async16(kg + (size_t)s0 * CC, &Kls[bi][w * 512]);
    async16(kg + (size_t)s0 * CC + 32, &Kls[bi][2048 + w * 512]);
    async16(vg + s0, &Vls[bi][w * 512]);
    async16(vg + s0 + 32, &Vls[bi][2048 + w * 512]);
  };
  stage(0, 0);
  for (int kb = 0; kb <= qb; kb++) {
    __syncthreads();
    if (kb < qb) stage(kb + 1, (kb + 1) & 1);
    int bi = kb & 1;
    int s0 = kb * 64;
    bf16x8 kfr[4][2], vfr[4][2];
    #pragma unroll
    for (int t = 0; t < 4; t++)
      #pragma unroll
      for (int ks = 0; ks < 2; ks++) {
        kfr[t][ks] = *(const bf16x8*)&Kls[bi][(ks * 64 + t * 16 + l16) * 32 + quad * 8];
        vfr[t][ks] = *(const bf16x8*)&Vls[bi][(ks * 64 + t * 16 + l16) * 32 + quad * 8];
      }
    f32x4 st[4];
    #pragma unroll
    for (int t = 0; t < 4; t++) {
      st[t] = f32x4{0.f, 0.f, 0.f, 0.f};
      #pragma unroll
      for (int ks = 0; ks < 2; ks++)
        st[t] = __builtin_amdgcn_mfma_f32_16x16x32_bf16(kfr[t][ks], aq[ks], st[t], 0, 0, 0);
    }
    float sv[4][4];
    float vmax = -1e30f;
    if (kb == qb) {
      #pragma unroll
      for (int t = 0; t < 4; t++)
        #pragma unroll
        for (int r = 0; r < 4; r++) {
          float sc = st[t][r] * ksc;
          int scol = s0 + t * 16 + quad * 4 + r;
          if (scol > trow) sc = -1e30f;
          sv[t][r] = sc;
          vmax = fmaxf(vmax, sc);
        }
    } else {
      #pragma unroll
      for (int t = 0; t < 4; t++)
        #pragma unroll
        for (int r = 0; r < 4; r++) {
          float sc = st[t][r] * ksc;
          sv[t][r] = sc;
          vmax = fmaxf(vmax, sc);
        }
    }
    vmax = fmaxf(vmax, __shfl_xor(vmax, 16));
    vmax = fmaxf(vmax, __shfl_xor(vmax, 32));
    float mnew = fmaxf(mrun, vmax);
    float alpha = __builtin_amdgcn_exp2f(mrun - mnew);
    mrun = mnew;
    float psum = 0.f;
    int pk[4][2];
    #pragma unroll
    for (int t = 0; t < 4; t++) {
      float p0 = __builtin_amdgcn_exp2f(sv[t][0] - mnew);
      float p1 = __builtin_amdgcn_exp2f(sv[t][1] - mnew);
      float p2 = __builtin_amdgcn_exp2f(sv[t][2] - mnew);
      float p3 = __builtin_amdgcn_exp2f(sv[t][3] - mnew);
      psum += (p0 + p1) + (p2 + p3);
      pk[t][0] = (int)((unsigned)f2b(p0) | ((unsigned)f2b(p1) << 16));
      pk[t][1] = (int)((unsigned)f2b(p2) | ((unsigned)f2b(p3) << 16));
    }
    psum += __shfl_xor(psum, 16);
    psum += __shfl_xor(psum, 32);
    lrun = lrun * alpha + psum;
    #pragma unroll
    for (int dt = 0; dt < 4; dt++) O[dt] *= alpha;
    #pragma unroll
    for (int g32 = 0; g32 < 2; g32++) {
      int t0 = 2 * g32, t1 = t0 + 1;
      int a0 = __shfl(pk[t0][0], src0), b0 = __shfl(pk[t1][0], src0);
      int a1 = __shfl(pk[t0][1], src0), b1 = __shfl(pk[t1][1], src0);
      int a2 = __shfl(pk[t0][0], src1), b2 = __shfl(pk[t1][0], src1);
      int a3 = __shfl(pk[t0][1], src1), b3 = __shfl(pk[t1][1], src1);
      union { int4 i; bf16x8 h; } u;
      u.i.x = hiq ? b0 : a0;
      u.i.y = hiq ? b1 : a1;
      u.i.z = hiq ? b2 : a2;
      u.i.w = hiq ? b3 : a3;
      #pragma unroll
      for (int dt = 0; dt < 4; dt++)
        O[dt] = __builtin_amdgcn_mfma_f32_16x16x32_bf16(vfr[dt][g32], u.h, O[dt], 0, 0, 0);
    }
  }
  float inv = 1.f / lrun;
  #pragma unroll
  for (int dt = 0; dt < 4; dt++) {
    ushort4 o;
    unsigned short* op = (unsigned short*)&o;
    #pragma unroll
    for (int r = 0; r < 4; r++) op[r] = f2b(O[dt][r] * inv);
    *(ushort4*)&out[(size_t)(b * T + trow) * 1024 + h * 64 + dt * 16 + quad * 4] = o;
  }
}

// ---------- host ----------
extern "C" void kernel_launch(void* const* d_in, const int* in_sizes, int n_in,
                              void* d_out, int out_size, void* d_ws, size_t ws_size,
                              hipStream_t stream) {
  const int B = 2, T = 2048, C = 1024, H = 16, D = 64, FF = 4096;
  const int M = B * T;  // 4096
  const float* x   = (const float*)d_in[0];
  const float* Wq  = (const float*)d_in[1];
  const float* Wk  = (const float*)d_in[2];
  const float* Wv  = (const float*)d_in[3];
  const float* Wo  = (const float*)d_in[4];
  const float* bo  = (const float*)d_in[5];
  const float* W1  = (const float*)d_in[6];
  const float* b1  = (const float*)d_in[7];
  const float* W2  = (const float*)d_in[8];
  const float* b2  = (const float*)d_in[9];
  const float* g1  = (const float*)d_in[10];
  const float* be1 = (const float*)d_in[11];
  const float* g2  = (const float*)d_in[12];
  const float* be2 = (const float*)d_in[13];
  float* out = (float*)d_out;

  char* ws = (char*)d_ws;
  size_t off = 0;
  auto alloc = [&](size_t bytes) {
    void* p = ws + off;
    off += (bytes + 255) & ~(size_t)255;
    return p;
  };
  // NOTE: split-K partial buffers alias dead regions (layout-dependent!):
  //   pf0 = vtb (spans vtb+aout, dead after Wo gemm)  = M*C floats
  //   pf1 = qkvt (spans qkvt+wot+w1t, dead after ff1) = M*C floats
  ushort_t* qkvt = (ushort_t*)alloc((size_t)3 * C * C * 2);  // 6.29 MB
  ushort_t* wot  = (ushort_t*)alloc((size_t)C * C * 2);      // 2.10 MB
  ushort_t* w1t  = (ushort_t*)alloc((size_t)FF * C * 2);     // 8.39 MB
  ushort_t* w2t  = (ushort_t*)alloc((size_t)C * FF * 2);     // 8.39 MB
  ushort_t* hbuf = (ushort_t*)alloc((size_t)M * C * 2);      // 8.39 MB
  ushort_t* big  = (ushort_t*)alloc((size_t)M * FF * 2);     // 33.55 MB
  ushort_t* vtb  = (ushort_t*)alloc((size_t)M * C * 2);      // 8.39 MB
  ushort_t* aout = (ushort_t*)alloc((size_t)M * C * 2);      // 8.39 MB
  float*    x2   = (float*)alloc((size_t)M * C * 4);         // 16.78 MB
  float* pf0 = (float*)vtb;    // 16.78 MB span (vtb+aout)
  float* pf1 = (float*)qkvt;   // 16.78 MB span (qkvt+wot+w1t)

  dim3 tb(32, 8);
  // all weight transposes in ONE launch (saves 5 launch+tail gaps)
  transpose_all_kernel<<<12288, tb, 0, stream>>>(
      Wq, Wk, Wv, Wo, W1, W2, qkvt, wot, w1t, w2t);
  ln_kernel<<<M, 256, 0, stream>>>(x, g1, be1, hbuf);
  // QKV = h @ Wqkv^T -> bf16  (768 blocks of 128^2 = 3/CU, XCD-grouped)
  gemm_bt_kernel<24, 3072, 1024, 2, 1><<<768, 256, 0, stream>>>(
      hbuf, qkvt, nullptr, nullptr, big, nullptr, nullptr);
  transpose_v_kernel<<<dim3(2, T / 32, B * H), tb, 0, stream>>>(big, vtb);
  attn_kernel<<<1024, 256, 0, stream>>>(big, vtb, aout);
  // x2 = attn @ Wo^T + bo + x (fp32)  (128x64 tiles: 512 blocks = 2/CU)
  gemm_bt64_kernel<1024, 1024, 4 | 8, 1><<<512, 256, 0, stream>>>(
      aout, wot, bo, x, x2, nullptr, nullptr);
  ln_kernel<<<M, 256, 0, stream>>>(x2, g2, be2, hbuf);
  // ff1 = relu(h2 @ W1^T + b1) -> bf16  (1024 blocks of 128^2 = 4/CU)
  gemm_bt_kernel<32, 4096, 1024, 1 | 2 | 4, 1><<<1024, 256, 0, stream>>>(
      hbuf, w1t, b1, nullptr, big, nullptr, nullptr);
  // ff2 split-K=2 at 128x64 tiles (1024 blocks = 4/CU), then reduce
  gemm_bt64_kernel<1024, 4096, 0, 2><<<1024, 256, 0, stream>>>(
      big, w2t, nullptr, nullptr, nullptr, pf0, pf1);
  reduce2_kernel<<<M * C / 1024, 256, 0, stream>>>(pf0, pf1, b2, x2, out);
}

// Round 9
// 355.738 us; speedup vs baseline: 1.0496x; 1.0132x over previous
//
#include <hip/hip_runtime.h>
#include <stdint.h>

typedef unsigned short ushort_t;
typedef __attribute__((ext_vector_type(8))) short bf16x8;   // 8 bf16 in 4 VGPRs
typedef __attribute__((ext_vector_type(4))) float f32x4;

// ---------- helpers ----------
__device__ __forceinline__ unsigned short f2b(float f) {
  unsigned u = __float_as_uint(f);
  u += 0x7fffu + ((u >> 16) & 1u);   // round-to-nearest-even
  return (unsigned short)(u >> 16);
}

__device__ __forceinline__ void async16(const void* g, void* l) {
  __builtin_amdgcn_global_load_lds(
      (const __attribute__((address_space(1))) void*)g,
      (__attribute__((address_space(3))) void*)l, 16, 0, 0);
}

// ---------- LayerNorm (fp32 in -> bf16 out), one block per row, C=1024 ----------
__global__ __launch_bounds__(256) void ln_kernel(
    const float* __restrict__ x, const float* __restrict__ g,
    const float* __restrict__ be, ushort_t* __restrict__ out) {
  const int C = 1024;
  int row = blockIdx.x;
  const float4* xr = (const float4*)(x + (size_t)row * C);
  int tid = threadIdx.x;
  float4 v = xr[tid];
  float s = v.x + v.y + v.z + v.w;
  float sq = v.x * v.x + v.y * v.y + v.z * v.z + v.w * v.w;
  #pragma unroll
  for (int off = 32; off > 0; off >>= 1) {
    s += __shfl_xor(s, off);
    sq += __shfl_xor(sq, off);
  }
  __shared__ float ss[4], ssq[4];
  int wv = tid >> 6;
  if ((tid & 63) == 0) { ss[wv] = s; ssq[wv] = sq; }
  __syncthreads();
  s = ss[0] + ss[1] + ss[2] + ss[3];
  sq = ssq[0] + ssq[1] + ssq[2] + ssq[3];
  float mu = s * (1.f / C);
  float var = sq * (1.f / C) - mu * mu;
  float rs = rsqrtf(var + 1e-5f);
  float4 gv = ((const float4*)g)[tid];
  float4 bv = ((const float4*)be)[tid];
  ushort4 o;
  o.x = f2b((v.x - mu) * rs * gv.x + bv.x);
  o.y = f2b((v.y - mu) * rs * gv.y + bv.y);
  o.z = f2b((v.z - mu) * rs * gv.z + bv.z);
  o.w = f2b((v.w - mu) * rs * gv.w + bv.w);
  ((ushort4*)(out + (size_t)row * C))[tid] = o;
}

// ---------- split-K final reduce: out = p0 + p1 + bias + resid (fp32), N=1024 ----------
__global__ __launch_bounds__(256) void reduce2_kernel(
    const float* __restrict__ p0, const float* __restrict__ p1,
    const float* __restrict__ bias, const float* __restrict__ resid,
    float* __restrict__ out) {
  int idx = blockIdx.x * 256 + threadIdx.x;      // float4 index
  float4 a = ((const float4*)p0)[idx];
  float4 b = ((const float4*)p1)[idx];
  float4 r = ((const float4*)resid)[idx];
  float4 bi = ((const float4*)bias)[idx & 255];  // 1024 floats = 256 float4 per row
  float4 o;
  o.x = a.x + b.x + r.x + bi.x;
  o.y = a.y + b.y + r.y + bi.y;
  o.z = a.z + b.z + r.z + bi.z;
  o.w = a.w + b.w + r.w + bi.w;
  ((float4*)out)[idx] = o;
}

// ---------- fused weight transpose+cast: ALL weights in one launch ----------
__global__ __launch_bounds__(256) void transpose_all_kernel(
    const float* __restrict__ Wq, const float* __restrict__ Wk,
    const float* __restrict__ Wv, const float* __restrict__ Wo,
    const float* __restrict__ W1, const float* __restrict__ W2,
    ushort_t* __restrict__ qkvt, ushort_t* __restrict__ wot,
    ushort_t* __restrict__ w1t, ushort_t* __restrict__ w2t) {
  int bid = blockIdx.x;
  const float* in;
  ushort_t* out;
  int R, Cin, bx, by;
  if (bid < 3072) {
    int z = bid >> 6, rem = bid & 63;
    bx = rem & 1; by = rem >> 1;
    int wsel = z >> 4, h = z & 15;
    in = (wsel == 0 ? Wq : wsel == 1 ? Wk : Wv) + (size_t)h * 1024 * 64;
    out = qkvt + (size_t)wsel * 1024 * 1024 + (size_t)h * 1024 * 64;
    R = 1024; Cin = 64;
  } else if (bid < 4096) {
    int rem = bid - 3072;
    bx = rem & 31; by = rem >> 5;
    in = Wo; out = wot; R = 1024; Cin = 1024;
  } else if (bid < 8192) {
    int rem = bid - 4096;
    bx = rem & 127; by = rem >> 7;
    in = W1; out = w1t; R = 1024; Cin = 4096;
  } else {
    int rem = bid - 8192;
    bx = rem & 31; by = rem >> 5;
    in = W2; out = w2t; R = 4096; Cin = 1024;
  }
  __shared__ float tile[32][33];
  int c0 = bx * 32, r0 = by * 32;
  int tx = threadIdx.x, ty = threadIdx.y;
  #pragma unroll
  for (int i = 0; i < 4; i++)
    tile[ty + 8 * i][tx] = in[(size_t)(r0 + ty + 8 * i) * Cin + c0 + tx];
  __syncthreads();
  #pragma unroll
  for (int i = 0; i < 4; i++)
    out[(size_t)(c0 + ty + 8 * i) * R + r0 + tx] = f2b(tile[tx][ty + 8 * i]);
}

// ---------- V transpose: QKV (4096,3072) bf16 -> Vt (B*H, 64, 2048) bf16 ----------
__global__ __launch_bounds__(256) void transpose_v_kernel(
    const ushort_t* __restrict__ qkv, ushort_t* __restrict__ vt) {
  __shared__ ushort_t tile[32][33];
  int bh = blockIdx.z;
  int b = bh >> 4, h = bh & 15;
  int d0 = blockIdx.x * 32, t0 = blockIdx.y * 32;
  int tx = threadIdx.x, ty = threadIdx.y;
  #pragma unroll
  for (int i = 0; i < 4; i++)
    tile[ty + 8 * i][tx] =
        qkv[(size_t)(b * 2048 + t0 + ty + 8 * i) * 3072 + 2048 + h * 64 + d0 + tx];
  __syncthreads();
  #pragma unroll
  for (int i = 0; i < 4; i++)
    vt[(size_t)(bh * 64 + d0 + ty + 8 * i) * 2048 + t0 + tx] = tile[tx][ty + 8 * i];
}

// ================= 256x256 8-phase GEMM (m201 template port) =================
// BM=BN=256, BK=64, 8 waves (2M x 4N), 512 threads, 128 KB LDS.
// Per wave: 128x64 output = acc[8][4]. Per phase: 16 MFMA (one C-quadrant,
// K=64). 4 phases per K-tile, 8 per iteration (2 K-tiles: even->dbuf0,
// odd->dbuf1). One half-tile (128x64) staged per phase, 2 async16/thread.
// Staging ledger (iter computes tiles T=2i, T+1):
//   P1: B0(T+1)->d1  P2: B1(T+1)->d1  P3: A0(T+2)->d0  P4: A1(T+2)->d0 +vmcnt(4)
//   P5: B0(T+2)->d0  P6: B1(T+2)->d0  P7: A0(T+3)->d1  P8: A1(T+3)->d1 +vmcnt(4)
// Each slot's previous reads ended >=1 barrier before its staging phase.
// vmcnt(4) leaves only the last 2 half-tiles in flight: every half-tile is
// retired one full phase before its first ds_read. Last iter: P4 vmcnt(0).
// LDS swizzle: slot = chunk ^ (row&7), realized by pre-swizzling the GLOBAL
// source chunk (LDS dest stays lane-linear); reads apply the same XOR ->
// 8 lanes/slot (minimal for b128). FLAGS: 1=relu, 2=bf16 out, 4=+bias.
#define RD_A(DB, MB) \
  _Pragma("unroll") \
  for (int mf_ = 0; mf_ < 4; mf_++) { \
    af[(MB) + mf_][0] = *(const bf16x8*)&Als[DB][wm][(aRow + ((MB) + mf_) * 16) * 64 + rof0]; \
    af[(MB) + mf_][1] = *(const bf16x8*)&Als[DB][wm][(aRow + ((MB) + mf_) * 16) * 64 + rof1]; \
  }
#define RD_B(DB, NB) \
  _Pragma("unroll") \
  for (int nf_ = 0; nf_ < 2; nf_++) { \
    bf[(NB) + nf_][0] = *(const bf16x8*)&Bls[DB][bh][(bRow + ((NB) + nf_) * 16) * 64 + rof0]; \
    bf[(NB) + nf_][1] = *(const bf16x8*)&Bls[DB][bh][(bRow + ((NB) + nf_) * 16) * 64 + rof1]; \
  }
#define MMPH(MB, NB) \
  __builtin_amdgcn_s_barrier(); \
  asm volatile("s_waitcnt lgkmcnt(0)" ::: "memory"); \
  __builtin_amdgcn_sched_barrier(0); \
  __builtin_amdgcn_s_setprio(1); \
  _Pragma("unroll") \
  for (int mf_ = 0; mf_ < 4; mf_++) \
    _Pragma("unroll") \
    for (int nf_ = 0; nf_ < 2; nf_++) { \
      acc[(MB) + mf_][(NB) + nf_] = __builtin_amdgcn_mfma_f32_16x16x32_bf16( \
          af[(MB) + mf_][0], bf[(NB) + nf_][0], acc[(MB) + mf_][(NB) + nf_], 0, 0, 0); \
      acc[(MB) + mf_][(NB) + nf_] = __builtin_amdgcn_mfma_f32_16x16x32_bf16( \
          af[(MB) + mf_][1], bf[(NB) + nf_][1], acc[(MB) + mf_][(NB) + nf_], 0, 0, 0); \
    } \
  __builtin_amdgcn_s_setprio(0);
#define ENDPH __builtin_amdgcn_s_barrier();

template <int N, int K, int FLAGS>
__global__ __launch_bounds__(512, 2) void gemm256p8_kernel(
    const ushort_t* __restrict__ A, const ushort_t* __restrict__ Bt,
    const float* __restrict__ bias, void* __restrict__ outv) {
  constexpr int NBN = N / 256;
  constexpr int NT2 = K / 128;           // iterations, 2 K-tiles each (>= 2)
  __shared__ __align__(16) ushort_t Als[2][2][128 * 64];   // 64 KB
  __shared__ __align__(16) ushort_t Bls[2][2][128 * 64];   // 64 KB
  int tid = threadIdx.x, w = tid >> 6, lane = tid & 63;
  int quad = lane >> 4, l16 = lane & 15;
  int wm = w >> 2, wn = w & 3;
  int bid = blockIdx.x;
  int bm = bid / NBN, bn = bid % NBN;
  int bm0 = bm * 256, bn0 = bn * 256;
  // staging constants: lane -> row (w*8 + lane>>3) within 64-row group,
  // source chunk pre-swizzled so linear LDS + XOR read recovers data.
  int lrow = (w << 3) + (lane >> 3);
  int kc8 = ((lane & 7) ^ ((lane >> 3) & 7)) << 3;
  const ushort_t* Ab = A + (size_t)(bm0 + lrow) * K + kc8;
  const ushort_t* Bb = Bt + (size_t)(bn0 + lrow) * K + kc8;
  // read constants
  int rof0 = (quad ^ (l16 & 7)) << 3;
  int rof1 = ((4 + quad) ^ (l16 & 7)) << 3;
  int bh = wn >> 1;
  int aRow = l16;
  int bRow = (wn & 1) * 64 + l16;

  auto stA = [&](int kt, int half, int db) {
    const ushort_t* g = Ab + (size_t)(half * 128) * K + kt * 64;
    ushort_t* l = &Als[db][half][w * 512];
    async16(g, l);
    async16(g + (size_t)64 * K, l + 4096);
  };
  auto stB = [&](int kt, int half, int db) {
    const ushort_t* g = Bb + (size_t)(half * 128) * K + kt * 64;
    ushort_t* l = &Bls[db][half][w * 512];
    async16(g, l);
    async16(g + (size_t)64 * K, l + 4096);
  };

  f32x4 acc[8][4];
  #pragma unroll
  for (int mf = 0; mf < 8; mf++)
    #pragma unroll
    for (int nf = 0; nf < 4; nf++) acc[mf][nf] = f32x4{0.f, 0.f, 0.f, 0.f};
  bf16x8 af[8][2], bf[4][2];

  // prologue: tile0 (A+B) -> d0, tile1 A -> d1; tile0 fully retired.
  stA(0, 0, 0); stA(0, 1, 0);
  stB(0, 0, 0); stB(0, 1, 0);
  stA(1, 0, 1); stA(1, 1, 1);
  asm volatile("s_waitcnt vmcnt(4)" ::: "memory");
  __builtin_amdgcn_s_barrier();

  #pragma unroll 1
  for (int i = 0; i < NT2; ++i) {
    bool lastI = (i == NT2 - 1);
    int t1 = 2 * i + 1;
    // ---- P1: quadrant (m0-3, n0-1) of tile 2i ----
    RD_A(0, 0)
    RD_B(0, 0)
    stB(t1, 0, 1);
    MMPH(0, 0)
    ENDPH
    // ---- P2: (m4-7, n0-1) ----
    RD_A(0, 4)
    stB(t1, 1, 1);
    MMPH(4, 0)
    ENDPH
    // ---- P3: (m4-7, n2-3) ----
    RD_B(0, 2)
    if (!lastI) stA(t1 + 1, 0, 0);
    MMPH(4, 2)
    ENDPH
    // ---- P4: (m0-3, n2-3); counted drain ----
    if (!lastI) stA(t1 + 1, 1, 0);
    MMPH(0, 2)
    if (!lastI) asm volatile("s_waitcnt vmcnt(4)" ::: "memory");
    else        asm volatile("s_waitcnt vmcnt(0)" ::: "memory");
    ENDPH
    // ---- P5: tile 2i+1, quadrant (m0-3, n0-1) ----
    RD_A(1, 0)
    RD_B(1, 0)
    if (!lastI) stB(t1 + 1, 0, 0);
    MMPH(0, 0)
    ENDPH
    // ---- P6: (m4-7, n0-1) ----
    RD_A(1, 4)
    if (!lastI) stB(t1 + 1, 1, 0);
    MMPH(4, 0)
    ENDPH
    // ---- P7: (m4-7, n2-3) ----
    RD_B(1, 2)
    if (!lastI) stA(t1 + 2, 0, 1);
    MMPH(4, 2)
    ENDPH
    // ---- P8: (m0-3, n2-3); counted drain ----
    if (!lastI) stA(t1 + 2, 1, 1);
    MMPH(0, 2)
    if (!lastI) asm volatile("s_waitcnt vmcnt(4)" ::: "memory");
    ENDPH
  }
  // ---- epilogue ----
  #pragma unroll
  for (int mf = 0; mf < 8; mf++)
    #pragma unroll
    for (int nf = 0; nf < 4; nf++)
      #pragma unroll
      for (int r = 0; r < 4; r++) {
        int row = bm0 + wm * 128 + mf * 16 + quad * 4 + r;
        int col = bn0 + wn * 64 + nf * 16 + l16;
        float v = acc[mf][nf][r];
        if constexpr (FLAGS & 4) v += bias[col];
        if constexpr (FLAGS & 1) v = fmaxf(v, 0.f);
        if constexpr ((FLAGS & 2) != 0)
          ((ushort_t*)outv)[(size_t)row * N + col] = f2b(v);
        else
          ((float*)outv)[(size_t)row * N + col] = v;
      }
}
#undef RD_A
#undef RD_B
#undef MMPH
#undef ENDPH

// ---------- GEMM 128x64 tile (m97 structure): Wo and FF2 split-K ----------
template <int N, int K, int FLAGS, int SK>
__global__ __launch_bounds__(256, 3) void gemm_bt64_kernel(
    const ushort_t* __restrict__ A, const ushort_t* __restrict__ Bt,
    const float* __restrict__ bias, const float* __restrict__ resid,
    void* __restrict__ outv, float* __restrict__ pp0, float* __restrict__ pp1) {
  constexpr int KS = K / SK;
  constexpr int NBM = 32;                // M = 4096 / 128
  constexpr int NBN = N / 64;
  constexpr int NWG = NBM * NBN * SK;    // must == gridDim.x, % 8 == 0
  __shared__ ushort_t Als[2][128 * 32];  // 16 KB
  __shared__ ushort_t Bls[2][64 * 32];   //  8 KB
  int tid = threadIdx.x, w = tid >> 6, lane = tid & 63, quad = lane >> 4, l16 = lane & 15;
  int bid = blockIdx.x;
  int swz = (bid & 7) * (NWG / 8) + (bid >> 3);
  int z = 0;
  if constexpr (SK > 1) { z = swz / (NBM * NBN); swz -= z * (NBM * NBN); }
  int bm = swz / NBN, bn = swz - bm * NBN;
  int bm0 = bm * 128, bn0 = bn * 64;
  int koff = z * KS;
  int wm = (w >> 1) * 64, wn = (w & 1) * 32;
  f32x4 acc[4][2];
  #pragma unroll
  for (int i = 0; i < 4; i++)
    #pragma unroll
    for (int j = 0; j < 2; j++) acc[i][j] = f32x4{0.f, 0.f, 0.f, 0.f};
  const ushort_t* Ag = A + (size_t)bm0 * K + koff;
  const ushort_t* Bg = Bt + (size_t)bn0 * K + koff;
  int lr = lane >> 2, lco = (lane & 3) * 8;
  auto stage = [&](int k0, int bi) {
    async16(Ag + (size_t)(w * 32 + lr) * K + k0 + lco, &Als[bi][w * 1024]);
    async16(Ag + (size_t)(w * 32 + 16 + lr) * K + k0 + lco, &Als[bi][w * 1024 + 512]);
    async16(Bg + (size_t)(w * 16 + lr) * K + k0 + lco, &Bls[bi][w * 512]);
  };
  stage(0, 0);
  int s = 0;
  for (int k0 = 0; k0 < KS; k0 += 32, s ^= 1) {
    __syncthreads();
    if (k0 + 32 < KS) stage(k0 + 32, s ^ 1);
    bf16x8 af[4], bf[2];
    #pragma unroll
    for (int i = 0; i < 4; i++)
      af[i] = *(const bf16x8*)&Als[s][(wm + i * 16 + l16) * 32 + quad * 8];
    #pragma unroll
    for (int j = 0; j < 2; j++)
      bf[j] = *(const bf16x8*)&Bls[s][(wn + j * 16 + l16) * 32 + quad * 8];
    #pragma unroll
    for (int i = 0; i < 4; i++)
      #pragma unroll
      for (int j = 0; j < 2; j++)
        acc[i][j] = __builtin_amdgcn_mfma_f32_16x16x32_bf16(af[i], bf[j], acc[i][j], 0, 0, 0);
  }
  float* pdst = nullptr;
  if constexpr (SK > 1) pdst = z ? pp1 : pp0;
  #pragma unroll
  for (int i = 0; i < 4; i++)
    #pragma unroll
    for (int j = 0; j < 2; j++)
      #pragma unroll
      for (int r = 0; r < 4; r++) {
        int row = bm0 + wm + i * 16 + quad * 4 + r;
        int col = bn0 + wn + j * 16 + l16;
        float v = acc[i][j][r];
        if constexpr (SK > 1) {
          pdst[(size_t)row * N + col] = v;   // raw partial
        } else {
          if constexpr (FLAGS & 4) v += bias[col];
          if constexpr (FLAGS & 8) v += resid[(size_t)row * N + col];
          if constexpr (FLAGS & 1) v = fmaxf(v, 0.f);
          if constexpr ((FLAGS & 2) != 0)
            ((ushort_t*)outv)[(size_t)row * N + col] = f2b(v);
          else
            ((float*)outv)[(size_t)row * N + col] = v;
        }
      }
}

// ---------- causal flash attention: dbuf LDS staging + S^T softmax ----------
__global__ __launch_bounds__(256, 4) void attn_kernel(
    const ushort_t* __restrict__ qkv, const ushort_t* __restrict__ vt,
    ushort_t* __restrict__ out) {
  const int T = 2048, CC = 3072;
  __shared__ ushort_t Kls[2][2 * 64 * 32];
  __shared__ ushort_t Vls[2][2 * 64 * 32];
  int fid = blockIdx.x;                       // 1024
  int bh = (fid & 7) * 4 + ((fid >> 3) & 3);  // XCD swizzle: 4 heads per XCD
  int qb = 31 - (fid >> 5);                   // longest q-blocks first
  int b = bh >> 4, h = bh & 15;
  int q0 = qb * 64;
  int tid = threadIdx.x, w = tid >> 6, lane = tid & 63, quad = lane >> 4, l16 = lane & 15;
  int srow = w * 16 + (lane >> 2);
  int sco = (lane & 3) * 8;
  const ushort_t* kg = qkv + (size_t)(b * T + srow) * CC + 1024 + h * 64 + sco;
  const ushort_t* vg = vt + (size_t)(bh * 64 + srow) * T + sco;
  int q0s = q0 + w * 16;
  int trow = q0s + l16;
  const ushort_t* qp = qkv + (size_t)(b * T + trow) * CC + h * 64 + quad * 8;
  bf16x8 aq[2] = { *(const bf16x8*)qp, *(const bf16x8*)(qp + 32) };
  f32x4 O[4];
  #pragma unroll
  for (int i = 0; i < 4; i++) O[i] = f32x4{0.f, 0.f, 0.f, 0.f};
  float mrun = -1e30f, lrun = 0.f;
  const float ksc = 0.03125f * 1.44269504f;  // C^-0.5 * log2(e)
  int src0 = (quad & 1) * 32 + l16;
  int src1 = src0 + 16;
  bool hiq = quad >= 2;
  auto stage = [&](int kb, int bi) {
    int s0 = kb * 64;
    async16(kg + (size_t)s0 * CC, &Kls[bi][w * 512]);
    async16(kg + (size_t)s0 * CC + 32, &Kls[bi][2048 + w * 512]);
    async16(vg + s0, &Vls[bi][w * 512]);
    async16(vg + s0 + 32, &Vls[bi][2048 + w * 512]);
  };
  stage(0, 0);
  for (int kb = 0; kb <= qb; kb++) {
    __syncthreads();
    if (kb < qb) stage(kb + 1, (kb + 1) & 1);
    int bi = kb & 1;
    int s0 = kb * 64;
    bf16x8 kfr[4][2], vfr[4][2];
    #pragma unroll
    for (int t = 0; t < 4; t++)
      #pragma unroll
      for (int ks = 0; ks < 2; ks++) {
        kfr[t][ks] = *(const bf16x8*)&Kls[bi][(ks * 64 + t * 16 + l16) * 32 + quad * 8];
        vfr[t][ks] = *(const bf16x8*)&Vls[bi][(ks * 64 + t * 16 + l16) * 32 + quad * 8];
      }
    f32x4 st[4];
    #pragma unroll
    for (int t = 0; t < 4; t++) {
      st[t] = f32x4{0.f, 0.f, 0.f, 0.f};
      #pragma unroll
      for (int ks = 0; ks < 2; ks++)
        st[t] = __builtin_amdgcn_mfma_f32_16x16x32_bf16(kfr[t][ks], aq[ks], st[t], 0, 0, 0);
    }
    float sv[4][4];
    float vmax = -1e30f;
    if (kb == qb) {
      #pragma unroll
      for (int t = 0; t < 4; t++)
        #pragma unroll
        for (int r = 0; r < 4; r++) {
          float sc = st[t][r] * ksc;
          int scol = s0 + t * 16 + quad * 4 + r;
          if (scol > trow) sc = -1e30f;
          sv[t][r] = sc;
          vmax = fmaxf(vmax, sc);
        }
    } else {
      #pragma unroll
      for (int t = 0; t < 4; t++)
        #pragma unroll
        for (int r = 0; r < 4; r++) {
          float sc = st[t][r] * ksc;
          sv[t][r] = sc;
          vmax = fmaxf(vmax, sc);
        }
    }
    vmax = fmaxf(vmax, __shfl_xor(vmax, 16));
    vmax = fmaxf(vmax, __shfl_xor(vmax, 32));
    float mnew = fmaxf(mrun, vmax);
    float alpha = __builtin_amdgcn_exp2f(mrun - mnew);
    mrun = mnew;
    float psum = 0.f;
    int pk[4][2];
    #pragma unroll
    for (int t = 0; t < 4; t++) {
      float p0 = __builtin_amdgcn_exp2f(sv[t][0] - mnew);
      float p1 = __builtin_amdgcn_exp2f(sv[t][1] - mnew);
      float p2 = __builtin_amdgcn_exp2f(sv[t][2] - mnew);
      float p3 = __builtin_amdgcn_exp2f(sv[t][3] - mnew);
      psum += (p0 + p1) + (p2 + p3);
      pk[t][0] = (int)((unsigned)f2b(p0) | ((unsigned)f2b(p1) << 16));
      pk[t][1] = (int)((unsigned)f2b(p2) | ((unsigned)f2b(p3) << 16));
    }
    psum += __shfl_xor(psum, 16);
    psum += __shfl_xor(psum, 32);
    lrun = lrun * alpha + psum;
    #pragma unroll
    for (int dt = 0; dt < 4; dt++) O[dt] *= alpha;
    #pragma unroll
    for (int g32 = 0; g32 < 2; g32++) {
      int t0 = 2 * g32, t1 = t0 + 1;
      int a0 = __shfl(pk[t0][0], src0), b0 = __shfl(pk[t1][0], src0);
      int a1 = __shfl(pk[t0][1], src0), b1 = __shfl(pk[t1][1], src0);
      int a2 = __shfl(pk[t0][0], src1), b2 = __shfl(pk[t1][0], src1);
      int a3 = __shfl(pk[t0][1], src1), b3 = __shfl(pk[t1][1], src1);
      union { int4 i; bf16x8 h; } u;
      u.i.x = hiq ? b0 : a0;
      u.i.y = hiq ? b1 : a1;
      u.i.z = hiq ? b2 : a2;
      u.i.w = hiq ? b3 : a3;
      #pragma unroll
      for (int dt = 0; dt < 4; dt++)
        O[dt] = __builtin_amdgcn_mfma_f32_16x16x32_bf16(vfr[dt][g32], u.h, O[dt], 0, 0, 0);
    }
  }
  float inv = 1.f / lrun;
  #pragma unroll
  for (int dt = 0; dt < 4; dt++) {
    ushort4 o;
    unsigned short* op = (unsigned short*)&o;
    #pragma unroll
    for (int r = 0; r < 4; r++) op[r] = f2b(O[dt][r] * inv);
    *(ushort4*)&out[(size_t)(b * T + trow) * 1024 + h * 64 + dt * 16 + quad * 4] = o;
  }
}

// ---------- host ----------
extern "C" void kernel_launch(void* const* d_in, const int* in_sizes, int n_in,
                              void* d_out, int out_size, void* d_ws, size_t ws_size,
                              hipStream_t stream) {
  const int B = 2, T = 2048, C = 1024, H = 16, D = 64, FF = 4096;
  const int M = B * T;  // 4096
  const float* x   = (const float*)d_in[0];
  const float* Wq  = (const float*)d_in[1];
  const float* Wk  = (const float*)d_in[2];
  const float* Wv  = (const float*)d_in[3];
  const float* Wo  = (const float*)d_in[4];
  const float* bo  = (const float*)d_in[5];
  const float* W1  = (const float*)d_in[6];
  const float* b1  = (const float*)d_in[7];
  const float* W2  = (const float*)d_in[8];
  const float* b2  = (const float*)d_in[9];
  const float* g1  = (const float*)d_in[10];
  const float* be1 = (const float*)d_in[11];
  const float* g2  = (const float*)d_in[12];
  const float* be2 = (const float*)d_in[13];
  float* out = (float*)d_out;

  char* ws = (char*)d_ws;
  size_t off = 0;
  auto alloc = [&](size_t bytes) {
    void* p = ws + off;
    off += (bytes + 255) & ~(size_t)255;
    return p;
  };
  // NOTE: split-K partial buffers alias dead regions (layout-dependent!):
  //   pf0 = vtb (spans vtb+aout, dead after Wo gemm)  = M*C floats
  //   pf1 = qkvt (spans qkvt+wot+w1t, dead after ff1) = M*C floats
  ushort_t* qkvt = (ushort_t*)alloc((size_t)3 * C * C * 2);  // 6.29 MB
  ushort_t* wot  = (ushort_t*)alloc((size_t)C * C * 2);      // 2.10 MB
  ushort_t* w1t  = (ushort_t*)alloc((size_t)FF * C * 2);     // 8.39 MB
  ushort_t* w2t  = (ushort_t*)alloc((size_t)C * FF * 2);     // 8.39 MB
  ushort_t* hbuf = (ushort_t*)alloc((size_t)M * C * 2);      // 8.39 MB
  ushort_t* big  = (ushort_t*)alloc((size_t)M * FF * 2);     // 33.55 MB
  ushort_t* vtb  = (ushort_t*)alloc((size_t)M * C * 2);      // 8.39 MB
  ushort_t* aout = (ushort_t*)alloc((size_t)M * C * 2);      // 8.39 MB
  float*    x2   = (float*)alloc((size_t)M * C * 4);         // 16.78 MB
  float* pf0 = (float*)vtb;    // 16.78 MB span (vtb+aout)
  float* pf1 = (float*)qkvt;   // 16.78 MB span (qkvt+wot+w1t)

  dim3 tb(32, 8);
  transpose_all_kernel<<<12288, tb, 0, stream>>>(
      Wq, Wk, Wv, Wo, W1, W2, qkvt, wot, w1t, w2t);
  ln_kernel<<<M, 256, 0, stream>>>(x, g1, be1, hbuf);
  // QKV = h @ Wqkv^T -> bf16  (192 blocks of 256^2 8-phase)
  gemm256p8_kernel<3072, 1024, 2><<<192, 512, 0, stream>>>(
      hbuf, qkvt, nullptr, big);
  transpose_v_kernel<<<dim3(2, T / 32, B * H), tb, 0, stream>>>(big, vtb);
  attn_kernel<<<1024, 256, 0, stream>>>(big, vtb, aout);
  // x2 = attn @ Wo^T + bo + x (fp32)  (128x64 tiles: 512 blocks)
  gemm_bt64_kernel<1024, 1024, 4 | 8, 1><<<512, 256, 0, stream>>>(
      aout, wot, bo, x, x2, nullptr, nullptr);
  ln_kernel<<<M, 256, 0, stream>>>(x2, g2, be2, hbuf);
  // ff1 = relu(h2 @ W1^T + b1) -> bf16  (256 blocks of 256^2 8-phase, 1/CU)
  gemm256p8_kernel<4096, 1024, 1 | 2 | 4><<<256, 512, 0, stream>>>(
      hbuf, w1t, b1, big);
  // ff2 split-K=2 at 128x64 tiles (1024 blocks = 4/CU), then reduce
  gemm_bt64_kernel<1024, 4096, 0, 2><<<1024, 256, 0, stream>>>(
      big, w2t, nullptr, nullptr, nullptr, pf0, pf1);
  reduce2_kernel<<<M * C / 1024, 256, 0, stream>>>(pf0, pf1, b2, x2, out);
}

// Round 10
// 351.186 us; speedup vs baseline: 1.0632x; 1.0130x over previous
//
#include <hip/hip_runtime.h>
#include <stdint.h>

typedef unsigned short ushort_t;
typedef __attribute__((ext_vector_type(8))) short bf16x8;   // 8 bf16 in 4 VGPRs
typedef __attribute__((ext_vector_type(4))) float f32x4;

// ---------- helpers ----------
__device__ __forceinline__ unsigned short f2b(float f) {
  unsigned u = __float_as_uint(f);
  u += 0x7fffu + ((u >> 16) & 1u);   // round-to-nearest-even
  return (unsigned short)(u >> 16);
}

__device__ __forceinline__ void async16(const void* g, void* l) {
  __builtin_amdgcn_global_load_lds(
      (const __attribute__((address_space(1))) void*)g,
      (__attribute__((address_space(3))) void*)l, 16, 0, 0);
}

// ---------- LayerNorm (fp32 in -> bf16 out), one block per row, C=1024 ----------
__global__ __launch_bounds__(256) void ln_kernel(
    const float* __restrict__ x, const float* __restrict__ g,
    const float* __restrict__ be, ushort_t* __restrict__ out) {
  const int C = 1024;
  int row = blockIdx.x;
  const float4* xr = (const float4*)(x + (size_t)row * C);
  int tid = threadIdx.x;
  float4 v = xr[tid];
  float s = v.x + v.y + v.z + v.w;
  float sq = v.x * v.x + v.y * v.y + v.z * v.z + v.w * v.w;
  #pragma unroll
  for (int off = 32; off > 0; off >>= 1) {
    s += __shfl_xor(s, off);
    sq += __shfl_xor(sq, off);
  }
  __shared__ float ss[4], ssq[4];
  int wv = tid >> 6;
  if ((tid & 63) == 0) { ss[wv] = s; ssq[wv] = sq; }
  __syncthreads();
  s = ss[0] + ss[1] + ss[2] + ss[3];
  sq = ssq[0] + ssq[1] + ssq[2] + ssq[3];
  float mu = s * (1.f / C);
  float var = sq * (1.f / C) - mu * mu;
  float rs = rsqrtf(var + 1e-5f);
  float4 gv = ((const float4*)g)[tid];
  float4 bv = ((const float4*)be)[tid];
  ushort4 o;
  o.x = f2b((v.x - mu) * rs * gv.x + bv.x);
  o.y = f2b((v.y - mu) * rs * gv.y + bv.y);
  o.z = f2b((v.z - mu) * rs * gv.z + bv.z);
  o.w = f2b((v.w - mu) * rs * gv.w + bv.w);
  ((ushort4*)(out + (size_t)row * C))[tid] = o;
}

// ---------- split-K=4 final reduce: out += p0 + p1 + p2 + bias + resid ----------
// (out already holds the z=3 partial; per-thread read-modify-write, no race)
__global__ __launch_bounds__(256) void reduce3_kernel(
    const float* __restrict__ p0, const float* __restrict__ p1,
    const float* __restrict__ p2, const float* __restrict__ bias,
    const float* __restrict__ resid, float* out) {
  int idx = blockIdx.x * 256 + threadIdx.x;      // float4 index
  float4 a = ((const float4*)p0)[idx];
  float4 b = ((const float4*)p1)[idx];
  float4 c = ((const float4*)p2)[idx];
  float4 r = ((const float4*)resid)[idx];
  float4 bi = ((const float4*)bias)[idx & 255];  // 1024 floats = 256 float4/row
  float4 o = ((const float4*)out)[idx];
  o.x += a.x + b.x + c.x + r.x + bi.x;
  o.y += a.y + b.y + c.y + r.y + bi.y;
  o.z += a.z + b.z + c.z + r.z + bi.z;
  o.w += a.w + b.w + c.w + r.w + bi.w;
  ((float4*)out)[idx] = o;
}

// ---------- fused weight transpose+cast: ALL weights in one launch ----------
__global__ __launch_bounds__(256) void transpose_all_kernel(
    const float* __restrict__ Wq, const float* __restrict__ Wk,
    const float* __restrict__ Wv, const float* __restrict__ Wo,
    const float* __restrict__ W1, const float* __restrict__ W2,
    ushort_t* __restrict__ qkvt, ushort_t* __restrict__ wot,
    ushort_t* __restrict__ w1t, ushort_t* __restrict__ w2t) {
  int bid = blockIdx.x;
  const float* in;
  ushort_t* out;
  int R, Cin, bx, by;
  if (bid < 3072) {
    int z = bid >> 6, rem = bid & 63;
    bx = rem & 1; by = rem >> 1;
    int wsel = z >> 4, h = z & 15;
    in = (wsel == 0 ? Wq : wsel == 1 ? Wk : Wv) + (size_t)h * 1024 * 64;
    out = qkvt + (size_t)wsel * 1024 * 1024 + (size_t)h * 1024 * 64;
    R = 1024; Cin = 64;
  } else if (bid < 4096) {
    int rem = bid - 3072;
    bx = rem & 31; by = rem >> 5;
    in = Wo; out = wot; R = 1024; Cin = 1024;
  } else if (bid < 8192) {
    int rem = bid - 4096;
    bx = rem & 127; by = rem >> 7;
    in = W1; out = w1t; R = 1024; Cin = 4096;
  } else {
    int rem = bid - 8192;
    bx = rem & 31; by = rem >> 5;
    in = W2; out = w2t; R = 4096; Cin = 1024;
  }
  __shared__ float tile[32][33];
  int c0 = bx * 32, r0 = by * 32;
  int tx = threadIdx.x, ty = threadIdx.y;
  #pragma unroll
  for (int i = 0; i < 4; i++)
    tile[ty + 8 * i][tx] = in[(size_t)(r0 + ty + 8 * i) * Cin + c0 + tx];
  __syncthreads();
  #pragma unroll
  for (int i = 0; i < 4; i++)
    out[(size_t)(c0 + ty + 8 * i) * R + r0 + tx] = f2b(tile[tx][ty + 8 * i]);
}

// ---------- V transpose: QKV (4096,3072) bf16 -> Vt (B*H, 64, 2048) bf16 ----------
__global__ __launch_bounds__(256) void transpose_v_kernel(
    const ushort_t* __restrict__ qkv, ushort_t* __restrict__ vt) {
  __shared__ ushort_t tile[32][33];
  int bh = blockIdx.z;
  int b = bh >> 4, h = bh & 15;
  int d0 = blockIdx.x * 32, t0 = blockIdx.y * 32;
  int tx = threadIdx.x, ty = threadIdx.y;
  #pragma unroll
  for (int i = 0; i < 4; i++)
    tile[ty + 8 * i][tx] =
        qkv[(size_t)(b * 2048 + t0 + ty + 8 * i) * 3072 + 2048 + h * 64 + d0 + tx];
  __syncthreads();
  #pragma unroll
  for (int i = 0; i < 4; i++)
    vt[(size_t)(bh * 64 + d0 + ty + 8 * i) * 2048 + t0 + tx] = tile[tx][ty + 8 * i];
}

// ================= 256x256 8-phase GEMM (m201 template port) =================
// BM=BN=256, BK=64, 8 waves (2M x 4N), 512 threads, 128 KB LDS (1 block/CU).
// Per wave: 128x64 output = acc[8][4]. Per phase: 16 MFMA (one C-quadrant,
// K=64). 4 phases per K-tile, 8 per iteration (2 K-tiles). One half-tile
// staged per phase; counted vmcnt(4) only at phases 4/8 (see r9 ledger).
// SK>1: K split into SK spans; block z writes raw fp32 partial to ppz.
// FLAGS: 1=relu, 2=bf16 out, 4=+bias (SK=1 only).
#define RD_A(DB, MB) \
  _Pragma("unroll") \
  for (int mf_ = 0; mf_ < 4; mf_++) { \
    af[(MB) + mf_][0] = *(const bf16x8*)&Als[DB][wm][(aRow + ((MB) + mf_) * 16) * 64 + rof0]; \
    af[(MB) + mf_][1] = *(const bf16x8*)&Als[DB][wm][(aRow + ((MB) + mf_) * 16) * 64 + rof1]; \
  }
#define RD_B(DB, NB) \
  _Pragma("unroll") \
  for (int nf_ = 0; nf_ < 2; nf_++) { \
    bf[(NB) + nf_][0] = *(const bf16x8*)&Bls[DB][bhh][(bRow + ((NB) + nf_) * 16) * 64 + rof0]; \
    bf[(NB) + nf_][1] = *(const bf16x8*)&Bls[DB][bhh][(bRow + ((NB) + nf_) * 16) * 64 + rof1]; \
  }
#define MMPH(MB, NB) \
  __builtin_amdgcn_s_barrier(); \
  asm volatile("s_waitcnt lgkmcnt(0)" ::: "memory"); \
  __builtin_amdgcn_sched_barrier(0); \
  __builtin_amdgcn_s_setprio(1); \
  _Pragma("unroll") \
  for (int mf_ = 0; mf_ < 4; mf_++) \
    _Pragma("unroll") \
    for (int nf_ = 0; nf_ < 2; nf_++) { \
      acc[(MB) + mf_][(NB) + nf_] = __builtin_amdgcn_mfma_f32_16x16x32_bf16( \
          af[(MB) + mf_][0], bf[(NB) + nf_][0], acc[(MB) + mf_][(NB) + nf_], 0, 0, 0); \
      acc[(MB) + mf_][(NB) + nf_] = __builtin_amdgcn_mfma_f32_16x16x32_bf16( \
          af[(MB) + mf_][1], bf[(NB) + nf_][1], acc[(MB) + mf_][(NB) + nf_], 0, 0, 0); \
    } \
  __builtin_amdgcn_s_setprio(0);
#define ENDPH __builtin_amdgcn_s_barrier();

template <int N, int K, int FLAGS, int SK>
__global__ __launch_bounds__(512, 2) void gemm256p8_kernel(
    const ushort_t* __restrict__ A, const ushort_t* __restrict__ Bt,
    const float* __restrict__ bias, void* __restrict__ outv,
    float* __restrict__ pp0, float* __restrict__ pp1,
    float* __restrict__ pp2, float* __restrict__ pp3) {
  constexpr int NBM = 4096 / 256;        // 16
  constexpr int NBN = N / 256;
  constexpr int KS = K / SK;             // K-span per block
  constexpr int NT2 = KS / 128;          // iterations, 2 K-tiles each (>= 2)
  __shared__ __align__(16) ushort_t Als[2][2][128 * 64];   // 64 KB
  __shared__ __align__(16) ushort_t Bls[2][2][128 * 64];   // 64 KB
  int tid = threadIdx.x, w = tid >> 6, lane = tid & 63;
  int quad = lane >> 4, l16 = lane & 15;
  int wm = w >> 2, wn = w & 3;
  int bid = blockIdx.x;
  int z = 0, rem = bid;
  if constexpr (SK > 1) { z = bid / (NBM * NBN); rem = bid - z * (NBM * NBN); }
  int bm = rem / NBN, bn = rem % NBN;
  int bm0 = bm * 256, bn0 = bn * 256;
  int koff = z * KS;
  // staging constants: lane -> row (w*8 + lane>>3) within 64-row group,
  // source chunk pre-swizzled so linear LDS + XOR read recovers data.
  int lrow = (w << 3) + (lane >> 3);
  int kc8 = ((lane & 7) ^ ((lane >> 3) & 7)) << 3;
  const ushort_t* Ab = A + (size_t)(bm0 + lrow) * K + koff + kc8;
  const ushort_t* Bb = Bt + (size_t)(bn0 + lrow) * K + koff + kc8;
  // read constants
  int rof0 = (quad ^ (l16 & 7)) << 3;
  int rof1 = ((4 + quad) ^ (l16 & 7)) << 3;
  int bhh = wn >> 1;
  int aRow = l16;
  int bRow = (wn & 1) * 64 + l16;

  auto stA = [&](int kt, int half, int db) {
    const ushort_t* g = Ab + (size_t)(half * 128) * K + kt * 64;
    ushort_t* l = &Als[db][half][w * 512];
    async16(g, l);
    async16(g + (size_t)64 * K, l + 4096);
  };
  auto stB = [&](int kt, int half, int db) {
    const ushort_t* g = Bb + (size_t)(half * 128) * K + kt * 64;
    ushort_t* l = &Bls[db][half][w * 512];
    async16(g, l);
    async16(g + (size_t)64 * K, l + 4096);
  };

  f32x4 acc[8][4];
  #pragma unroll
  for (int mf = 0; mf < 8; mf++)
    #pragma unroll
    for (int nf = 0; nf < 4; nf++) acc[mf][nf] = f32x4{0.f, 0.f, 0.f, 0.f};
  bf16x8 af[8][2], bf[4][2];

  // prologue: tile0 (A+B) -> d0, tile1 A -> d1; tile0 fully retired.
  stA(0, 0, 0); stA(0, 1, 0);
  stB(0, 0, 0); stB(0, 1, 0);
  stA(1, 0, 1); stA(1, 1, 1);
  asm volatile("s_waitcnt vmcnt(4)" ::: "memory");
  __builtin_amdgcn_s_barrier();

  #pragma unroll 1
  for (int i = 0; i < NT2; ++i) {
    bool lastI = (i == NT2 - 1);
    int t1 = 2 * i + 1;
    // ---- P1: quadrant (m0-3, n0-1) of tile 2i ----
    RD_A(0, 0)
    RD_B(0, 0)
    stB(t1, 0, 1);
    MMPH(0, 0)
    ENDPH
    // ---- P2: (m4-7, n0-1) ----
    RD_A(0, 4)
    stB(t1, 1, 1);
    MMPH(4, 0)
    ENDPH
    // ---- P3: (m4-7, n2-3) ----
    RD_B(0, 2)
    if (!lastI) stA(t1 + 1, 0, 0);
    MMPH(4, 2)
    ENDPH
    // ---- P4: (m0-3, n2-3); counted drain ----
    if (!lastI) stA(t1 + 1, 1, 0);
    MMPH(0, 2)
    if (!lastI) asm volatile("s_waitcnt vmcnt(4)" ::: "memory");
    else        asm volatile("s_waitcnt vmcnt(0)" ::: "memory");
    ENDPH
    // ---- P5: tile 2i+1, quadrant (m0-3, n0-1) ----
    RD_A(1, 0)
    RD_B(1, 0)
    if (!lastI) stB(t1 + 1, 0, 0);
    MMPH(0, 0)
    ENDPH
    // ---- P6: (m4-7, n0-1) ----
    RD_A(1, 4)
    if (!lastI) stB(t1 + 1, 1, 0);
    MMPH(4, 0)
    ENDPH
    // ---- P7: (m4-7, n2-3) ----
    RD_B(1, 2)
    if (!lastI) stA(t1 + 2, 0, 1);
    MMPH(4, 2)
    ENDPH
    // ---- P8: (m0-3, n2-3); counted drain ----
    if (!lastI) stA(t1 + 2, 1, 1);
    MMPH(0, 2)
    if (!lastI) asm volatile("s_waitcnt vmcnt(4)" ::: "memory");
    ENDPH
  }
  // ---- epilogue ----
  if constexpr (SK > 1) {
    float* pdst = z == 0 ? pp0 : z == 1 ? pp1 : z == 2 ? pp2 : pp3;
    #pragma unroll
    for (int mf = 0; mf < 8; mf++)
      #pragma unroll
      for (int nf = 0; nf < 4; nf++)
        #pragma unroll
        for (int r = 0; r < 4; r++) {
          int row = bm0 + wm * 128 + mf * 16 + quad * 4 + r;
          int col = bn0 + wn * 64 + nf * 16 + l16;
          pdst[(size_t)row * N + col] = acc[mf][nf][r];   // raw partial
        }
  } else {
    #pragma unroll
    for (int mf = 0; mf < 8; mf++)
      #pragma unroll
      for (int nf = 0; nf < 4; nf++)
        #pragma unroll
        for (int r = 0; r < 4; r++) {
          int row = bm0 + wm * 128 + mf * 16 + quad * 4 + r;
          int col = bn0 + wn * 64 + nf * 16 + l16;
          float v = acc[mf][nf][r];
          if constexpr (FLAGS & 4) v += bias[col];
          if constexpr (FLAGS & 1) v = fmaxf(v, 0.f);
          if constexpr ((FLAGS & 2) != 0)
            ((ushort_t*)outv)[(size_t)row * N + col] = f2b(v);
          else
            ((float*)outv)[(size_t)row * N + col] = v;
        }
  }
}
#undef RD_A
#undef RD_B
#undef MMPH
#undef ENDPH

// ---------- GEMM 128x64 tile (m97 structure): Wo projection ----------
template <int N, int K, int FLAGS, int SK>
__global__ __launch_bounds__(256, 3) void gemm_bt64_kernel(
    const ushort_t* __restrict__ A, const ushort_t* __restrict__ Bt,
    const float* __restrict__ bias, const float* __restrict__ resid,
    void* __restrict__ outv, float* __restrict__ pp0, float* __restrict__ pp1) {
  constexpr int KS = K / SK;
  constexpr int NBM = 32;                // M = 4096 / 128
  constexpr int NBN = N / 64;
  constexpr int NWG = NBM * NBN * SK;    // must == gridDim.x, % 8 == 0
  __shared__ ushort_t Als[2][128 * 32];  // 16 KB
  __shared__ ushort_t Bls[2][64 * 32];   //  8 KB
  int tid = threadIdx.x, w = tid >> 6, lane = tid & 63, quad = lane >> 4, l16 = lane & 15;
  int bid = blockIdx.x;
  int swz = (bid & 7) * (NWG / 8) + (bid >> 3);
  int z = 0;
  if constexpr (SK > 1) { z = swz / (NBM * NBN); swz -= z * (NBM * NBN); }
  int bm = swz / NBN, bn = swz - bm * NBN;
  int bm0 = bm * 128, bn0 = bn * 64;
  int koff = z * KS;
  int wm = (w >> 1) * 64, wn = (w & 1) * 32;
  f32x4 acc[4][2];
  #pragma unroll
  for (int i = 0; i < 4; i++)
    #pragma unroll
    for (int j = 0; j < 2; j++) acc[i][j] = f32x4{0.f, 0.f, 0.f, 0.f};
  const ushort_t* Ag = A + (size_t)bm0 * K + koff;
  const ushort_t* Bg = Bt + (size_t)bn0 * K + koff;
  int lr = lane >> 2, lco = (lane & 3) * 8;
  auto stage = [&](int k0, int bi) {
    async16(Ag + (size_t)(w * 32 + lr) * K + k0 + lco, &Als[bi][w * 1024]);
    async16(Ag + (size_t)(w * 32 + 16 + lr) * K + k0 + lco, &Als[bi][w * 1024 + 512]);
    async16(Bg + (size_t)(w * 16 + lr) * K + k0 + lco, &Bls[bi][w * 512]);
  };
  stage(0, 0);
  int s = 0;
  for (int k0 = 0; k0 < KS; k0 += 32, s ^= 1) {
    __syncthreads();
    if (k0 + 32 < KS) stage(k0 + 32, s ^ 1);
    bf16x8 af[4], bf[2];
    #pragma unroll
    for (int i = 0; i < 4; i++)
      af[i] = *(const bf16x8*)&Als[s][(wm + i * 16 + l16) * 32 + quad * 8];
    #pragma unroll
    for (int j = 0; j < 2; j++)
      bf[j] = *(const bf16x8*)&Bls[s][(wn + j * 16 + l16) * 32 + quad * 8];
    #pragma unroll
    for (int i = 0; i < 4; i++)
      #pragma unroll
      for (int j = 0; j < 2; j++)
        acc[i][j] = __builtin_amdgcn_mfma_f32_16x16x32_bf16(af[i], bf[j], acc[i][j], 0, 0, 0);
  }
  float* pdst = nullptr;
  if constexpr (SK > 1) pdst = z ? pp1 : pp0;
  #pragma unroll
  for (int i = 0; i < 4; i++)
    #pragma unroll
    for (int j = 0; j < 2; j++)
      #pragma unroll
      for (int r = 0; r < 4; r++) {
        int row = bm0 + wm + i * 16 + quad * 4 + r;
        int col = bn0 + wn + j * 16 + l16;
        float v = acc[i][j][r];
        if constexpr (SK > 1) {
          pdst[(size_t)row * N + col] = v;   // raw partial
        } else {
          if constexpr (FLAGS & 4) v += bias[col];
          if constexpr (FLAGS & 8) v += resid[(size_t)row * N + col];
          if constexpr (FLAGS & 1) v = fmaxf(v, 0.f);
          if constexpr ((FLAGS & 2) != 0)
            ((ushort_t*)outv)[(size_t)row * N + col] = f2b(v);
          else
            ((float*)outv)[(size_t)row * N + col] = v;
        }
      }
}

// ---------- causal flash attention: dbuf LDS staging + S^T softmax ----------
__global__ __launch_bounds__(256, 4) void attn_kernel(
    const ushort_t* __restrict__ qkv, const ushort_t* __restrict__ vt,
    ushort_t* __restrict__ out) {
  const int T = 2048, CC = 3072;
  __shared__ ushort_t Kls[2][2 * 64 * 32];
  __shared__ ushort_t Vls[2][2 * 64 * 32];
  int fid = blockIdx.x;                       // 1024
  int bh = (fid & 7) * 4 + ((fid >> 3) & 3);  // XCD swizzle: 4 heads per XCD
  int qb = 31 - (fid >> 5);                   // longest q-blocks first
  int b = bh >> 4, h = bh & 15;
  int q0 = qb * 64;
  int tid = threadIdx.x, w = tid >> 6, lane = tid & 63, quad = lane >> 4, l16 = lane & 15;
  int srow = w * 16 + (lane >> 2);
  int sco = (lane & 3) * 8;
  const ushort_t* kg = qkv + (size_t)(b * T + srow) * CC + 1024 + h * 64 + sco;
  const ushort_t* vg = vt + (size_t)(bh * 64 + srow) * T + sco;
  int q0s = q0 + w * 16;
  int trow = q0s + l16;
  const ushort_t* qp = qkv + (size_t)(b * T + trow) * CC + h * 64 + quad * 8;
  bf16x8 aq[2] = { *(const bf16x8*)qp, *(const bf16x8*)(qp + 32) };
  f32x4 O[4];
  #pragma unroll
  for (int i = 0; i < 4; i++) O[i] = f32x4{0.f, 0.f, 0.f, 0.f};
  float mrun = -1e30f, lrun = 0.f;
  const float ksc = 0.03125f * 1.44269504f;  // C^-0.5 * log2(e)
  int src0 = (quad & 1) * 32 + l16;
  int src1 = src0 + 16;
  bool hiq = quad >= 2;
  auto stage = [&](int kb, int bi) {
    int s0 = kb * 64;
    async16(kg + (size_t)s0 * CC, &Kls[bi][w * 512]);
    async16(kg + (size_t)s0 * CC + 32, &Kls[bi][2048 + w * 512]);
    async16(vg + s0, &Vls[bi][w * 512]);
    async16(vg + s0 + 32, &Vls[bi][2048 + w * 512]);
  };
  stage(0, 0);
  for (int kb = 0; kb <= qb; kb++) {
    __syncthreads();
    if (kb < qb) stage(kb + 1, (kb + 1) & 1);
    int bi = kb & 1;
    int s0 = kb * 64;
    bf16x8 kfr[4][2], vfr[4][2];
    #pragma unroll
    for (int t = 0; t < 4; t++)
      #pragma unroll
      for (int ks = 0; ks < 2; ks++) {
        kfr[t][ks] = *(const bf16x8*)&Kls[bi][(ks * 64 + t * 16 + l16) * 32 + quad * 8];
        vfr[t][ks] = *(const bf16x8*)&Vls[bi][(ks * 64 + t * 16 + l16) * 32 + quad * 8];
      }
    f32x4 st[4];
    #pragma unroll
    for (int t = 0; t < 4; t++) {
      st[t] = f32x4{0.f, 0.f, 0.f, 0.f};
      #pragma unroll
      for (int ks = 0; ks < 2; ks++)
        st[t] = __builtin_amdgcn_mfma_f32_16x16x32_bf16(kfr[t][ks], aq[ks], st[t], 0, 0, 0);
    }
    float sv[4][4];
    float vmax = -1e30f;
    if (kb == qb) {
      #pragma unroll
      for (int t = 0; t < 4; t++)
        #pragma unroll
        for (int r = 0; r < 4; r++) {
          float sc = st[t][r] * ksc;
          int scol = s0 + t * 16 + quad * 4 + r;
          if (scol > trow) sc = -1e30f;
          sv[t][r] = sc;
          vmax = fmaxf(vmax, sc);
        }
    } else {
      #pragma unroll
      for (int t = 0; t < 4; t++)
        #pragma unroll
        for (int r = 0; r < 4; r++) {
          float sc = st[t][r] * ksc;
          sv[t][r] = sc;
          vmax = fmaxf(vmax, sc);
        }
    }
    vmax = fmaxf(vmax, __shfl_xor(vmax, 16));
    vmax = fmaxf(vmax, __shfl_xor(vmax, 32));
    float mnew = fmaxf(mrun, vmax);
    float alpha = __builtin_amdgcn_exp2f(mrun - mnew);
    mrun = mnew;
    float psum = 0.f;
    int pk[4][2];
    #pragma unroll
    for (int t = 0; t < 4; t++) {
      float p0 = __builtin_amdgcn_exp2f(sv[t][0] - mnew);
      float p1 = __builtin_amdgcn_exp2f(sv[t][1] - mnew);
      float p2 = __builtin_amdgcn_exp2f(sv[t][2] - mnew);
      float p3 = __builtin_amdgcn_exp2f(sv[t][3] - mnew);
      psum += (p0 + p1) + (p2 + p3);
      pk[t][0] = (int)((unsigned)f2b(p0) | ((unsigned)f2b(p1) << 16));
      pk[t][1] = (int)((unsigned)f2b(p2) | ((unsigned)f2b(p3) << 16));
    }
    psum += __shfl_xor(psum, 16);
    psum += __shfl_xor(psum, 32);
    lrun = lrun * alpha + psum;
    #pragma unroll
    for (int dt = 0; dt < 4; dt++) O[dt] *= alpha;
    #pragma unroll
    for (int g32 = 0; g32 < 2; g32++) {
      int t0 = 2 * g32, t1 = t0 + 1;
      int a0 = __shfl(pk[t0][0], src0), b0 = __shfl(pk[t1][0], src0);
      int a1 = __shfl(pk[t0][1], src0), b1 = __shfl(pk[t1][1], src0);
      int a2 = __shfl(pk[t0][0], src1), b2 = __shfl(pk[t1][0], src1);
      int a3 = __shfl(pk[t0][1], src1), b3 = __shfl(pk[t1][1], src1);
      union { int4 i; bf16x8 h; } u;
      u.i.x = hiq ? b0 : a0;
      u.i.y = hiq ? b1 : a1;
      u.i.z = hiq ? b2 : a2;
      u.i.w = hiq ? b3 : a3;
      #pragma unroll
      for (int dt = 0; dt < 4; dt++)
        O[dt] = __builtin_amdgcn_mfma_f32_16x16x32_bf16(vfr[dt][g32], u.h, O[dt], 0, 0, 0);
    }
  }
  float inv = 1.f / lrun;
  #pragma unroll
  for (int dt = 0; dt < 4; dt++) {
    ushort4 o;
    unsigned short* op = (unsigned short*)&o;
    #pragma unroll
    for (int r = 0; r < 4; r++) op[r] = f2b(O[dt][r] * inv);
    *(ushort4*)&out[(size_t)(b * T + trow) * 1024 + h * 64 + dt * 16 + quad * 4] = o;
  }
}

// ---------- host ----------
extern "C" void kernel_launch(void* const* d_in, const int* in_sizes, int n_in,
                              void* d_out, int out_size, void* d_ws, size_t ws_size,
                              hipStream_t stream) {
  const int B = 2, T = 2048, C = 1024, H = 16, D = 64, FF = 4096;
  const int M = B * T;  // 4096
  const float* x   = (const float*)d_in[0];
  const float* Wq  = (const float*)d_in[1];
  const float* Wk  = (const float*)d_in[2];
  const float* Wv  = (const float*)d_in[3];
  const float* Wo  = (const float*)d_in[4];
  const float* bo  = (const float*)d_in[5];
  const float* W1  = (const float*)d_in[6];
  const float* b1  = (const float*)d_in[7];
  const float* W2  = (const float*)d_in[8];
  const float* b2  = (const float*)d_in[9];
  const float* g1  = (const float*)d_in[10];
  const float* be1 = (const float*)d_in[11];
  const float* g2  = (const float*)d_in[12];
  const float* be2 = (const float*)d_in[13];
  float* out = (float*)d_out;

  char* ws = (char*)d_ws;
  size_t off = 0;
  auto alloc = [&](size_t bytes) {
    void* p = ws + off;
    off += (bytes + 255) & ~(size_t)255;
    return p;
  };
  // FF2 split-K=4 partial buffers alias dead regions (layout-dependent!):
  //   pf0 = qkvt span (qkvt+wot+w1t = exactly M*C floats; all dead post-FF1)
  //   pf1 = hbuf (OVERSIZED to M*C floats; dead after FF1)
  //   pf2 = vtb span (vtb+aout = M*C floats; dead after Wo)
  //   pf3 = d_out (z=3 partial written there; reduce3 does out += p0+p1+p2+...)
  ushort_t* qkvt = (ushort_t*)alloc((size_t)3 * C * C * 2);  // 6.29 MB
  ushort_t* wot  = (ushort_t*)alloc((size_t)C * C * 2);      // 2.10 MB
  ushort_t* w1t  = (ushort_t*)alloc((size_t)FF * C * 2);     // 8.39 MB
  ushort_t* w2t  = (ushort_t*)alloc((size_t)C * FF * 2);     // 8.39 MB
  ushort_t* hbuf = (ushort_t*)alloc((size_t)M * C * 4);      // 16.78 MB (oversized)
  ushort_t* big  = (ushort_t*)alloc((size_t)M * FF * 2);     // 33.55 MB
  ushort_t* vtb  = (ushort_t*)alloc((size_t)M * C * 2);      // 8.39 MB
  ushort_t* aout = (ushort_t*)alloc((size_t)M * C * 2);      // 8.39 MB
  float*    x2   = (float*)alloc((size_t)M * C * 4);         // 16.78 MB
  float* pf0 = (float*)qkvt;   // 16.78 MB span (qkvt+wot+w1t)
  float* pf1 = (float*)hbuf;   // 16.78 MB (oversized hbuf)
  float* pf2 = (float*)vtb;    // 16.78 MB span (vtb+aout)

  dim3 tb(32, 8);
  transpose_all_kernel<<<12288, tb, 0, stream>>>(
      Wq, Wk, Wv, Wo, W1, W2, qkvt, wot, w1t, w2t);
  ln_kernel<<<M, 256, 0, stream>>>(x, g1, be1, hbuf);
  // QKV = h @ Wqkv^T -> bf16  (192 blocks of 256^2 8-phase)
  gemm256p8_kernel<3072, 1024, 2, 1><<<192, 512, 0, stream>>>(
      hbuf, qkvt, nullptr, big, nullptr, nullptr, nullptr, nullptr);
  transpose_v_kernel<<<dim3(2, T / 32, B * H), tb, 0, stream>>>(big, vtb);
  attn_kernel<<<1024, 256, 0, stream>>>(big, vtb, aout);
  // x2 = attn @ Wo^T + bo + x (fp32)  (128x64 tiles: 512 blocks)
  gemm_bt64_kernel<1024, 1024, 4 | 8, 1><<<512, 256, 0, stream>>>(
      aout, wot, bo, x, x2, nullptr, nullptr);
  ln_kernel<<<M, 256, 0, stream>>>(x2, g2, be2, hbuf);
  // ff1 = relu(h2 @ W1^T + b1) -> bf16  (256 blocks of 256^2 8-phase, 1/CU)
  gemm256p8_kernel<4096, 1024, 1 | 2 | 4, 1><<<256, 512, 0, stream>>>(
      hbuf, w1t, b1, big, nullptr, nullptr, nullptr, nullptr);
  // ff2 split-K=4 at 256^2 8-phase (256 blocks = 1/CU), partials -> reduce3
  gemm256p8_kernel<1024, 4096, 0, 4><<<256, 512, 0, stream>>>(
      big, w2t, nullptr, nullptr, pf0, pf1, pf2, out);
  reduce3_kernel<<<M * C / 1024, 256, 0, stream>>>(pf0, pf1, pf2, b2, x2, out);
}

// Round 12
// 348.544 us; speedup vs baseline: 1.0713x; 1.0076x over previous
//
#include <hip/hip_runtime.h>
#include <stdint.h>

typedef unsigned short ushort_t;
typedef __attribute__((ext_vector_type(8))) short bf16x8;   // 8 bf16 in 4 VGPRs
typedef __attribute__((ext_vector_type(4))) float f32x4;

// ---------- helpers ----------
__device__ __forceinline__ unsigned short f2b(float f) {
  unsigned u = __float_as_uint(f);
  u += 0x7fffu + ((u >> 16) & 1u);   // round-to-nearest-even
  return (unsigned short)(u >> 16);
}

__device__ __forceinline__ void async16(const void* g, void* l) {
  __builtin_amdgcn_global_load_lds(
      (const __attribute__((address_space(1))) void*)g,
      (__attribute__((address_space(3))) void*)l, 16, 0, 0);
}

// ---------- LayerNorm (fp32 in -> bf16 out), one block per row, C=1024 ----------
__global__ __launch_bounds__(256) void ln_kernel(
    const float* __restrict__ x, const float* __restrict__ g,
    const float* __restrict__ be, ushort_t* __restrict__ out) {
  const int C = 1024;
  int row = blockIdx.x;
  const float4* xr = (const float4*)(x + (size_t)row * C);
  int tid = threadIdx.x;
  float4 v = xr[tid];
  float s = v.x + v.y + v.z + v.w;
  float sq = v.x * v.x + v.y * v.y + v.z * v.z + v.w * v.w;
  #pragma unroll
  for (int off = 32; off > 0; off >>= 1) {
    s += __shfl_xor(s, off);
    sq += __shfl_xor(sq, off);
  }
  __shared__ float ss[4], ssq[4];
  int wv = tid >> 6;
  if ((tid & 63) == 0) { ss[wv] = s; ssq[wv] = sq; }
  __syncthreads();
  s = ss[0] + ss[1] + ss[2] + ss[3];
  sq = ssq[0] + ssq[1] + ssq[2] + ssq[3];
  float mu = s * (1.f / C);
  float var = sq * (1.f / C) - mu * mu;
  float rs = rsqrtf(var + 1e-5f);
  float4 gv = ((const float4*)g)[tid];
  float4 bv = ((const float4*)be)[tid];
  ushort4 o;
  o.x = f2b((v.x - mu) * rs * gv.x + bv.x);
  o.y = f2b((v.y - mu) * rs * gv.y + bv.y);
  o.z = f2b((v.z - mu) * rs * gv.z + bv.z);
  o.w = f2b((v.w - mu) * rs * gv.w + bv.w);
  ((ushort4*)(out + (size_t)row * C))[tid] = o;
}

// ---------- split-K=4 final reduce: out += p0 + p1 + p2 + bias + resid ----------
// (out already holds the z=3 partial; per-thread read-modify-write, no race)
__global__ __launch_bounds__(256) void reduce3_kernel(
    const float* __restrict__ p0, const float* __restrict__ p1,
    const float* __restrict__ p2, const float* __restrict__ bias,
    const float* __restrict__ resid, float* out) {
  int idx = blockIdx.x * 256 + threadIdx.x;      // float4 index
  float4 a = ((const float4*)p0)[idx];
  float4 b = ((const float4*)p1)[idx];
  float4 c = ((const float4*)p2)[idx];
  float4 r = ((const float4*)resid)[idx];
  float4 bi = ((const float4*)bias)[idx & 255];  // 1024 floats = 256 float4/row
  float4 o = ((const float4*)out)[idx];
  o.x += a.x + b.x + c.x + r.x + bi.x;
  o.y += a.y + b.y + c.y + r.y + bi.y;
  o.z += a.z + b.z + c.z + r.z + bi.z;
  o.w += a.w + b.w + c.w + r.w + bi.w;
  ((float4*)out)[idx] = o;
}

// ---------- fused weight transpose+cast: ALL weights in one launch ----------
__global__ __launch_bounds__(256) void transpose_all_kernel(
    const float* __restrict__ Wq, const float* __restrict__ Wk,
    const float* __restrict__ Wv, const float* __restrict__ Wo,
    const float* __restrict__ W1, const float* __restrict__ W2,
    ushort_t* __restrict__ qkvt, ushort_t* __restrict__ wot,
    ushort_t* __restrict__ w1t, ushort_t* __restrict__ w2t) {
  int bid = blockIdx.x;
  const float* in;
  ushort_t* out;
  int R, Cin, bx, by;
  if (bid < 3072) {
    int z = bid >> 6, rem = bid & 63;
    bx = rem & 1; by = rem >> 1;
    int wsel = z >> 4, h = z & 15;
    in = (wsel == 0 ? Wq : wsel == 1 ? Wk : Wv) + (size_t)h * 1024 * 64;
    out = qkvt + (size_t)wsel * 1024 * 1024 + (size_t)h * 1024 * 64;
    R = 1024; Cin = 64;
  } else if (bid < 4096) {
    int rem = bid - 3072;
    bx = rem & 31; by = rem >> 5;
    in = Wo; out = wot; R = 1024; Cin = 1024;
  } else if (bid < 8192) {
    int rem = bid - 4096;
    bx = rem & 127; by = rem >> 7;
    in = W1; out = w1t; R = 1024; Cin = 4096;
  } else {
    int rem = bid - 8192;
    bx = rem & 31; by = rem >> 5;
    in = W2; out = w2t; R = 4096; Cin = 1024;
  }
  __shared__ float tile[32][33];
  int c0 = bx * 32, r0 = by * 32;
  int tx = threadIdx.x, ty = threadIdx.y;
  #pragma unroll
  for (int i = 0; i < 4; i++)
    tile[ty + 8 * i][tx] = in[(size_t)(r0 + ty + 8 * i) * Cin + c0 + tx];
  __syncthreads();
  #pragma unroll
  for (int i = 0; i < 4; i++)
    out[(size_t)(c0 + ty + 8 * i) * R + r0 + tx] = f2b(tile[tx][ty + 8 * i]);
}

// ---------- V transpose: QKV (4096,3072) bf16 -> Vt (B*H, 64, 2048) bf16 ----------
__global__ __launch_bounds__(256) void transpose_v_kernel(
    const ushort_t* __restrict__ qkv, ushort_t* __restrict__ vt) {
  __shared__ ushort_t tile[32][33];
  int bh = blockIdx.z;
  int b = bh >> 4, h = bh & 15;
  int d0 = blockIdx.x * 32, t0 = blockIdx.y * 32;
  int tx = threadIdx.x, ty = threadIdx.y;
  #pragma unroll
  for (int i = 0; i < 4; i++)
    tile[ty + 8 * i][tx] =
        qkv[(size_t)(b * 2048 + t0 + ty + 8 * i) * 3072 + 2048 + h * 64 + d0 + tx];
  __syncthreads();
  #pragma unroll
  for (int i = 0; i < 4; i++)
    vt[(size_t)(bh * 64 + d0 + ty + 8 * i) * 2048 + t0 + tx] = tile[tx][ty + 8 * i];
}

// ================= 256x256 8-phase GEMM (m201 template port) =================
// BM=BN=256, BK=64, 8 waves (2M x 4N), 512 threads, 128 KB LDS (1 block/CU).
// Per wave: 128x64 output = acc[8][4]. Per phase: 16 MFMA (one C-quadrant,
// K=64). 4 phases per K-tile, 8 per iteration (2 K-tiles). One half-tile
// staged per phase; counted vmcnt(4) only at phases 4/8 (see r9 ledger).
// SK>1: K split into SK spans; block z writes raw fp32 partial to ppz.
// FLAGS: 1=relu, 2=bf16 out, 4=+bias (SK=1 only).
#define RD_A(DB, MB) \
  _Pragma("unroll") \
  for (int mf_ = 0; mf_ < 4; mf_++) { \
    af[(MB) + mf_][0] = *(const bf16x8*)&Als[DB][wm][(aRow + ((MB) + mf_) * 16) * 64 + rof0]; \
    af[(MB) + mf_][1] = *(const bf16x8*)&Als[DB][wm][(aRow + ((MB) + mf_) * 16) * 64 + rof1]; \
  }
#define RD_B(DB, NB) \
  _Pragma("unroll") \
  for (int nf_ = 0; nf_ < 2; nf_++) { \
    bf[(NB) + nf_][0] = *(const bf16x8*)&Bls[DB][bhh][(bRow + ((NB) + nf_) * 16) * 64 + rof0]; \
    bf[(NB) + nf_][1] = *(const bf16x8*)&Bls[DB][bhh][(bRow + ((NB) + nf_) * 16) * 64 + rof1]; \
  }
#define MMPH(MB, NB) \
  __builtin_amdgcn_s_barrier(); \
  asm volatile("s_waitcnt lgkmcnt(0)" ::: "memory"); \
  __builtin_amdgcn_sched_barrier(0); \
  __builtin_amdgcn_s_setprio(1); \
  _Pragma("unroll") \
  for (int mf_ = 0; mf_ < 4; mf_++) \
    _Pragma("unroll") \
    for (int nf_ = 0; nf_ < 2; nf_++) { \
      acc[(MB) + mf_][(NB) + nf_] = __builtin_amdgcn_mfma_f32_16x16x32_bf16( \
          af[(MB) + mf_][0], bf[(NB) + nf_][0], acc[(MB) + mf_][(NB) + nf_], 0, 0, 0); \
      acc[(MB) + mf_][(NB) + nf_] = __builtin_amdgcn_mfma_f32_16x16x32_bf16( \
          af[(MB) + mf_][1], bf[(NB) + nf_][1], acc[(MB) + mf_][(NB) + nf_], 0, 0, 0); \
    } \
  __builtin_amdgcn_s_setprio(0);
#define ENDPH __builtin_amdgcn_s_barrier();

template <int N, int K, int FLAGS, int SK>
__global__ __launch_bounds__(512, 2) void gemm256p8_kernel(
    const ushort_t* __restrict__ A, const ushort_t* __restrict__ Bt,
    const float* __restrict__ bias, void* __restrict__ outv,
    float* __restrict__ pp0, float* __restrict__ pp1,
    float* __restrict__ pp2, float* __restrict__ pp3) {
  constexpr int NBM = 4096 / 256;        // 16
  constexpr int NBN = N / 256;
  constexpr int KS = K / SK;             // K-span per block
  constexpr int NT2 = KS / 128;          // iterations, 2 K-tiles each (>= 2)
  __shared__ __align__(16) ushort_t Als[2][2][128 * 64];   // 64 KB
  __shared__ __align__(16) ushort_t Bls[2][2][128 * 64];   // 64 KB
  int tid = threadIdx.x, w = tid >> 6, lane = tid & 63;
  int quad = lane >> 4, l16 = lane & 15;
  int wm = w >> 2, wn = w & 3;
  int bid = blockIdx.x;
  int z = 0, rem = bid;
  if constexpr (SK > 1) { z = bid / (NBM * NBN); rem = bid - z * (NBM * NBN); }
  int bm = rem / NBN, bn = rem % NBN;
  int bm0 = bm * 256, bn0 = bn * 256;
  int koff = z * KS;
  // staging constants: lane -> row (w*8 + lane>>3) within 64-row group,
  // source chunk pre-swizzled so linear LDS + XOR read recovers data.
  int lrow = (w << 3) + (lane >> 3);
  int kc8 = ((lane & 7) ^ ((lane >> 3) & 7)) << 3;
  const ushort_t* Ab = A + (size_t)(bm0 + lrow) * K + koff + kc8;
  const ushort_t* Bb = Bt + (size_t)(bn0 + lrow) * K + koff + kc8;
  // read constants
  int rof0 = (quad ^ (l16 & 7)) << 3;
  int rof1 = ((4 + quad) ^ (l16 & 7)) << 3;
  int bhh = wn >> 1;
  int aRow = l16;
  int bRow = (wn & 1) * 64 + l16;

  auto stA = [&](int kt, int half, int db) {
    const ushort_t* g = Ab + (size_t)(half * 128) * K + kt * 64;
    ushort_t* l = &Als[db][half][w * 512];
    async16(g, l);
    async16(g + (size_t)64 * K, l + 4096);
  };
  auto stB = [&](int kt, int half, int db) {
    const ushort_t* g = Bb + (size_t)(half * 128) * K + kt * 64;
    ushort_t* l = &Bls[db][half][w * 512];
    async16(g, l);
    async16(g + (size_t)64 * K, l + 4096);
  };

  f32x4 acc[8][4];
  #pragma unroll
  for (int mf = 0; mf < 8; mf++)
    #pragma unroll
    for (int nf = 0; nf < 4; nf++) acc[mf][nf] = f32x4{0.f, 0.f, 0.f, 0.f};
  bf16x8 af[8][2], bf[4][2];

  // prologue: tile0 (A+B) -> d0, tile1 A -> d1; tile0 fully retired.
  stA(0, 0, 0); stA(0, 1, 0);
  stB(0, 0, 0); stB(0, 1, 0);
  stA(1, 0, 1); stA(1, 1, 1);
  asm volatile("s_waitcnt vmcnt(4)" ::: "memory");
  __builtin_amdgcn_s_barrier();

  #pragma unroll 1
  for (int i = 0; i < NT2; ++i) {
    bool lastI = (i == NT2 - 1);
    int t1 = 2 * i + 1;
    // ---- P1: quadrant (m0-3, n0-1) of tile 2i ----
    RD_A(0, 0)
    RD_B(0, 0)
    stB(t1, 0, 1);
    MMPH(0, 0)
    ENDPH
    // ---- P2: (m4-7, n0-1) ----
    RD_A(0, 4)
    stB(t1, 1, 1);
    MMPH(4, 0)
    ENDPH
    // ---- P3: (m4-7, n2-3) ----
    RD_B(0, 2)
    if (!lastI) stA(t1 + 1, 0, 0);
    MMPH(4, 2)
    ENDPH
    // ---- P4: (m0-3, n2-3); counted drain ----
    if (!lastI) stA(t1 + 1, 1, 0);
    MMPH(0, 2)
    if (!lastI) asm volatile("s_waitcnt vmcnt(4)" ::: "memory");
    else        asm volatile("s_waitcnt vmcnt(0)" ::: "memory");
    ENDPH
    // ---- P5: tile 2i+1, quadrant (m0-3, n0-1) ----
    RD_A(1, 0)
    RD_B(1, 0)
    if (!lastI) stB(t1 + 1, 0, 0);
    MMPH(0, 0)
    ENDPH
    // ---- P6: (m4-7, n0-1) ----
    RD_A(1, 4)
    if (!lastI) stB(t1 + 1, 1, 0);
    MMPH(4, 0)
    ENDPH
    // ---- P7: (m4-7, n2-3) ----
    RD_B(1, 2)
    if (!lastI) stA(t1 + 2, 0, 1);
    MMPH(4, 2)
    ENDPH
    // ---- P8: (m0-3, n2-3); counted drain ----
    if (!lastI) stA(t1 + 2, 1, 1);
    MMPH(0, 2)
    if (!lastI) asm volatile("s_waitcnt vmcnt(4)" ::: "memory");
    ENDPH
  }
  // ---- epilogue ----
  if constexpr (SK > 1) {
    float* pdst = z == 0 ? pp0 : z == 1 ? pp1 : z == 2 ? pp2 : pp3;
    #pragma unroll
    for (int mf = 0; mf < 8; mf++)
      #pragma unroll
      for (int nf = 0; nf < 4; nf++)
        #pragma unroll
        for (int r = 0; r < 4; r++) {
          int row = bm0 + wm * 128 + mf * 16 + quad * 4 + r;
          int col = bn0 + wn * 64 + nf * 16 + l16;
          pdst[(size_t)row * N + col] = acc[mf][nf][r];   // raw partial
        }
  } else {
    #pragma unroll
    for (int mf = 0; mf < 8; mf++)
      #pragma unroll
      for (int nf = 0; nf < 4; nf++)
        #pragma unroll
        for (int r = 0; r < 4; r++) {
          int row = bm0 + wm * 128 + mf * 16 + quad * 4 + r;
          int col = bn0 + wn * 64 + nf * 16 + l16;
          float v = acc[mf][nf][r];
          if constexpr (FLAGS & 4) v += bias[col];
          if constexpr (FLAGS & 1) v = fmaxf(v, 0.f);
          if constexpr ((FLAGS & 2) != 0)
            ((ushort_t*)outv)[(size_t)row * N + col] = f2b(v);
          else
            ((float*)outv)[(size_t)row * N + col] = v;
        }
  }
}
#undef RD_A
#undef RD_B
#undef MMPH
#undef ENDPH

// ---------- GEMM 128x64 tile (m97 structure): Wo projection ----------
template <int N, int K, int FLAGS, int SK>
__global__ __launch_bounds__(256, 3) void gemm_bt64_kernel(
    const ushort_t* __restrict__ A, const ushort_t* __restrict__ Bt,
    const float* __restrict__ bias, const float* __restrict__ resid,
    void* __restrict__ outv, float* __restrict__ pp0, float* __restrict__ pp1) {
  constexpr int KS = K / SK;
  constexpr int NBM = 32;                // M = 4096 / 128
  constexpr int NBN = N / 64;
  constexpr int NWG = NBM * NBN * SK;    // must == gridDim.x, % 8 == 0
  __shared__ ushort_t Als[2][128 * 32];  // 16 KB
  __shared__ ushort_t Bls[2][64 * 32];   //  8 KB
  int tid = threadIdx.x, w = tid >> 6, lane = tid & 63, quad = lane >> 4, l16 = lane & 15;
  int bid = blockIdx.x;
  int swz = (bid & 7) * (NWG / 8) + (bid >> 3);
  int z = 0;
  if constexpr (SK > 1) { z = swz / (NBM * NBN); swz -= z * (NBM * NBN); }
  int bm = swz / NBN, bn = swz - bm * NBN;
  int bm0 = bm * 128, bn0 = bn * 64;
  int koff = z * KS;
  int wm = (w >> 1) * 64, wn = (w & 1) * 32;
  f32x4 acc[4][2];
  #pragma unroll
  for (int i = 0; i < 4; i++)
    #pragma unroll
    for (int j = 0; j < 2; j++) acc[i][j] = f32x4{0.f, 0.f, 0.f, 0.f};
  const ushort_t* Ag = A + (size_t)bm0 * K + koff;
  const ushort_t* Bg = Bt + (size_t)bn0 * K + koff;
  int lr = lane >> 2, lco = (lane & 3) * 8;
  auto stage = [&](int k0, int bi) {
    async16(Ag + (size_t)(w * 32 + lr) * K + k0 + lco, &Als[bi][w * 1024]);
    async16(Ag + (size_t)(w * 32 + 16 + lr) * K + k0 + lco, &Als[bi][w * 1024 + 512]);
    async16(Bg + (size_t)(w * 16 + lr) * K + k0 + lco, &Bls[bi][w * 512]);
  };
  stage(0, 0);
  int s = 0;
  for (int k0 = 0; k0 < KS; k0 += 32, s ^= 1) {
    __syncthreads();
    if (k0 + 32 < KS) stage(k0 + 32, s ^ 1);
    bf16x8 af[4], bf[2];
    #pragma unroll
    for (int i = 0; i < 4; i++)
      af[i] = *(const bf16x8*)&Als[s][(wm + i * 16 + l16) * 32 + quad * 8];
    #pragma unroll
    for (int j = 0; j < 2; j++)
      bf[j] = *(const bf16x8*)&Bls[s][(wn + j * 16 + l16) * 32 + quad * 8];
    #pragma unroll
    for (int i = 0; i < 4; i++)
      #pragma unroll
      for (int j = 0; j < 2; j++)
        acc[i][j] = __builtin_amdgcn_mfma_f32_16x16x32_bf16(af[i], bf[j], acc[i][j], 0, 0, 0);
  }
  float* pdst = nullptr;
  if constexpr (SK > 1) pdst = z ? pp1 : pp0;
  #pragma unroll
  for (int i = 0; i < 4; i++)
    #pragma unroll
    for (int j = 0; j < 2; j++)
      #pragma unroll
      for (int r = 0; r < 4; r++) {
        int row = bm0 + wm + i * 16 + quad * 4 + r;
        int col = bn0 + wn + j * 16 + l16;
        float v = acc[i][j][r];
        if constexpr (SK > 1) {
          pdst[(size_t)row * N + col] = v;   // raw partial
        } else {
          if constexpr (FLAGS & 4) v += bias[col];
          if constexpr (FLAGS & 8) v += resid[(size_t)row * N + col];
          if constexpr (FLAGS & 1) v = fmaxf(v, 0.f);
          if constexpr ((FLAGS & 2) != 0)
            ((ushort_t*)outv)[(size_t)row * N + col] = f2b(v);
          else
            ((float*)outv)[(size_t)row * N + col] = v;
        }
      }
}

// ---------- causal flash attention: dbuf LDS staging + S^T softmax ----------
// VALU reduction (r10: VALU 38.8%, Mfma 12.2%): (a) T13 defer-max — skip
// O/lrun rescale when __all(vmax - mrun <= 8) (P bounded by 2^8, safe in f32);
// wave-uniform branch, no divergence. (b) P->bf16 via truncation (P >= 0;
// <=1 ulp bias, ~0.2% on softmax weights): 3 VALU per pair vs ~10 for RNE.
__global__ __launch_bounds__(256, 4) void attn_kernel(
    const ushort_t* __restrict__ qkv, const ushort_t* __restrict__ vt,
    ushort_t* __restrict__ out) {
  const int T = 2048, CC = 3072;
  __shared__ ushort_t Kls[2][2 * 64 * 32];
  __shared__ ushort_t Vls[2][2 * 64 * 32];
  int fid = blockIdx.x;                       // 1024
  int bh = (fid & 7) * 4 + ((fid >> 3) & 3);  // XCD swizzle: 4 heads per XCD
  int qb = 31 - (fid >> 5);                   // longest q-blocks first
  int b = bh >> 4, h = bh & 15;
  int q0 = qb * 64;
  int tid = threadIdx.x, w = tid >> 6, lane = tid & 63, quad = lane >> 4, l16 = lane & 15;
  int srow = w * 16 + (lane >> 2);
  int sco = (lane & 3) * 8;
  const ushort_t* kg = qkv + (size_t)(b * T + srow) * CC + 1024 + h * 64 + sco;
  const ushort_t* vg = vt + (size_t)(bh * 64 + srow) * T + sco;
  int q0s = q0 + w * 16;
  int trow = q0s + l16;
  const ushort_t* qp = qkv + (size_t)(b * T + trow) * CC + h * 64 + quad * 8;
  bf16x8 aq[2] = { *(const bf16x8*)qp, *(const bf16x8*)(qp + 32) };
  f32x4 O[4];
  #pragma unroll
  for (int i = 0; i < 4; i++) O[i] = f32x4{0.f, 0.f, 0.f, 0.f};
  float mrun = -1e30f, lrun = 0.f;
  const float ksc = 0.03125f * 1.44269504f;  // C^-0.5 * log2(e)
  int src0 = (quad & 1) * 32 + l16;
  int src1 = src0 + 16;
  bool hiq = quad >= 2;
  auto stage = [&](int kb, int bi) {
    int s0 = kb * 64;
    async16(kg + (size_t)s0 * CC, &Kls[bi][w * 512]);
    async16(kg + (size_t)s0 * CC + 32, &Kls[bi][2048 + w * 512]);
    async16(vg + s0, &Vls[bi][w * 512]);
    async16(vg + s0 + 32, &Vls[bi][2048 + w * 512]);
  };
  stage(0, 0);
  for (int kb = 0; kb <= qb; kb++) {
    __syncthreads();
    if (kb < qb) stage(kb + 1, (kb + 1) & 1);
    int bi = kb & 1;
    int s0 = kb * 64;
    bf16x8 kfr[4][2], vfr[4][2];
    #pragma unroll
    for (int t = 0; t < 4; t++)
      #pragma unroll
      for (int ks = 0; ks < 2; ks++) {
        kfr[t][ks] = *(const bf16x8*)&Kls[bi][(ks * 64 + t * 16 + l16) * 32 + quad * 8];
        vfr[t][ks] = *(const bf16x8*)&Vls[bi][(ks * 64 + t * 16 + l16) * 32 + quad * 8];
      }
    f32x4 st[4];
    #pragma unroll
    for (int t = 0; t < 4; t++) {
      st[t] = f32x4{0.f, 0.f, 0.f, 0.f};
      #pragma unroll
      for (int ks = 0; ks < 2; ks++)
        st[t] = __builtin_amdgcn_mfma_f32_16x16x32_bf16(kfr[t][ks], aq[ks], st[t], 0, 0, 0);
    }
    float sv[4][4];
    float vmax = -1e30f;
    if (kb == qb) {
      #pragma unroll
      for (int t = 0; t < 4; t++)
        #pragma unroll
        for (int r = 0; r < 4; r++) {
          float sc = st[t][r] * ksc;
          int scol = s0 + t * 16 + quad * 4 + r;
          if (scol > trow) sc = -1e30f;
          sv[t][r] = sc;
          vmax = fmaxf(vmax, sc);
        }
    } else {
      #pragma unroll
      for (int t = 0; t < 4; t++)
        #pragma unroll
        for (int r = 0; r < 4; r++) {
          float sc = st[t][r] * ksc;
          sv[t][r] = sc;
          vmax = fmaxf(vmax, sc);
        }
    }
    vmax = fmaxf(vmax, __shfl_xor(vmax, 16));
    vmax = fmaxf(vmax, __shfl_xor(vmax, 32));
    // T13 defer-max: rescale only when some row's max grew by > 8 (wave-
    // uniform). P stays bounded by 2^8; first iter takes the grow path.
    if (!__all(vmax - mrun <= 8.f)) {
      float mnew = fmaxf(mrun, vmax);
      float alpha = __builtin_amdgcn_exp2f(mrun - mnew);
      mrun = mnew;
      lrun *= alpha;
      #pragma unroll
      for (int dt = 0; dt < 4; dt++) O[dt] *= alpha;
    }
    float psum = 0.f;
    int pk[4][2];
    #pragma unroll
    for (int t = 0; t < 4; t++) {
      float p0 = __builtin_amdgcn_exp2f(sv[t][0] - mrun);
      float p1 = __builtin_amdgcn_exp2f(sv[t][1] - mrun);
      float p2 = __builtin_amdgcn_exp2f(sv[t][2] - mrun);
      float p3 = __builtin_amdgcn_exp2f(sv[t][3] - mrun);
      psum += (p0 + p1) + (p2 + p3);
      // truncation pack (P >= 0): 3 VALU vs ~10 for RNE f2b pair
      pk[t][0] = (int)((__float_as_uint(p0) >> 16) | (__float_as_uint(p1) & 0xffff0000u));
      pk[t][1] = (int)((__float_as_uint(p2) >> 16) | (__float_as_uint(p3) & 0xffff0000u));
    }
    psum += __shfl_xor(psum, 16);
    psum += __shfl_xor(psum, 32);
    lrun += psum;
    #pragma unroll
    for (int g32 = 0; g32 < 2; g32++) {
      int t0 = 2 * g32, t1 = t0 + 1;
      int a0 = __shfl(pk[t0][0], src0), b0 = __shfl(pk[t1][0], src0);
      int a1 = __shfl(pk[t0][1], src0), b1 = __shfl(pk[t1][1], src0);
      int a2 = __shfl(pk[t0][0], src1), b2 = __shfl(pk[t1][0], src1);
      int a3 = __shfl(pk[t0][1], src1), b3 = __shfl(pk[t1][1], src1);
      union { int4 i; bf16x8 h; } u;
      u.i.x = hiq ? b0 : a0;
      u.i.y = hiq ? b1 : a1;
      u.i.z = hiq ? b2 : a2;
      u.i.w = hiq ? b3 : a3;
      #pragma unroll
      for (int dt = 0; dt < 4; dt++)
        O[dt] = __builtin_amdgcn_mfma_f32_16x16x32_bf16(vfr[dt][g32], u.h, O[dt], 0, 0, 0);
    }
  }
  float inv = 1.f / lrun;
  #pragma unroll
  for (int dt = 0; dt < 4; dt++) {
    ushort4 o;
    unsigned short* op = (unsigned short*)&o;
    #pragma unroll
    for (int r = 0; r < 4; r++) op[r] = f2b(O[dt][r] * inv);
    *(ushort4*)&out[(size_t)(b * T + trow) * 1024 + h * 64 + dt * 16 + quad * 4] = o;
  }
}

// ---------- host ----------
extern "C" void kernel_launch(void* const* d_in, const int* in_sizes, int n_in,
                              void* d_out, int out_size, void* d_ws, size_t ws_size,
                              hipStream_t stream) {
  const int B = 2, T = 2048, C = 1024, H = 16, D = 64, FF = 4096;
  const int M = B * T;  // 4096
  const float* x   = (const float*)d_in[0];
  const float* Wq  = (const float*)d_in[1];
  const float* Wk  = (const float*)d_in[2];
  const float* Wv  = (const float*)d_in[3];
  const float* Wo  = (const float*)d_in[4];
  const float* bo  = (const float*)d_in[5];
  const float* W1  = (const float*)d_in[6];
  const float* b1  = (const float*)d_in[7];
  const float* W2  = (const float*)d_in[8];
  const float* b2  = (const float*)d_in[9];
  const float* g1  = (const float*)d_in[10];
  const float* be1 = (const float*)d_in[11];
  const float* g2  = (const float*)d_in[12];
  const float* be2 = (const float*)d_in[13];
  float* out = (float*)d_out;

  char* ws = (char*)d_ws;
  size_t off = 0;
  auto alloc = [&](size_t bytes) {
    void* p = ws + off;
    off += (bytes + 255) & ~(size_t)255;
    return p;
  };
  // FF2 split-K=4 partial buffers alias dead regions (layout-dependent!):
  //   pf0 = qkvt span (qkvt+wot+w1t = exactly M*C floats; all dead post-FF1)
  //   pf1 = hbuf (OVERSIZED to M*C floats; dead after FF1)
  //   pf2 = vtb span (vtb+aout = M*C floats; dead after Wo)
  //   pf3 = d_out (z=3 partial written there; reduce3 does out += p0+p1+p2+...)
  ushort_t* qkvt = (ushort_t*)alloc((size_t)3 * C * C * 2);  // 6.29 MB
  ushort_t* wot  = (ushort_t*)alloc((size_t)C * C * 2);      // 2.10 MB
  ushort_t* w1t  = (ushort_t*)alloc((size_t)FF * C * 2);     // 8.39 MB
  ushort_t* w2t  = (ushort_t*)alloc((size_t)C * FF * 2);     // 8.39 MB
  ushort_t* hbuf = (ushort_t*)alloc((size_t)M * C * 4);      // 16.78 MB (oversized)
  ushort_t* big  = (ushort_t*)alloc((size_t)M * FF * 2);     // 33.55 MB
  ushort_t* vtb  = (ushort_t*)alloc((size_t)M * C * 2);      // 8.39 MB
  ushort_t* aout = (ushort_t*)alloc((size_t)M * C * 2);      // 8.39 MB
  float*    x2   = (float*)alloc((size_t)M * C * 4);         // 16.78 MB
  float* pf0 = (float*)qkvt;   // 16.78 MB span (qkvt+wot+w1t)
  float* pf1 = (float*)hbuf;   // 16.78 MB (oversized hbuf)
  float* pf2 = (float*)vtb;    // 16.78 MB span (vtb+aout)

  dim3 tb(32, 8);
  transpose_all_kernel<<<12288, tb, 0, stream>>>(
      Wq, Wk, Wv, Wo, W1, W2, qkvt, wot, w1t, w2t);
  ln_kernel<<<M, 256, 0, stream>>>(x, g1, be1, hbuf);
  // QKV = h @ Wqkv^T -> bf16  (192 blocks of 256^2 8-phase)
  gemm256p8_kernel<3072, 1024, 2, 1><<<192, 512, 0, stream>>>(
      hbuf, qkvt, nullptr, big, nullptr, nullptr, nullptr, nullptr);
  transpose_v_kernel<<<dim3(2, T / 32, B * H), tb, 0, stream>>>(big, vtb);
  attn_kernel<<<1024, 256, 0, stream>>>(big, vtb, aout);
  // x2 = attn @ Wo^T + bo + x (fp32)  (128x64 tiles: 512 blocks)
  gemm_bt64_kernel<1024, 1024, 4 | 8, 1><<<512, 256, 0, stream>>>(
      aout, wot, bo, x, x2, nullptr, nullptr);
  ln_kernel<<<M, 256, 0, stream>>>(x2, g2, be2, hbuf);
  // ff1 = relu(h2 @ W1^T + b1) -> bf16  (256 blocks of 256^2 8-phase, 1/CU)
  gemm256p8_kernel<4096, 1024, 1 | 2 | 4, 1><<<256, 512, 0, stream>>>(
      hbuf, w1t, b1, big, nullptr, nullptr, nullptr, nullptr);
  // ff2 split-K=4 at 256^2 8-phase (256 blocks = 1/CU), partials -> reduce3
  gemm256p8_kernel<1024, 4096, 0, 4><<<256, 512, 0, stream>>>(
      big, w2t, nullptr, nullptr, pf0, pf1, pf2, out);
  reduce3_kernel<<<M * C / 1024, 256, 0, stream>>>(pf0, pf1, pf2, b2, x2, out);
}